// Round 2
// baseline (4614.558 us; speedup 1.0000x reference)
//
#include <hip/hip_runtime.h>
#include <hip/hip_bf16.h>

// Problem constants
constexpr int kB = 4, kN = 1024, kD = 512, kH = 8, kDh = 64, kT = 512;
constexpr int kHid = 512, kI = 2048, kRel = 65, kDepth = 4;
constexpr int kBN = kB * kN;

// ---------------- dual-dtype load helper ----------------
__device__ __forceinline__ float ldin(const void* p, long i, int isb) {
  if (isb) return __bfloat162float(((const __hip_bfloat16*)p)[i]);
  return ((const float*)p)[i];
}

// ---------------- dtype detect ----------------
// Interpret first 64 u32 words of x. If input is bf16, the low 16 bits of each
// word are a bf16 of N(0,1) data -> exponent field (bits 14..7) lands in
// [100,140] almost surely. If fp32, those bits are random mantissa bits ->
// ~16% in-band. Vote.
__global__ void k_detect(const void* __restrict__ x, int* __restrict__ flag) {
  const unsigned int* u = (const unsigned int*)x;
  unsigned int v = u[threadIdx.x];
  int e = (v >> 7) & 0xFF;
  int good = (e >= 100 && e <= 140) ? 1 : 0;
  unsigned long long m = __ballot(good);
  if (threadIdx.x == 0) flag[0] = (__popcll(m) >= 48) ? 1 : 0;
}

// ---------------- t_act = silu(time) ----------------
__global__ void k_tact(const void* __restrict__ timein, float* __restrict__ tact,
                       const int* __restrict__ flag) {
  const int isb = *flag;
  int i = blockIdx.x * 256 + threadIdx.x;
  if (i < kB * kT) {
    float v = ldin(timein, i, isb);
    tact[i] = v / (1.f + __expf(-v));
  }
}

// ---------------- x = x_in * mask ----------------
__global__ void k_xinit(const void* __restrict__ xin, const void* __restrict__ seqm,
                        float* __restrict__ x, const int* __restrict__ flag) {
  const int isb = *flag;
  int i = blockIdx.x * 256 + threadIdx.x; // kBN*kD total
  int row = i >> 9; // / kD
  x[i] = ldin(xin, i, isb) * ldin(seqm, row, isb);
}

// ---------------- time projections for all layers ----------------
// grid: (20, DEPTH). cols 0..1023 -> attn sc|sh (2*kD), cols 1024..5119 ->
// ff sc|sh (2*kI = 4096).
__global__ __launch_bounds__(256) void k_timeproj(
    const float* __restrict__ tact,
    const void* __restrict__ atw, const void* __restrict__ atb,
    const void* __restrict__ ftw, const void* __restrict__ ftb,
    float* __restrict__ ascsh, float* __restrict__ fscsh,
    const int* __restrict__ flag) {
  const int isb = *flag;
  __shared__ float T[kB * kT];
  const int d = blockIdx.y;
  for (int i = threadIdx.x; i < kB * kT; i += 256) T[i] = tact[i];
  __syncthreads();
  const int c = blockIdx.x * 256 + threadIdx.x;
  float a0 = 0, a1 = 0, a2 = 0, a3 = 0;
  if (c < 2 * kD) {
    const long wo = (long)d * kT * 2 * kD + c;
    #pragma unroll 4
    for (int tt = 0; tt < kT; tt++) {
      const float w = ldin(atw, wo + (long)tt * 2 * kD, isb);
      a0 += T[0 * kT + tt] * w; a1 += T[1 * kT + tt] * w;
      a2 += T[2 * kT + tt] * w; a3 += T[3 * kT + tt] * w;
    }
    const float bv = ldin(atb, (long)d * 2 * kD + c, isb);
    ascsh[((long)d * kB + 0) * 2 * kD + c] = a0 + bv;
    ascsh[((long)d * kB + 1) * 2 * kD + c] = a1 + bv;
    ascsh[((long)d * kB + 2) * 2 * kD + c] = a2 + bv;
    ascsh[((long)d * kB + 3) * 2 * kD + c] = a3 + bv;
  } else {
    const int c2 = c - 2 * kD;
    if (c2 < 2 * kI) {
      const long wo = (long)d * kT * 2 * kI + c2;
      #pragma unroll 4
      for (int tt = 0; tt < kT; tt++) {
        const float w = ldin(ftw, wo + (long)tt * 2 * kI, isb);
        a0 += T[0 * kT + tt] * w; a1 += T[1 * kT + tt] * w;
        a2 += T[2 * kT + tt] * w; a3 += T[3 * kT + tt] * w;
      }
      const float bv = ldin(ftb, (long)d * 2 * kI + c2, isb);
      fscsh[((long)d * kB + 0) * 2 * kI + c2] = a0 + bv;
      fscsh[((long)d * kB + 1) * 2 * kI + c2] = a1 + bv;
      fscsh[((long)d * kB + 2) * 2 * kI + c2] = a2 + bv;
      fscsh[((long)d * kB + 3) * 2 * kI + c2] = a3 + bv;
    }
  }
}

// ---------------- LayerNorm (+optional AdaLN modulation + mask) ----------------
// one wave per row; grid = kBN/4, block 256.
__global__ __launch_bounds__(256) void k_ln(
    const float* __restrict__ x, const void* __restrict__ g,
    const float* __restrict__ scsh, const void* __restrict__ seqm,
    float* __restrict__ xn, int d, int domod, const int* __restrict__ flag) {
  const int isb = *flag;
  const int wid = threadIdx.x >> 6, lane = threadIdx.x & 63;
  const int row = blockIdx.x * 4 + wid;
  const int b = row >> 10;
  const float* xr = x + (long)row * kD;
  float v[8];
  float s = 0.f, s2 = 0.f;
  #pragma unroll
  for (int i = 0; i < 8; i++) {
    float tv = xr[lane + i * 64];
    v[i] = tv; s += tv; s2 += tv * tv;
  }
  #pragma unroll
  for (int off = 1; off < 64; off <<= 1) { s += __shfl_xor(s, off); s2 += __shfl_xor(s2, off); }
  const float mean = s * (1.f / kD);
  const float var = fmaxf(s2 * (1.f / kD) - mean * mean, 0.f);
  const float rstd = rsqrtf(var + 1e-5f);
  float mk = 1.f;
  if (domod) mk = ldin(seqm, row, isb);
  #pragma unroll
  for (int i = 0; i < 8; i++) {
    const int cc = lane + i * 64;
    float y = (v[i] - mean) * rstd * ldin(g, (long)d * kD + cc, isb);
    if (domod)
      y = (y * (scsh[(long)b * 2 * kD + cc] + 1.f) + scsh[(long)b * 2 * kD + kD + cc]) * mk;
    xn[(long)row * kD + cc] = y;
  }
}

// ---------------- fp32 tiled GEMM, 64x64 tile, BK=16, 4x4/thread ----------------
// EPI: 0 = C = acc*fscale (q)            1 = C = acc (kv)
//      2 = C += acc*mask (out-proj)      3 = C = silu(acc+b)*(sc+1)+sh (ff_in)
//      4 = C = (C + acc + b)*mask (ff_out)
template <int EPI>
__global__ __launch_bounds__(256) void k_gemm(
    const float* __restrict__ A, const void* __restrict__ W, long woff,
    int K, int Nc, float* __restrict__ C,
    const void* __restrict__ bias, long boff,
    const float* __restrict__ scsh, const void* __restrict__ seqm,
    float fscale, const int* __restrict__ flag) {
  const int isb = *flag;
  __shared__ float As[16][68];
  __shared__ float Bs[16][68];
  const int t = threadIdx.x;
  const int tx = t & 15, ty = t >> 4;
  const int n0 = blockIdx.x * 64, m0 = blockIdx.y * 64;
  float acc[4][4] = {};
  for (int k0 = 0; k0 < K; k0 += 16) {
    #pragma unroll
    for (int i = 0; i < 4; i++) {
      int idx = t + i * 256;
      int m = idx >> 4, kk = idx & 15;
      As[kk][m] = A[(long)(m0 + m) * K + k0 + kk];
    }
    #pragma unroll
    for (int i = 0; i < 4; i++) {
      int idx = t + i * 256;
      int kk = idx >> 6, n = idx & 63;
      Bs[kk][n] = ldin(W, woff + (long)(k0 + kk) * Nc + n0 + n, isb);
    }
    __syncthreads();
    #pragma unroll
    for (int kk = 0; kk < 16; kk++) {
      const float4 a = *(const float4*)&As[kk][ty * 4];
      const float4 bv = *(const float4*)&Bs[kk][tx * 4];
      acc[0][0] += a.x * bv.x; acc[0][1] += a.x * bv.y; acc[0][2] += a.x * bv.z; acc[0][3] += a.x * bv.w;
      acc[1][0] += a.y * bv.x; acc[1][1] += a.y * bv.y; acc[1][2] += a.y * bv.z; acc[1][3] += a.y * bv.w;
      acc[2][0] += a.z * bv.x; acc[2][1] += a.z * bv.y; acc[2][2] += a.z * bv.z; acc[2][3] += a.z * bv.w;
      acc[3][0] += a.w * bv.x; acc[3][1] += a.w * bv.y; acc[3][2] += a.w * bv.z; acc[3][3] += a.w * bv.w;
    }
    __syncthreads();
  }
  #pragma unroll
  for (int i = 0; i < 4; i++) {
    const int r = m0 + ty * 4 + i;
    const int bb = r >> 10;
    (void)bb;
    float mk = 1.f;
    if constexpr (EPI == 2 || EPI == 4) mk = ldin(seqm, r, isb);
    #pragma unroll
    for (int j = 0; j < 4; j++) {
      const int cc = n0 + tx * 4 + j;
      const long off = (long)r * Nc + cc;
      float v = acc[i][j];
      if constexpr (EPI == 0) {
        C[off] = v * fscale;
      } else if constexpr (EPI == 1) {
        C[off] = v;
      } else if constexpr (EPI == 2) {
        C[off] += v * mk;
      } else if constexpr (EPI == 3) {
        v += ldin(bias, boff + cc, isb);
        v = v / (1.f + __expf(-v));
        const float scv = scsh[(long)bb * 2 * kI + cc];
        const float shv = scsh[(long)bb * 2 * kI + kI + cc];
        C[off] = v * (scv + 1.f) + shv;
      } else {
        v += ldin(bias, boff + cc, isb);
        C[off] = (C[off] + v) * mk;
      }
    }
  }
}

// ---------------- attention (flash-style, 32 q-rows/block) ----------------
// grid: (N/32, H, B); block 256. thread t owns row r=t>>3 (32 rows, 8 thr/row),
// out cols (t&7)*8..+8; scores: 4 j-cols per thread per 32-wide j-tile.
__global__ __launch_bounds__(256) void k_attn(
    const float* __restrict__ q, const float* __restrict__ kv, float* __restrict__ ao,
    const void* __restrict__ rpw, const void* __restrict__ rpb,
    const void* __restrict__ seqm, const int* __restrict__ ridx,
    const int* __restrict__ flag) {
  const int isb = *flag;
  const int t = threadIdx.x;
  const int i0 = blockIdx.x * 32;
  const int h = blockIdx.y;
  const int b = blockIdx.z;
  __shared__ float Q[32][72], Kt[32][72], Vt[32][72], P[32][36];
  __shared__ float biasw[kRel];
  __shared__ int riq[32], rik[32];
  __shared__ float mkq[32], mkk[32];

  if (t < kRel) biasw[t] = ldin(rpw, (long)t * kH + h, isb) + ldin(rpb, h, isb);
  for (int idx = t; idx < 32 * 64; idx += 256) {
    int rr = idx >> 6, cc = idx & 63;
    Q[rr][cc] = q[((long)(b * kN + i0 + rr)) * kHid + h * kDh + cc];
  }
  if (t < 32) { riq[t] = ridx[b * kN + i0 + t]; mkq[t] = ldin(seqm, b * kN + i0 + t, isb); }
  __syncthreads();

  const int r = t >> 3, c = t & 7;
  const int j1 = c * 4;
  float m_run = -1e30f, l_run = 0.f;
  float o[8] = {0, 0, 0, 0, 0, 0, 0, 0};

  for (int j0 = 0; j0 < kN; j0 += 32) {
    for (int idx = t; idx < 32 * 64; idx += 256) {
      int rr = idx >> 6, cc = idx & 63;
      long base = ((long)(b * kN + j0 + rr)) * (2 * kHid) + h * kDh + cc;
      Kt[rr][cc] = kv[base];
      Vt[rr][cc] = kv[base + kHid];
    }
    if (t < 32) { rik[t] = ridx[b * kN + j0 + t]; mkk[t] = ldin(seqm, b * kN + j0 + t, isb); }
    __syncthreads();

    float sv[4] = {0.f, 0.f, 0.f, 0.f};
    #pragma unroll
    for (int d4 = 0; d4 < 16; d4++) {
      const float4 qv = *(const float4*)&Q[r][d4 * 4];
      const float4 ka = *(const float4*)&Kt[j1 + 0][d4 * 4];
      const float4 kb = *(const float4*)&Kt[j1 + 1][d4 * 4];
      const float4 kc = *(const float4*)&Kt[j1 + 2][d4 * 4];
      const float4 kd = *(const float4*)&Kt[j1 + 3][d4 * 4];
      sv[0] += qv.x * ka.x + qv.y * ka.y + qv.z * ka.z + qv.w * ka.w;
      sv[1] += qv.x * kb.x + qv.y * kb.y + qv.z * kb.z + qv.w * kb.w;
      sv[2] += qv.x * kc.x + qv.y * kc.y + qv.z * kc.z + qv.w * kc.w;
      sv[3] += qv.x * kd.x + qv.y * kd.y + qv.z * kd.z + qv.w * kd.w;
    }
    const float mq = mkq[r];
    const int rq = riq[r];
    #pragma unroll
    for (int u = 0; u < 4; u++) {
      int di = rq - rik[j1 + u];
      di = di < -32 ? -32 : (di > 32 ? 32 : di);
      const float pm = mq * mkk[j1 + u];
      sv[u] += biasw[di + 32] - (1.f - pm) * 1e6f;
    }
    float mx = fmaxf(fmaxf(sv[0], sv[1]), fmaxf(sv[2], sv[3]));
    mx = fmaxf(mx, __shfl_xor(mx, 1));
    mx = fmaxf(mx, __shfl_xor(mx, 2));
    mx = fmaxf(mx, __shfl_xor(mx, 4));
    const float m_new = fmaxf(m_run, mx);
    const float rescale = __expf(m_run - m_new);
    float ps = 0.f;
    #pragma unroll
    for (int u = 0; u < 4; u++) {
      const float p = __expf(sv[u] - m_new);
      P[r][j1 + u] = p;
      ps += p;
    }
    ps += __shfl_xor(ps, 1); ps += __shfl_xor(ps, 2); ps += __shfl_xor(ps, 4);
    l_run = l_run * rescale + ps;
    m_run = m_new;
    #pragma unroll
    for (int u = 0; u < 8; u++) o[u] *= rescale;
    __syncthreads(); // P visible
    #pragma unroll 4
    for (int jj = 0; jj < 32; jj++) {
      const float p = P[r][jj];
      const float4 v0 = *(const float4*)&Vt[jj][c * 8];
      const float4 v1 = *(const float4*)&Vt[jj][c * 8 + 4];
      o[0] += p * v0.x; o[1] += p * v0.y; o[2] += p * v0.z; o[3] += p * v0.w;
      o[4] += p * v1.x; o[5] += p * v1.y; o[6] += p * v1.z; o[7] += p * v1.w;
    }
    __syncthreads(); // done with Kt/Vt/P before next stage
  }
  const float inv = 1.f / l_run;
  const long base = ((long)(b * kN + i0 + r)) * kHid + h * kDh + c * 8;
  #pragma unroll
  for (int u = 0; u < 8; u++) ao[base + u] = o[u] * inv;
}

// ---------------- write out (dual dtype) ----------------
__global__ void k_out(const float* __restrict__ x, void* __restrict__ out,
                      const int* __restrict__ flag) {
  const int i = blockIdx.x * 256 + threadIdx.x;
  if (*flag) ((__hip_bfloat16*)out)[i] = __float2bfloat16(x[i]);
  else ((float*)out)[i] = x[i];
}

extern "C" void kernel_launch(void* const* d_in, const int* in_sizes, int n_in,
                              void* d_out, int out_size, void* d_ws, size_t ws_size,
                              hipStream_t stream) {
  const void* xin  = d_in[0];
  const void* timein = d_in[1];
  const void* seqm = d_in[2];
  const int*  ridx = (const int*)d_in[3];
  const void* rpw  = d_in[4];
  const void* rpb  = d_in[5];
  const void* ang  = d_in[6];
  const void* atw  = d_in[7];
  const void* atb  = d_in[8];
  const void* wq   = d_in[9];
  const void* wkv  = d_in[10];
  const void* wo   = d_in[11];
  const void* fng  = d_in[12];
  const void* ftw  = d_in[13];
  const void* ftb  = d_in[14];
  const void* wfi  = d_in[15];
  const void* bfi  = d_in[16];
  const void* wfo  = d_in[17];
  const void* bfo  = d_in[18];

  float* ws = (float*)d_ws;
  float* x    = ws;                       // 2,097,152
  float* xn   = ws + 2097152;             // 2,097,152
  float* big  = ws + 4194304;             // 8,388,608 (q|kv|ao, aliased by h)
  float* q    = big;                      // 2,097,152
  float* kv   = big + 2097152;            // 4,194,304
  float* ao   = big + 6291456;            // 2,097,152
  float* h    = big;                      // aliases q/kv/ao (ff phase only)
  float* tact = ws + 12582912;            // 2,048
  float* ascsh = ws + 12584960;           // 16,384  [DEPTH][B][2*kD]
  float* fscsh = ws + 12601344;           // 65,536  [DEPTH][B][2*kI]
  int* flag   = (int*)(ws + 12666880);

  k_detect<<<1, 64, 0, stream>>>(xin, flag);
  k_tact<<<8, 256, 0, stream>>>(timein, tact, flag);
  k_xinit<<<kBN * kD / 256, 256, 0, stream>>>(xin, seqm, x, flag);
  k_timeproj<<<dim3(20, kDepth), 256, 0, stream>>>(tact, atw, atb, ftw, ftb, ascsh, fscsh, flag);

  for (int d = 0; d < kDepth; ++d) {
    // attn pre-LN with AdaLN mod
    k_ln<<<kBN / 4, 256, 0, stream>>>(x, ang, ascsh + (long)d * kB * 2 * kD, seqm, xn, d, 1, flag);
    // q = (xn @ Wq) * SCALE
    k_gemm<0><<<dim3(kHid / 64, kBN / 64), 256, 0, stream>>>(
        xn, wq, (long)d * kD * kHid, kD, kHid, q, nullptr, 0, nullptr, nullptr, 0.125f, flag);
    // kv = x @ Wkv
    k_gemm<1><<<dim3(2 * kHid / 64, kBN / 64), 256, 0, stream>>>(
        x, wkv, (long)d * kD * 2 * kHid, kD, 2 * kHid, kv, nullptr, 0, nullptr, nullptr, 1.f, flag);
    // attention
    k_attn<<<dim3(kN / 32, kH, kB), 256, 0, stream>>>(q, kv, ao, rpw, rpb, seqm, ridx, flag);
    // x += (ao @ Wo) * mask
    k_gemm<2><<<dim3(kD / 64, kBN / 64), 256, 0, stream>>>(
        ao, wo, (long)d * kHid * kD, kHid, kD, x, nullptr, 0, nullptr, seqm, 1.f, flag);
    // ff pre-LN (no mod)
    k_ln<<<kBN / 4, 256, 0, stream>>>(x, fng, nullptr, seqm, xn, d, 0, flag);
    // h = silu(xn @ Wfi + b)*(sc+1)+sh
    k_gemm<3><<<dim3(kI / 64, kBN / 64), 256, 0, stream>>>(
        xn, wfi, (long)d * kD * kI, kD, kI, h, bfi, (long)d * kI,
        fscsh + (long)d * kB * 2 * kI, nullptr, 1.f, flag);
    // x = (x + h @ Wfo + b)*mask
    k_gemm<4><<<dim3(kD / 64, kBN / 64), 256, 0, stream>>>(
        h, wfo, (long)d * kI * kD, kI, kD, x, bfo, (long)d * kD, nullptr, seqm, 1.f, flag);
  }
  k_out<<<kBN * kD / 256, 256, 0, stream>>>(x, d_out, flag);
}

// Round 3
// 1659.640 us; speedup vs baseline: 2.7805x; 2.7805x over previous
//
#include <hip/hip_runtime.h>
#include <hip/hip_bf16.h>

// Problem constants
constexpr int kB = 4, kN = 1024, kD = 512, kH = 8, kDh = 64, kT = 512;
constexpr int kHid = 512, kI = 2048, kRel = 65, kDepth = 4;
constexpr int kBN = kB * kN;

typedef short s16x8 __attribute__((ext_vector_type(8)));
typedef float f32x4 __attribute__((ext_vector_type(4)));

// ---------------- dual-dtype load helper ----------------
__device__ __forceinline__ float ldin(const void* p, long i, int isb) {
  if (isb) return __bfloat162float(((const __hip_bfloat16*)p)[i]);
  return ((const float*)p)[i];
}

__device__ __forceinline__ unsigned short bfbits(float v) {
  __hip_bfloat16 h = __float2bfloat16(v);
  return *(unsigned short*)&h;
}

// async global->LDS, 16B per lane. LDS dest must be wave-uniform base.
__device__ __forceinline__ void gload16(const void* g, void* l) {
  __builtin_amdgcn_global_load_lds(
      (const __attribute__((address_space(1))) unsigned int*)g,
      (__attribute__((address_space(3))) unsigned int*)l, 16, 0, 0);
}

// ---------------- dtype detect ----------------
__global__ void k_detect(const void* __restrict__ x, int* __restrict__ flag) {
  const unsigned int* u = (const unsigned int*)x;
  unsigned int v = u[threadIdx.x];
  int e = (v >> 7) & 0xFF;
  int good = (e >= 100 && e <= 140) ? 1 : 0;
  unsigned long long m = __ballot(good);
  if (threadIdx.x == 0) flag[0] = (__popcll(m) >= 48) ? 1 : 0;
}

// ---------------- t_act = silu(time) ----------------
__global__ void k_tact(const void* __restrict__ timein, float* __restrict__ tact,
                       const int* __restrict__ flag) {
  const int isb = *flag;
  int i = blockIdx.x * 256 + threadIdx.x;
  if (i < kB * kT) {
    float v = ldin(timein, i, isb);
    tact[i] = v / (1.f + __expf(-v));
  }
}

// ---------------- x = x_in * mask (fp32 + bf16 copies) ----------------
__global__ void k_xinit(const void* __restrict__ xin, const void* __restrict__ seqm,
                        float* __restrict__ x, __hip_bfloat16* __restrict__ xb,
                        const int* __restrict__ flag) {
  const int isb = *flag;
  const long base = ((long)blockIdx.x * 256 + threadIdx.x) * 8;
  const int row = (int)(base >> 9);
  const float mk = ldin(seqm, row, isb);
  __align__(16) unsigned short pk[8];
  #pragma unroll
  for (int j = 0; j < 8; j++) {
    float v = ldin(xin, base + j, isb) * mk;
    x[base + j] = v;
    pk[j] = bfbits(v);
  }
  *(uint4*)(xb + base) = *(const uint4*)pk;
}

// ---------------- weight transpose-convert: W[d][K][N] -> Wt[d][N][K] bf16 ----
__global__ __launch_bounds__(256) void k_wt(const void* __restrict__ W,
                                            __hip_bfloat16* __restrict__ Wt,
                                            int K, int N, const int* __restrict__ flag) {
  const int isb = *flag;
  __shared__ float T[64][65];
  const int t = threadIdx.x;
  const int cn = t & 63, r4 = t >> 6;
  const int n0 = blockIdx.x * 64, k0 = blockIdx.y * 64;
  const long ibase = (long)blockIdx.z * K * N;
  const long obase = (long)blockIdx.z * N * K;
  for (int rr = r4; rr < 64; rr += 4)
    T[rr][cn] = ldin(W, ibase + (long)(k0 + rr) * N + n0 + cn, isb);
  __syncthreads();
  for (int nn = r4; nn < 64; nn += 4)
    Wt[obase + (long)(n0 + nn) * K + k0 + cn] = __float2bfloat16(T[cn][nn]);
}

// ---------------- time projections for all layers ----------------
__global__ __launch_bounds__(256) void k_timeproj(
    const float* __restrict__ tact,
    const void* __restrict__ atw, const void* __restrict__ atb,
    const void* __restrict__ ftw, const void* __restrict__ ftb,
    float* __restrict__ ascsh, float* __restrict__ fscsh,
    const int* __restrict__ flag) {
  const int isb = *flag;
  __shared__ float T[kB * kT];
  const int d = blockIdx.y;
  for (int i = threadIdx.x; i < kB * kT; i += 256) T[i] = tact[i];
  __syncthreads();
  const int c = blockIdx.x * 256 + threadIdx.x;
  float a0 = 0, a1 = 0, a2 = 0, a3 = 0;
  if (c < 2 * kD) {
    const long wo = (long)d * kT * 2 * kD + c;
    #pragma unroll 4
    for (int tt = 0; tt < kT; tt++) {
      const float w = ldin(atw, wo + (long)tt * 2 * kD, isb);
      a0 += T[0 * kT + tt] * w; a1 += T[1 * kT + tt] * w;
      a2 += T[2 * kT + tt] * w; a3 += T[3 * kT + tt] * w;
    }
    const float bv = ldin(atb, (long)d * 2 * kD + c, isb);
    ascsh[((long)d * kB + 0) * 2 * kD + c] = a0 + bv;
    ascsh[((long)d * kB + 1) * 2 * kD + c] = a1 + bv;
    ascsh[((long)d * kB + 2) * 2 * kD + c] = a2 + bv;
    ascsh[((long)d * kB + 3) * 2 * kD + c] = a3 + bv;
  } else {
    const int c2 = c - 2 * kD;
    if (c2 < 2 * kI) {
      const long wo = (long)d * kT * 2 * kI + c2;
      #pragma unroll 4
      for (int tt = 0; tt < kT; tt++) {
        const float w = ldin(ftw, wo + (long)tt * 2 * kI, isb);
        a0 += T[0 * kT + tt] * w; a1 += T[1 * kT + tt] * w;
        a2 += T[2 * kT + tt] * w; a3 += T[3 * kT + tt] * w;
      }
      const float bv = ldin(ftb, (long)d * 2 * kI + c2, isb);
      fscsh[((long)d * kB + 0) * 2 * kI + c2] = a0 + bv;
      fscsh[((long)d * kB + 1) * 2 * kI + c2] = a1 + bv;
      fscsh[((long)d * kB + 2) * 2 * kI + c2] = a2 + bv;
      fscsh[((long)d * kB + 3) * 2 * kI + c2] = a3 + bv;
    }
  }
}

// ---------------- LayerNorm -> bf16 out (+optional AdaLN mod + mask) --------
__global__ __launch_bounds__(256) void k_ln(
    const float* __restrict__ x, const void* __restrict__ g,
    const float* __restrict__ scsh, const void* __restrict__ seqm,
    __hip_bfloat16* __restrict__ xnb, int d, int domod, const int* __restrict__ flag) {
  const int isb = *flag;
  const int wid = threadIdx.x >> 6, lane = threadIdx.x & 63;
  const int row = blockIdx.x * 4 + wid;
  const int b = row >> 10;
  const float* xr = x + (long)row * kD + lane * 8;
  const float4 v0 = *(const float4*)xr;
  const float4 v1 = *(const float4*)(xr + 4);
  float v[8] = {v0.x, v0.y, v0.z, v0.w, v1.x, v1.y, v1.z, v1.w};
  float s = 0.f, s2 = 0.f;
  #pragma unroll
  for (int i = 0; i < 8; i++) { s += v[i]; s2 += v[i] * v[i]; }
  #pragma unroll
  for (int off = 1; off < 64; off <<= 1) { s += __shfl_xor(s, off); s2 += __shfl_xor(s2, off); }
  const float mean = s * (1.f / kD);
  const float var = fmaxf(s2 * (1.f / kD) - mean * mean, 0.f);
  const float rstd = rsqrtf(var + 1e-5f);
  float mk = 1.f;
  if (domod) mk = ldin(seqm, row, isb);
  __align__(16) unsigned short pk[8];
  #pragma unroll
  for (int i = 0; i < 8; i++) {
    const int cc = lane * 8 + i;
    float y = (v[i] - mean) * rstd * ldin(g, (long)d * kD + cc, isb);
    if (domod)
      y = (y * (scsh[(long)b * 2 * kD + cc] + 1.f) + scsh[(long)b * 2 * kD + kD + cc]) * mk;
    pk[i] = bfbits(y);
  }
  *(uint4*)(xnb + (long)row * kD + lane * 8) = *(const uint4*)pk;
}

// ---------------- bf16 MFMA GEMM: C[M,Nc] = A[M,K] @ Wt[Nc,K]^T --------------
// BM=64, BN=128, BK=32; 4 waves (2m x 2n); wave = 32x64 = 2x4 frags of 16x16.
// EPI: 0 q: Cf=acc*fscale   1 kv: Cf=acc          2 out: X+=acc*mask
//      3 ffin: Cb=bf16(silu(acc+b)*(sc+1)+sh)     4 ffout: X=(X+acc+b)*mask, Xb=bf16(X)
template <int EPI>
__global__ __launch_bounds__(256) void k_mgemm(
    const __hip_bfloat16* __restrict__ A, const __hip_bfloat16* __restrict__ Wt,
    long woff, int K, int Nc,
    float* __restrict__ Cf, __hip_bfloat16* __restrict__ Cb,
    float* __restrict__ X, __hip_bfloat16* __restrict__ Xb,
    const void* __restrict__ bias, long boff,
    const float* __restrict__ scsh, const void* __restrict__ seqm,
    float fscale, const int* __restrict__ flag) {
  const int isb = *flag;
  __shared__ __align__(16) short As[64 * 32];
  __shared__ __align__(16) short Bs[128 * 32];
  const int t = threadIdx.x;
  const int l = t & 63, wid = t >> 6;
  const int wm = wid & 1, wn = wid >> 1;
  const int lr = l >> 4, lc = l & 15;
  const int m0 = blockIdx.y * 64, n0 = blockIdx.x * 128;

  f32x4 acc[2][4] = {};

  const __hip_bfloat16* gA = A + (long)(m0 + (t >> 2)) * K + ((t & 3) << 3);
  const __hip_bfloat16* gB = Wt + woff + (long)(n0 + (t >> 2)) * K + ((t & 3) << 3);
  const __hip_bfloat16* gB2 = gB + (long)64 * K;
  short* ldsA = As + (wid << 9);
  short* ldsB0 = Bs + (wid << 9);
  short* ldsB1 = Bs + 2048 + (wid << 9);

  for (int k0 = 0; k0 < K; k0 += 32) {
    gload16(gA + k0, ldsA);
    gload16(gB + k0, ldsB0);
    gload16(gB2 + k0, ldsB1);
    __syncthreads();  // drains vmcnt before barrier (compiler-inserted)
    s16x8 af[2], bf[4];
    #pragma unroll
    for (int fm = 0; fm < 2; fm++)
      af[fm] = *(const s16x8*)&As[(wm * 32 + fm * 16 + lc) * 32 + lr * 8];
    #pragma unroll
    for (int fn = 0; fn < 4; fn++)
      bf[fn] = *(const s16x8*)&Bs[(wn * 64 + fn * 16 + lc) * 32 + lr * 8];
    #pragma unroll
    for (int fm = 0; fm < 2; fm++)
      #pragma unroll
      for (int fn = 0; fn < 4; fn++)
        acc[fm][fn] = __builtin_amdgcn_mfma_f32_16x16x32_bf16(af[fm], bf[fn], acc[fm][fn], 0, 0, 0);
    __syncthreads();
  }

  #pragma unroll
  for (int fm = 0; fm < 2; fm++) {
    #pragma unroll
    for (int j = 0; j < 4; j++) {
      const int r = m0 + wm * 32 + fm * 16 + lr * 4 + j;
      const int bb = r >> 10;
      float mk = 1.f;
      if constexpr (EPI == 2 || EPI == 4) mk = ldin(seqm, r, isb);
      #pragma unroll
      for (int fn = 0; fn < 4; fn++) {
        const int cc = n0 + wn * 64 + fn * 16 + lc;
        const long off = (long)r * Nc + cc;
        float v = acc[fm][fn][j];
        if constexpr (EPI == 0) {
          Cf[off] = v * fscale;
        } else if constexpr (EPI == 1) {
          Cf[off] = v;
        } else if constexpr (EPI == 2) {
          X[off] += v * mk;
        } else if constexpr (EPI == 3) {
          v += ldin(bias, boff + cc, isb);
          v = v / (1.f + __expf(-v));
          v = v * (scsh[(long)bb * 2 * kI + cc] + 1.f) + scsh[(long)bb * 2 * kI + kI + cc];
          Cb[off] = __float2bfloat16(v);
        } else {
          v += ldin(bias, boff + cc, isb);
          const float nx = (X[off] + v) * mk;
          X[off] = nx;
          Xb[off] = __float2bfloat16(nx);
        }
      }
    }
  }
}

// ---------------- attention (flash-style, 32 q-rows/block) ----------------
// thread t: row r=t>>3, c=t&7; scores j = c + 8u (2-way LDS conflict max).
__global__ __launch_bounds__(256) void k_attn(
    const float* __restrict__ q, const float* __restrict__ kv,
    __hip_bfloat16* __restrict__ aob,
    const void* __restrict__ rpw, const void* __restrict__ rpb,
    const void* __restrict__ seqm, const int* __restrict__ ridx,
    const int* __restrict__ flag) {
  const int isb = *flag;
  const int t = threadIdx.x;
  const int i0 = blockIdx.x * 32;
  const int h = blockIdx.y;
  const int b = blockIdx.z;
  __shared__ float Q[32][72], Kt[32][72], Vt[32][72], P[32][36];
  __shared__ float biasw[kRel];
  __shared__ int riq[32], rik[32];
  __shared__ float mkq[32], mkk[32];

  if (t < kRel) biasw[t] = ldin(rpw, (long)t * kH + h, isb) + ldin(rpb, h, isb);
  for (int idx = t; idx < 32 * 64; idx += 256) {
    int rr = idx >> 6, cc = idx & 63;
    Q[rr][cc] = q[((long)(b * kN + i0 + rr)) * kHid + h * kDh + cc];
  }
  if (t < 32) { riq[t] = ridx[b * kN + i0 + t]; mkq[t] = ldin(seqm, b * kN + i0 + t, isb); }
  __syncthreads();

  const int r = t >> 3, c = t & 7;
  float m_run = -1e30f, l_run = 0.f;
  float o[8] = {0, 0, 0, 0, 0, 0, 0, 0};

  for (int j0 = 0; j0 < kN; j0 += 32) {
    for (int idx = t; idx < 32 * 64; idx += 256) {
      int rr = idx >> 6, cc = idx & 63;
      long base = ((long)(b * kN + j0 + rr)) * (2 * kHid) + h * kDh + cc;
      Kt[rr][cc] = kv[base];
      Vt[rr][cc] = kv[base + kHid];
    }
    if (t < 32) { rik[t] = ridx[b * kN + j0 + t]; mkk[t] = ldin(seqm, b * kN + j0 + t, isb); }
    __syncthreads();

    float sv[4] = {0.f, 0.f, 0.f, 0.f};
    #pragma unroll
    for (int d4 = 0; d4 < 16; d4++) {
      const float4 qv = *(const float4*)&Q[r][d4 * 4];
      const float4 ka = *(const float4*)&Kt[c][d4 * 4];
      const float4 kb = *(const float4*)&Kt[c + 8][d4 * 4];
      const float4 kc = *(const float4*)&Kt[c + 16][d4 * 4];
      const float4 kd = *(const float4*)&Kt[c + 24][d4 * 4];
      sv[0] += qv.x * ka.x + qv.y * ka.y + qv.z * ka.z + qv.w * ka.w;
      sv[1] += qv.x * kb.x + qv.y * kb.y + qv.z * kb.z + qv.w * kb.w;
      sv[2] += qv.x * kc.x + qv.y * kc.y + qv.z * kc.z + qv.w * kc.w;
      sv[3] += qv.x * kd.x + qv.y * kd.y + qv.z * kd.z + qv.w * kd.w;
    }
    const float mq = mkq[r];
    const int rq = riq[r];
    #pragma unroll
    for (int u = 0; u < 4; u++) {
      const int jj = c + 8 * u;
      int di = rq - rik[jj];
      di = di < -32 ? -32 : (di > 32 ? 32 : di);
      const float pm = mq * mkk[jj];
      sv[u] += biasw[di + 32] - (1.f - pm) * 1e6f;
    }
    float mx = fmaxf(fmaxf(sv[0], sv[1]), fmaxf(sv[2], sv[3]));
    mx = fmaxf(mx, __shfl_xor(mx, 1));
    mx = fmaxf(mx, __shfl_xor(mx, 2));
    mx = fmaxf(mx, __shfl_xor(mx, 4));
    const float m_new = fmaxf(m_run, mx);
    const float rescale = __expf(m_run - m_new);
    float ps = 0.f;
    #pragma unroll
    for (int u = 0; u < 4; u++) {
      const float p = __expf(sv[u] - m_new);
      P[r][c + 8 * u] = p;
      ps += p;
    }
    ps += __shfl_xor(ps, 1); ps += __shfl_xor(ps, 2); ps += __shfl_xor(ps, 4);
    l_run = l_run * rescale + ps;
    m_run = m_new;
    #pragma unroll
    for (int u = 0; u < 8; u++) o[u] *= rescale;
    // P[r][*] is produced and consumed by the same wave: no barrier needed.
    #pragma unroll 4
    for (int jj = 0; jj < 32; jj++) {
      const float p = P[r][jj];
      const float4 v0 = *(const float4*)&Vt[jj][c * 8];
      const float4 v1 = *(const float4*)&Vt[jj][c * 8 + 4];
      o[0] += p * v0.x; o[1] += p * v0.y; o[2] += p * v0.z; o[3] += p * v0.w;
      o[4] += p * v1.x; o[5] += p * v1.y; o[6] += p * v1.z; o[7] += p * v1.w;
    }
    __syncthreads(); // done with Kt/Vt before next stage
  }
  const float inv = 1.f / l_run;
  const long base = ((long)(b * kN + i0 + r)) * kHid + h * kDh + c * 8;
  __align__(16) unsigned short pk[8];
  #pragma unroll
  for (int u = 0; u < 8; u++) pk[u] = bfbits(o[u] * inv);
  *(uint4*)(aob + base) = *(const uint4*)pk;
}

// ---------------- write out (dual dtype) ----------------
__global__ void k_out(const float* __restrict__ x, void* __restrict__ out,
                      const int* __restrict__ flag) {
  const int i = blockIdx.x * 256 + threadIdx.x;
  if (*flag) ((__hip_bfloat16*)out)[i] = __float2bfloat16(x[i]);
  else ((float*)out)[i] = x[i];
}

extern "C" void kernel_launch(void* const* d_in, const int* in_sizes, int n_in,
                              void* d_out, int out_size, void* d_ws, size_t ws_size,
                              hipStream_t stream) {
  const void* xin  = d_in[0];
  const void* timein = d_in[1];
  const void* seqm = d_in[2];
  const int*  ridx = (const int*)d_in[3];
  const void* rpw  = d_in[4];
  const void* rpb  = d_in[5];
  const void* ang  = d_in[6];
  const void* atw  = d_in[7];
  const void* atb  = d_in[8];
  const void* wq   = d_in[9];
  const void* wkv  = d_in[10];
  const void* wo   = d_in[11];
  const void* fng  = d_in[12];
  const void* ftw  = d_in[13];
  const void* ftb  = d_in[14];
  const void* wfi  = d_in[15];
  const void* bfi  = d_in[16];
  const void* wfo  = d_in[17];
  const void* bfo  = d_in[18];

  float* ws = (float*)d_ws;
  float* x     = ws;                 // 2,097,152 f32
  float* q     = ws + 2097152;       // 2,097,152 f32
  float* kv    = ws + 4194304;       // 4,194,304 f32
  float* tact  = ws + 8388608;       // 2,048
  float* ascsh = ws + 8390656;       // 16,384  [D][B][2*kD]
  float* fscsh = ws + 8407040;       // 65,536  [D][B][2*kI]
  int*   flag  = (int*)(ws + 8472576);
  __hip_bfloat16* bfb = (__hip_bfloat16*)(ws + 8472640);
  __hip_bfloat16* xnb  = bfb;             // 2,097,152
  __hip_bfloat16* xb   = bfb + 2097152;   // 2,097,152
  __hip_bfloat16* aob  = bfb + 4194304;   // 2,097,152
  __hip_bfloat16* hb   = bfb + 6291456;   // 8,388,608
  __hip_bfloat16* wtq  = bfb + 14680064;  // 1,048,576 [D][512][512]
  __hip_bfloat16* wtkv = bfb + 15728640;  // 2,097,152 [D][1024][512]
  __hip_bfloat16* wto  = bfb + 17825792;  // 1,048,576 [D][512][512]
  __hip_bfloat16* wtfi = bfb + 18874368;  // 4,194,304 [D][2048][512]
  __hip_bfloat16* wtfo = bfb + 23068672;  // 4,194,304 [D][512][2048]

  k_detect<<<1, 64, 0, stream>>>(xin, flag);
  k_tact<<<8, 256, 0, stream>>>(timein, tact, flag);
  k_xinit<<<kBN * kD / 2048, 256, 0, stream>>>(xin, seqm, x, xb, flag);
  k_timeproj<<<dim3(20, kDepth), 256, 0, stream>>>(tact, atw, atb, ftw, ftb, ascsh, fscsh, flag);
  k_wt<<<dim3(8, 8, kDepth), 256, 0, stream>>>(wq, wtq, kD, kHid, flag);
  k_wt<<<dim3(16, 8, kDepth), 256, 0, stream>>>(wkv, wtkv, kD, 2 * kHid, flag);
  k_wt<<<dim3(8, 8, kDepth), 256, 0, stream>>>(wo, wto, kHid, kD, flag);
  k_wt<<<dim3(32, 8, kDepth), 256, 0, stream>>>(wfi, wtfi, kD, kI, flag);
  k_wt<<<dim3(8, 32, kDepth), 256, 0, stream>>>(wfo, wtfo, kI, kD, flag);

  for (int d = 0; d < kDepth; ++d) {
    k_ln<<<kBN / 4, 256, 0, stream>>>(x, ang, ascsh + (long)d * kB * 2 * kD, seqm, xnb, d, 1, flag);
    // q = (xn @ Wq) * SCALE
    k_mgemm<0><<<dim3(kHid / 128, kBN / 64), 256, 0, stream>>>(
        xnb, wtq, (long)d * kD * kHid, kD, kHid, q, nullptr, nullptr, nullptr,
        nullptr, 0, nullptr, nullptr, 0.125f, flag);
    // kv = x @ Wkv
    k_mgemm<1><<<dim3(2 * kHid / 128, kBN / 64), 256, 0, stream>>>(
        xb, wtkv, (long)d * kD * 2 * kHid, kD, 2 * kHid, kv, nullptr, nullptr, nullptr,
        nullptr, 0, nullptr, nullptr, 1.f, flag);
    k_attn<<<dim3(kN / 32, kH, kB), 256, 0, stream>>>(q, kv, aob, rpw, rpb, seqm, ridx, flag);
    // x += (ao @ Wo) * mask
    k_mgemm<2><<<dim3(kD / 128, kBN / 64), 256, 0, stream>>>(
        aob, wto, (long)d * kHid * kD, kHid, kD, nullptr, nullptr, x, nullptr,
        nullptr, 0, nullptr, seqm, 1.f, flag);
    k_ln<<<kBN / 4, 256, 0, stream>>>(x, fng, nullptr, seqm, xnb, d, 0, flag);
    // h = silu(xn @ Wfi + b)*(sc+1)+sh
    k_mgemm<3><<<dim3(kI / 128, kBN / 64), 256, 0, stream>>>(
        xnb, wtfi, (long)d * kD * kI, kD, kI, nullptr, hb, nullptr, nullptr,
        bfi, (long)d * kI, fscsh + (long)d * kB * 2 * kI, nullptr, 1.f, flag);
    // x = (x + h @ Wfo + b)*mask ; xb = bf16(x)
    k_mgemm<4><<<dim3(kD / 128, kBN / 64), 256, 0, stream>>>(
        hb, wtfo, (long)d * kI * kD, kI, kD, nullptr, nullptr, x, xb,
        bfo, (long)d * kD, nullptr, seqm, 1.f, flag);
  }
  k_out<<<kBN * kD / 256, 256, 0, stream>>>(x, d_out, flag);
}

// Round 5
// 994.123 us; speedup vs baseline: 4.6418x; 1.6695x over previous
//
#include <hip/hip_runtime.h>
#include <hip/hip_bf16.h>

// Problem constants
constexpr int kB = 4, kN = 1024, kD = 512, kH = 8, kDh = 64, kT = 512;
constexpr int kHid = 512, kI = 2048, kRel = 65, kDepth = 4;
constexpr int kBN = kB * kN;

typedef short s16x8 __attribute__((ext_vector_type(8)));
typedef float f32x4 __attribute__((ext_vector_type(4)));

// ---------------- dual-dtype load helper ----------------
__device__ __forceinline__ float ldin(const void* p, long i, int isb) {
  if (isb) return __bfloat162float(((const __hip_bfloat16*)p)[i]);
  return ((const float*)p)[i];
}

__device__ __forceinline__ unsigned short bfbits(float v) {
  __hip_bfloat16 h = __float2bfloat16(v);
  return *(unsigned short*)&h;
}

// async global->LDS, 16B per lane. LDS dest must be wave-uniform base.
__device__ __forceinline__ void gload16(const void* g, void* l) {
  __builtin_amdgcn_global_load_lds(
      (const __attribute__((address_space(1))) unsigned int*)g,
      (__attribute__((address_space(3))) unsigned int*)l, 16, 0, 0);
}

// ---------------- dtype detect ----------------
__global__ void k_detect(const void* __restrict__ x, int* __restrict__ flag) {
  const unsigned int* u = (const unsigned int*)x;
  unsigned int v = u[threadIdx.x];
  int e = (v >> 7) & 0xFF;
  int good = (e >= 100 && e <= 140) ? 1 : 0;
  unsigned long long m = __ballot(good);
  if (threadIdx.x == 0) flag[0] = (__popcll(m) >= 48) ? 1 : 0;
}

// ---------------- t_act = silu(time) ----------------
__global__ void k_tact(const void* __restrict__ timein, float* __restrict__ tact,
                       const int* __restrict__ flag) {
  const int isb = *flag;
  int i = blockIdx.x * 256 + threadIdx.x;
  if (i < kB * kT) {
    float v = ldin(timein, i, isb);
    tact[i] = v / (1.f + __expf(-v));
  }
}

// ---------------- x = x_in * mask (fp32 + bf16 copies) ----------------
__global__ void k_xinit(const void* __restrict__ xin, const void* __restrict__ seqm,
                        float* __restrict__ x, __hip_bfloat16* __restrict__ xb,
                        const int* __restrict__ flag) {
  const int isb = *flag;
  const long base = ((long)blockIdx.x * 256 + threadIdx.x) * 8;
  const int row = (int)(base >> 9);
  const float mk = ldin(seqm, row, isb);
  __align__(16) unsigned short pk[8];
  #pragma unroll
  for (int j = 0; j < 8; j++) {
    float v = ldin(xin, base + j, isb) * mk;
    x[base + j] = v;
    pk[j] = bfbits(v);
  }
  *(uint4*)(xb + base) = *(const uint4*)pk;
}

// ---------------- weight transpose-convert: W[d][K][N] -> Wt[d][N][K] bf16 ----
__global__ __launch_bounds__(256) void k_wt(const void* __restrict__ W,
                                            __hip_bfloat16* __restrict__ Wt,
                                            int K, int N, const int* __restrict__ flag) {
  const int isb = *flag;
  __shared__ float T[64][65];
  const int t = threadIdx.x;
  const int cn = t & 63, r4 = t >> 6;
  const int n0 = blockIdx.x * 64, k0 = blockIdx.y * 64;
  const long ibase = (long)blockIdx.z * K * N;
  const long obase = (long)blockIdx.z * N * K;
  for (int rr = r4; rr < 64; rr += 4)
    T[rr][cn] = ldin(W, ibase + (long)(k0 + rr) * N + n0 + cn, isb);
  __syncthreads();
  for (int nn = r4; nn < 64; nn += 4)
    Wt[obase + (long)(n0 + nn) * K + k0 + cn] = __float2bfloat16(T[cn][nn]);
}

// ---------------- time projections for all layers ----------------
__global__ __launch_bounds__(256) void k_timeproj(
    const float* __restrict__ tact,
    const void* __restrict__ atw, const void* __restrict__ atb,
    const void* __restrict__ ftw, const void* __restrict__ ftb,
    float* __restrict__ ascsh, float* __restrict__ fscsh,
    const int* __restrict__ flag) {
  const int isb = *flag;
  __shared__ float T[kB * kT];
  const int d = blockIdx.y;
  for (int i = threadIdx.x; i < kB * kT; i += 256) T[i] = tact[i];
  __syncthreads();
  const int c = blockIdx.x * 256 + threadIdx.x;
  float a0 = 0, a1 = 0, a2 = 0, a3 = 0;
  if (c < 2 * kD) {
    const long wo = (long)d * kT * 2 * kD + c;
    #pragma unroll 4
    for (int tt = 0; tt < kT; tt++) {
      const float w = ldin(atw, wo + (long)tt * 2 * kD, isb);
      a0 += T[0 * kT + tt] * w; a1 += T[1 * kT + tt] * w;
      a2 += T[2 * kT + tt] * w; a3 += T[3 * kT + tt] * w;
    }
    const float bv = ldin(atb, (long)d * 2 * kD + c, isb);
    ascsh[((long)d * kB + 0) * 2 * kD + c] = a0 + bv;
    ascsh[((long)d * kB + 1) * 2 * kD + c] = a1 + bv;
    ascsh[((long)d * kB + 2) * 2 * kD + c] = a2 + bv;
    ascsh[((long)d * kB + 3) * 2 * kD + c] = a3 + bv;
  } else {
    const int c2 = c - 2 * kD;
    if (c2 < 2 * kI) {
      const long wo = (long)d * kT * 2 * kI + c2;
      #pragma unroll 4
      for (int tt = 0; tt < kT; tt++) {
        const float w = ldin(ftw, wo + (long)tt * 2 * kI, isb);
        a0 += T[0 * kT + tt] * w; a1 += T[1 * kT + tt] * w;
        a2 += T[2 * kT + tt] * w; a3 += T[3 * kT + tt] * w;
      }
      const float bv = ldin(ftb, (long)d * 2 * kI + c2, isb);
      fscsh[((long)d * kB + 0) * 2 * kI + c2] = a0 + bv;
      fscsh[((long)d * kB + 1) * 2 * kI + c2] = a1 + bv;
      fscsh[((long)d * kB + 2) * 2 * kI + c2] = a2 + bv;
      fscsh[((long)d * kB + 3) * 2 * kI + c2] = a3 + bv;
    }
  }
}

// ---------------- LayerNorm -> bf16 out (+optional AdaLN mod + mask) --------
__global__ __launch_bounds__(256) void k_ln(
    const float* __restrict__ x, const void* __restrict__ g,
    const float* __restrict__ scsh, const void* __restrict__ seqm,
    __hip_bfloat16* __restrict__ xnb, int d, int domod, const int* __restrict__ flag) {
  const int isb = *flag;
  const int wid = threadIdx.x >> 6, lane = threadIdx.x & 63;
  const int row = blockIdx.x * 4 + wid;
  const int b = row >> 10;
  const float* xr = x + (long)row * kD + lane * 8;
  const float4 v0 = *(const float4*)xr;
  const float4 v1 = *(const float4*)(xr + 4);
  float v[8] = {v0.x, v0.y, v0.z, v0.w, v1.x, v1.y, v1.z, v1.w};
  float s = 0.f, s2 = 0.f;
  #pragma unroll
  for (int i = 0; i < 8; i++) { s += v[i]; s2 += v[i] * v[i]; }
  #pragma unroll
  for (int off = 1; off < 64; off <<= 1) { s += __shfl_xor(s, off); s2 += __shfl_xor(s2, off); }
  const float mean = s * (1.f / kD);
  const float var = fmaxf(s2 * (1.f / kD) - mean * mean, 0.f);
  const float rstd = rsqrtf(var + 1e-5f);
  float mk = 1.f;
  if (domod) mk = ldin(seqm, row, isb);
  __align__(16) unsigned short pk[8];
  #pragma unroll
  for (int i = 0; i < 8; i++) {
    const int cc = lane * 8 + i;
    float y = (v[i] - mean) * rstd * ldin(g, (long)d * kD + cc, isb);
    if (domod)
      y = (y * (scsh[(long)b * 2 * kD + cc] + 1.f) + scsh[(long)b * 2 * kD + kD + cc]) * mk;
    pk[i] = bfbits(y);
  }
  *(uint4*)(xnb + (long)row * kD + lane * 8) = *(const uint4*)pk;
}

// ---------------- bf16 MFMA GEMM: C[M,Nc] = A[M,K] @ Wt[Nc,K]^T --------------
// BM=64, BN=128, BK=32; 4 waves (2m x 2n); wave = 32x64 = 2x4 frags of 16x16.
// EPI: 0 q: Cb=bf16(acc*fscale)  1 kv: Cb=bf16(acc)   2 out: X+=acc*mask
//      3 ffin: Cb=bf16(silu(acc+b)*(sc+1)+sh)  4 ffout: X=(X+acc+b)*mask, Xb=bf16(X)
template <int EPI>
__global__ __launch_bounds__(256) void k_mgemm(
    const __hip_bfloat16* __restrict__ A, const __hip_bfloat16* __restrict__ Wt,
    long woff, int K, int Nc,
    float* __restrict__ Cf, __hip_bfloat16* __restrict__ Cb,
    float* __restrict__ X, __hip_bfloat16* __restrict__ Xb,
    const void* __restrict__ bias, long boff,
    const float* __restrict__ scsh, const void* __restrict__ seqm,
    float fscale, const int* __restrict__ flag) {
  const int isb = *flag;
  __shared__ __align__(16) short As[64 * 32];
  __shared__ __align__(16) short Bs[128 * 32];
  const int t = threadIdx.x;
  const int l = t & 63, wid = t >> 6;
  const int wm = wid & 1, wn = wid >> 1;
  const int lr = l >> 4, lc = l & 15;
  const int m0 = blockIdx.y * 64, n0 = blockIdx.x * 128;

  f32x4 acc[2][4] = {};

  const __hip_bfloat16* gA = A + (long)(m0 + (t >> 2)) * K + ((t & 3) << 3);
  const __hip_bfloat16* gB = Wt + woff + (long)(n0 + (t >> 2)) * K + ((t & 3) << 3);
  const __hip_bfloat16* gB2 = gB + (long)64 * K;
  short* ldsA = As + (wid << 9);
  short* ldsB0 = Bs + (wid << 9);
  short* ldsB1 = Bs + 2048 + (wid << 9);

  for (int k0 = 0; k0 < K; k0 += 32) {
    gload16(gA + k0, ldsA);
    gload16(gB + k0, ldsB0);
    gload16(gB2 + k0, ldsB1);
    __syncthreads();
    s16x8 af[2], bf[4];
    #pragma unroll
    for (int fm = 0; fm < 2; fm++)
      af[fm] = *(const s16x8*)&As[(wm * 32 + fm * 16 + lc) * 32 + lr * 8];
    #pragma unroll
    for (int fn = 0; fn < 4; fn++)
      bf[fn] = *(const s16x8*)&Bs[(wn * 64 + fn * 16 + lc) * 32 + lr * 8];
    #pragma unroll
    for (int fm = 0; fm < 2; fm++)
      #pragma unroll
      for (int fn = 0; fn < 4; fn++)
        acc[fm][fn] = __builtin_amdgcn_mfma_f32_16x16x32_bf16(af[fm], bf[fn], acc[fm][fn], 0, 0, 0);
    __syncthreads();
  }

  #pragma unroll
  for (int fm = 0; fm < 2; fm++) {
    #pragma unroll
    for (int j = 0; j < 4; j++) {
      const int r = m0 + wm * 32 + fm * 16 + lr * 4 + j;
      const int bb = r >> 10;
      float mk = 1.f;
      if constexpr (EPI == 2 || EPI == 4) mk = ldin(seqm, r, isb);
      #pragma unroll
      for (int fn = 0; fn < 4; fn++) {
        const int cc = n0 + wn * 64 + fn * 16 + lc;
        const long off = (long)r * Nc + cc;
        float v = acc[fm][fn][j];
        if constexpr (EPI == 0) {
          Cb[off] = __float2bfloat16(v * fscale);
        } else if constexpr (EPI == 1) {
          Cb[off] = __float2bfloat16(v);
        } else if constexpr (EPI == 2) {
          X[off] += v * mk;
        } else if constexpr (EPI == 3) {
          v += ldin(bias, boff + cc, isb);
          v = v / (1.f + __expf(-v));
          v = v * (scsh[(long)bb * 2 * kI + cc] + 1.f) + scsh[(long)bb * 2 * kI + kI + cc];
          Cb[off] = __float2bfloat16(v);
        } else {
          v += ldin(bias, boff + cc, isb);
          const float nx = (X[off] + v) * mk;
          X[off] = nx;
          Xb[off] = __float2bfloat16(nx);
        }
      }
    }
  }
}

// ---------------- MFMA flash attention ----------------
// grid (kN/64, kH, kB), block 256 = 4 waves x 16 q-rows.
// Per 64-wide j-tile: QK^T (8 mfma) -> online softmax on C-frags ->
// P via per-wave LDS relayout -> PV (8 mfma) with V^T tile.
// K tile: linear LDS, XOR-swizzled via pre-swizzled global source (gload16).
// V^T tile: padded rows (72), conflict-free scatter fill.
__global__ __launch_bounds__(256) void k_attn(
    const __hip_bfloat16* __restrict__ qb, const __hip_bfloat16* __restrict__ kvb,
    __hip_bfloat16* __restrict__ aob,
    const void* __restrict__ rpw, const void* __restrict__ rpb,
    const void* __restrict__ seqm, const int* __restrict__ ridx,
    const int* __restrict__ flag) {
  const int isb = *flag;
  const int t = threadIdx.x;
  const int i0 = blockIdx.x * 64;
  const int h = blockIdx.y;
  const int b = blockIdx.z;

  __shared__ __align__(16) short Ks[64 * 64];      // swizzled: elem d at d^((j&7)*8)
  __shared__ __align__(16) short Vt[64 * 72];      // Vt[d][j], rows padded to 72
  __shared__ __align__(16) short Ps[4][16 * 72];   // per-wave P, rows padded to 72
  __shared__ float biasw[kRel];
  __shared__ int riq[64], rik[64];
  __shared__ float mkq[64], mkk[64];

  const int l = t & 63, wid = t >> 6;
  const int g = l >> 4, li = l & 15;

  if (t < kRel) biasw[t] = ldin(rpw, (long)t * kH + h, isb) + ldin(rpb, h, isb);
  if (t < 64) { riq[t] = ridx[b * kN + i0 + t]; mkq[t] = ldin(seqm, b * kN + i0 + t, isb); }

  // Q fragments (A-layout): lane holds Q[i0+wid*16+li][kc*32 + g*8 .. +8]
  const __hip_bfloat16* qptr =
      qb + ((long)(b * kN + i0 + wid * 16 + li)) * kHid + h * kDh + g * 8;
  s16x8 aq[2];
  aq[0] = *(const s16x8*)qptr;
  aq[1] = *(const s16x8*)(qptr + 32);

  __syncthreads();  // riq/mkq/biasw visible

  // hoist per-lane row metadata (C-frag rows: i = g*4 + r)
  float mkqv[4]; int riqv[4];
  #pragma unroll
  for (int r = 0; r < 4; r++) {
    riqv[r] = riq[wid * 16 + g * 4 + r];
    mkqv[r] = mkq[wid * 16 + g * 4 + r];
  }

  float m_run[4] = {-1e30f, -1e30f, -1e30f, -1e30f};
  float l_run[4] = {0.f, 0.f, 0.f, 0.f};
  f32x4 o[4] = {};  // O frags: rows i, cols d = fd*16+li

  for (int j0 = 0; j0 < kN; j0 += 64) {
    if (t < 64) { rik[t] = ridx[b * kN + j0 + t]; mkk[t] = ldin(seqm, b * kN + j0 + t, isb); }
    // --- stage K (swizzled source -> linear LDS) ---
    #pragma unroll
    for (int p = 0; p < 2; p++) {
      const int j = p * 32 + wid * 8 + (l >> 3);
      const short* gk = (const short*)kvb + ((long)(b * kN + j0 + j)) * 1024 + h * 64 +
                        (((l & 7) ^ (l >> 3)) * 8);
      gload16(gk, Ks + p * 2048 + wid * 512);
    }
    // --- stage V^T (reg transpose, conflict-free scatter) ---
    {
      const int jv = l;  // 0..63
      const int d0 = wid * 16;
      const short* gv = (const short*)kvb + ((long)(b * kN + j0 + jv)) * 1024 + 512 + h * 64 + d0;
      s16x8 v0 = *(const s16x8*)gv;
      s16x8 v1 = *(const s16x8*)(gv + 8);
      #pragma unroll
      for (int dd = 0; dd < 8; dd++) {
        Vt[(d0 + dd) * 72 + jv] = v0[dd];
        Vt[(d0 + 8 + dd) * 72 + jv] = v1[dd];
      }
    }
    __syncthreads();

    // --- S = Q K^T (C-frags: row i = g*4+r, col j = fc*16+li) ---
    f32x4 s[4] = {};
    #pragma unroll
    for (int kc = 0; kc < 2; kc++) {
      #pragma unroll
      for (int fc = 0; fc < 4; fc++) {
        const int jl = fc * 16 + li;
        const s16x8 bk = *(const s16x8*)&Ks[jl * 64 + ((kc * 32 + g * 8) ^ ((li & 7) * 8))];
        s[fc] = __builtin_amdgcn_mfma_f32_16x16x32_bf16(aq[kc], bk, s[fc], 0, 0, 0);
      }
    }

    // --- bias + mask ---
    int rikv[4]; float mkkv[4];
    #pragma unroll
    for (int fc = 0; fc < 4; fc++) { rikv[fc] = rik[fc * 16 + li]; mkkv[fc] = mkk[fc * 16 + li]; }
    #pragma unroll
    for (int fc = 0; fc < 4; fc++) {
      #pragma unroll
      for (int r = 0; r < 4; r++) {
        int di = riqv[r] - rikv[fc];
        di = di < -32 ? -32 : (di > 32 ? 32 : di);
        s[fc][r] += biasw[di + 32] - (1.f - mkqv[r] * mkkv[fc]) * 1e6f;
      }
    }

    // --- online softmax (rows shared by the 16 lanes with same g) ---
    #pragma unroll
    for (int r = 0; r < 4; r++) {
      float mx = fmaxf(fmaxf(s[0][r], s[1][r]), fmaxf(s[2][r], s[3][r]));
      mx = fmaxf(mx, __shfl_xor(mx, 1));
      mx = fmaxf(mx, __shfl_xor(mx, 2));
      mx = fmaxf(mx, __shfl_xor(mx, 4));
      mx = fmaxf(mx, __shfl_xor(mx, 8));
      const float m_new = fmaxf(m_run[r], mx);
      const float e = __expf(m_run[r] - m_new);
      float ps = 0.f;
      #pragma unroll
      for (int fc = 0; fc < 4; fc++) {
        const float p = __expf(s[fc][r] - m_new);
        ps += p;
        Ps[wid][(g * 4 + r) * 72 + fc * 16 + li] = (short)bfbits(p);
      }
      ps += __shfl_xor(ps, 1);
      ps += __shfl_xor(ps, 2);
      ps += __shfl_xor(ps, 4);
      ps += __shfl_xor(ps, 8);
      l_run[r] = l_run[r] * e + ps;
      m_run[r] = m_new;
      o[0][r] *= e; o[1][r] *= e; o[2][r] *= e; o[3][r] *= e;
    }

    // --- PV: A = P (rows i, k=j), B = V^T-trick (Vt row-major) ---
    #pragma unroll
    for (int kc = 0; kc < 2; kc++) {
      const s16x8 pa = *(const s16x8*)&Ps[wid][li * 72 + kc * 32 + g * 8];
      #pragma unroll
      for (int fd = 0; fd < 4; fd++) {
        const s16x8 bv = *(const s16x8*)&Vt[(fd * 16 + li) * 72 + kc * 32 + g * 8];
        o[fd] = __builtin_amdgcn_mfma_f32_16x16x32_bf16(pa, bv, o[fd], 0, 0, 0);
      }
    }
    __syncthreads();  // Ks/Vt reuse next tile
  }

  // --- normalize + write ---
  float inv[4];
  #pragma unroll
  for (int r = 0; r < 4; r++) inv[r] = 1.f / l_run[r];
  #pragma unroll
  for (int fd = 0; fd < 4; fd++) {
    #pragma unroll
    for (int r = 0; r < 4; r++) {
      const long off =
          ((long)(b * kN + i0 + wid * 16 + g * 4 + r)) * kHid + h * kDh + fd * 16 + li;
      aob[off] = __float2bfloat16(o[fd][r] * inv[r]);
    }
  }
}

// ---------------- write out (dual dtype) ----------------
__global__ void k_out(const float* __restrict__ x, void* __restrict__ out,
                      const int* __restrict__ flag) {
  const int i = blockIdx.x * 256 + threadIdx.x;
  if (*flag) ((__hip_bfloat16*)out)[i] = __float2bfloat16(x[i]);
  else ((float*)out)[i] = x[i];
}

extern "C" void kernel_launch(void* const* d_in, const int* in_sizes, int n_in,
                              void* d_out, int out_size, void* d_ws, size_t ws_size,
                              hipStream_t stream) {
  const void* xin  = d_in[0];
  const void* timein = d_in[1];
  const void* seqm = d_in[2];
  const int*  ridx = (const int*)d_in[3];
  const void* rpw  = d_in[4];
  const void* rpb  = d_in[5];
  const void* ang  = d_in[6];
  const void* atw  = d_in[7];
  const void* atb  = d_in[8];
  const void* wq   = d_in[9];
  const void* wkv  = d_in[10];
  const void* wo   = d_in[11];
  const void* fng  = d_in[12];
  const void* ftw  = d_in[13];
  const void* ftb  = d_in[14];
  const void* wfi  = d_in[15];
  const void* bfi  = d_in[16];
  const void* wfo  = d_in[17];
  const void* bfo  = d_in[18];

  float* ws = (float*)d_ws;
  float* x     = ws;                 // 2,097,152 f32
  float* tact  = ws + 2097152;       // 2,048
  float* ascsh = ws + 2099200;       // 16,384  [D][B][2*kD]
  float* fscsh = ws + 2115584;       // 65,536  [D][B][2*kI]
  int*   flag  = (int*)(ws + 2181120);
  __hip_bfloat16* bfb = (__hip_bfloat16*)(ws + 2181184);
  __hip_bfloat16* xnb  = bfb;             // 2,097,152
  __hip_bfloat16* xb   = bfb + 2097152;   // 2,097,152
  __hip_bfloat16* aob  = bfb + 4194304;   // 2,097,152
  __hip_bfloat16* hb   = bfb + 6291456;   // 8,388,608
  __hip_bfloat16* qbuf = bfb + 14680064;  // 2,097,152
  __hip_bfloat16* kvb  = bfb + 16777216;  // 4,194,304
  __hip_bfloat16* wtq  = bfb + 20971520;  // 1,048,576 [D][512][512]
  __hip_bfloat16* wtkv = bfb + 22020096;  // 2,097,152 [D][1024][512]
  __hip_bfloat16* wto  = bfb + 24117248;  // 1,048,576 [D][512][512]
  __hip_bfloat16* wtfi = bfb + 25165824;  // 4,194,304 [D][2048][512]
  __hip_bfloat16* wtfo = bfb + 29360128;  // 4,194,304 [D][512][2048]

  k_detect<<<1, 64, 0, stream>>>(xin, flag);
  k_tact<<<8, 256, 0, stream>>>(timein, tact, flag);
  k_xinit<<<kBN * kD / 2048, 256, 0, stream>>>(xin, seqm, x, xb, flag);
  k_timeproj<<<dim3(20, kDepth), 256, 0, stream>>>(tact, atw, atb, ftw, ftb, ascsh, fscsh, flag);
  k_wt<<<dim3(8, 8, kDepth), 256, 0, stream>>>(wq, wtq, kD, kHid, flag);
  k_wt<<<dim3(16, 8, kDepth), 256, 0, stream>>>(wkv, wtkv, kD, 2 * kHid, flag);
  k_wt<<<dim3(8, 8, kDepth), 256, 0, stream>>>(wo, wto, kHid, kD, flag);
  k_wt<<<dim3(32, 8, kDepth), 256, 0, stream>>>(wfi, wtfi, kD, kI, flag);
  k_wt<<<dim3(8, 32, kDepth), 256, 0, stream>>>(wfo, wtfo, kI, kD, flag);

  for (int d = 0; d < kDepth; ++d) {
    k_ln<<<kBN / 4, 256, 0, stream>>>(x, ang, ascsh + (long)d * kB * 2 * kD, seqm, xnb, d, 1, flag);
    // q = bf16((xn @ Wq) * SCALE)
    k_mgemm<0><<<dim3(kHid / 128, kBN / 64), 256, 0, stream>>>(
        xnb, wtq, (long)d * kD * kHid, kD, kHid, nullptr, qbuf, nullptr, nullptr,
        nullptr, 0, nullptr, nullptr, 0.125f, flag);
    // kv = bf16(x @ Wkv)
    k_mgemm<1><<<dim3(2 * kHid / 128, kBN / 64), 256, 0, stream>>>(
        xb, wtkv, (long)d * kD * 2 * kHid, kD, 2 * kHid, nullptr, kvb, nullptr, nullptr,
        nullptr, 0, nullptr, nullptr, 1.f, flag);
    k_attn<<<dim3(kN / 64, kH, kB), 256, 0, stream>>>(qbuf, kvb, aob, rpw, rpb, seqm, ridx, flag);
    // x += (ao @ Wo) * mask
    k_mgemm<2><<<dim3(kD / 128, kBN / 64), 256, 0, stream>>>(
        aob, wto, (long)d * kHid * kD, kHid, kD, nullptr, nullptr, x, nullptr,
        nullptr, 0, nullptr, seqm, 1.f, flag);
    k_ln<<<kBN / 4, 256, 0, stream>>>(x, fng, nullptr, seqm, xnb, d, 0, flag);
    // h = silu(xn @ Wfi + b)*(sc+1)+sh
    k_mgemm<3><<<dim3(kI / 128, kBN / 64), 256, 0, stream>>>(
        xnb, wtfi, (long)d * kD * kI, kD, kI, nullptr, hb, nullptr, nullptr,
        bfi, (long)d * kI, fscsh + (long)d * kB * 2 * kI, nullptr, 1.f, flag);
    // x = (x + h @ Wfo + b)*mask ; xb = bf16(x)
    k_mgemm<4><<<dim3(kD / 128, kBN / 64), 256, 0, stream>>>(
        hb, wtfo, (long)d * kI * kD, kI, kD, nullptr, nullptr, x, xb,
        bfo, (long)d * kD, nullptr, seqm, 1.f, flag);
  }
  k_out<<<kBN * kD / 256, 256, 0, stream>>>(x, d_out, flag);
}

// Round 10
// 852.420 us; speedup vs baseline: 5.4135x; 1.1662x over previous
//
#include <hip/hip_runtime.h>
#include <hip/hip_bf16.h>

// Problem constants
constexpr int kB = 4, kN = 1024, kD = 512, kH = 8, kDh = 64, kT = 512;
constexpr int kHid = 512, kI = 2048, kRel = 65, kDepth = 4;
constexpr int kBN = kB * kN;

typedef short s16x8 __attribute__((ext_vector_type(8)));
typedef float f32x4 __attribute__((ext_vector_type(4)));

// ---------------- dual-dtype load helper ----------------
__device__ __forceinline__ float ldin(const void* p, long i, int isb) {
  if (isb) return __bfloat162float(((const __hip_bfloat16*)p)[i]);
  return ((const float*)p)[i];
}

__device__ __forceinline__ unsigned short bfbits(float v) {
  __hip_bfloat16 h = __float2bfloat16(v);
  return *(unsigned short*)&h;
}

// async global->LDS, 16B per lane. LDS dest must be wave-uniform base.
__device__ __forceinline__ void gload16(const void* g, void* l) {
  __builtin_amdgcn_global_load_lds(
      (const __attribute__((address_space(1))) unsigned int*)g,
      (__attribute__((address_space(3))) unsigned int*)l, 16, 0, 0);
}

// ---------------- dtype detect ----------------
__global__ void k_detect(const void* __restrict__ x, int* __restrict__ flag) {
  const unsigned int* u = (const unsigned int*)x;
  unsigned int v = u[threadIdx.x];
  int e = (v >> 7) & 0xFF;
  int good = (e >= 100 && e <= 140) ? 1 : 0;
  unsigned long long m = __ballot(good);
  if (threadIdx.x == 0) flag[0] = (__popcll(m) >= 48) ? 1 : 0;
}

// ---------------- x = x_in * mask (fp32 + bf16 copies) ----------------
__global__ void k_xinit(const void* __restrict__ xin, const void* __restrict__ seqm,
                        float* __restrict__ x, __hip_bfloat16* __restrict__ xb,
                        const int* __restrict__ flag) {
  const int isb = *flag;
  const long base = ((long)blockIdx.x * 256 + threadIdx.x) * 8;
  const int row = (int)(base >> 9);
  const float mk = ldin(seqm, row, isb);
  __align__(16) unsigned short pk[8];
  #pragma unroll
  for (int j = 0; j < 8; j++) {
    float v = ldin(xin, base + j, isb) * mk;
    x[base + j] = v;
    pk[j] = bfbits(v);
  }
  *(uint4*)(xb + base) = *(const uint4*)pk;
}

// ---------------- time projection, split-K partials ----------------
// grid (20, 8, kDepth). Each block: 64 t-values of the K=512 reduction,
// 256 cols. cols 0..1023 -> attn 2*kD, 1024..5119 -> ff 2*kI.
// silu(time) computed on the fly (no tact buffer).
__global__ __launch_bounds__(256) void k_timeproj_part(
    const void* __restrict__ timein,
    const void* __restrict__ atw, const void* __restrict__ ftw,
    float* __restrict__ part, const int* __restrict__ flag) {
  const int isb = *flag;
  __shared__ float T[kB * 64];
  const int d = blockIdx.z, kc = blockIdx.y;
  const int tt0 = kc * 64;
  {
    const int b = threadIdx.x >> 6, ttl = threadIdx.x & 63;
    const float tv = ldin(timein, (long)b * kT + tt0 + ttl, isb);
    T[b * 64 + ttl] = tv / (1.f + __expf(-tv));
  }
  __syncthreads();
  const int c = blockIdx.x * 256 + threadIdx.x;
  float a0 = 0, a1 = 0, a2 = 0, a3 = 0;
  if (c < 2 * kD) {
    const long wo = (long)d * kT * 2 * kD + (long)tt0 * 2 * kD + c;
    #pragma unroll 4
    for (int tt = 0; tt < 64; tt++) {
      const float w = ldin(atw, wo + (long)tt * 2 * kD, isb);
      a0 += T[0 * 64 + tt] * w; a1 += T[1 * 64 + tt] * w;
      a2 += T[2 * 64 + tt] * w; a3 += T[3 * 64 + tt] * w;
    }
  } else {
    const int c2 = c - 2 * kD;
    const long wo = (long)d * kT * 2 * kI + (long)tt0 * 2 * kI + c2;
    #pragma unroll 4
    for (int tt = 0; tt < 64; tt++) {
      const float w = ldin(ftw, wo + (long)tt * 2 * kI, isb);
      a0 += T[0 * 64 + tt] * w; a1 += T[1 * 64 + tt] * w;
      a2 += T[2 * 64 + tt] * w; a3 += T[3 * 64 + tt] * w;
    }
  }
  float* pp = part + ((long)(d * 8 + kc) * 4) * 5120 + c;
  pp[0] = a0; pp[5120] = a1; pp[2 * 5120] = a2; pp[3 * 5120] = a3;
}

// grid (20, kDepth): sum 8 partials + bias -> ascsh / fscsh
__global__ __launch_bounds__(256) void k_timeproj_comb(
    const float* __restrict__ part,
    const void* __restrict__ atb, const void* __restrict__ ftb,
    float* __restrict__ ascsh, float* __restrict__ fscsh,
    const int* __restrict__ flag) {
  const int isb = *flag;
  const int d = blockIdx.y;
  const int c = blockIdx.x * 256 + threadIdx.x;
  float s[4] = {0, 0, 0, 0};
  #pragma unroll
  for (int kc = 0; kc < 8; kc++) {
    const float* pp = part + ((long)(d * 8 + kc) * 4) * 5120 + c;
    s[0] += pp[0]; s[1] += pp[5120]; s[2] += pp[2 * 5120]; s[3] += pp[3 * 5120];
  }
  if (c < 2 * kD) {
    const float bv = ldin(atb, (long)d * 2 * kD + c, isb);
    #pragma unroll
    for (int b = 0; b < 4; b++) ascsh[((long)d * kB + b) * 2 * kD + c] = s[b] + bv;
  } else {
    const int c2 = c - 2 * kD;
    const float bv = ldin(ftb, (long)d * 2 * kI + c2, isb);
    #pragma unroll
    for (int b = 0; b < 4; b++) fscsh[((long)d * kB + b) * 2 * kI + c2] = s[b] + bv;
  }
}

// ---------------- fused weight transpose-convert (all 5 weights) ----------
// 64x64 tiles; ranges: wq[0,256) wkv[256,768) wo[768,1024) wfi[1024,2048)
// wfo[2048,3072).
__global__ __launch_bounds__(256) void k_wtall(
    const void* __restrict__ wq, const void* __restrict__ wkv,
    const void* __restrict__ wo, const void* __restrict__ wfi,
    const void* __restrict__ wfo,
    __hip_bfloat16* __restrict__ wtq, __hip_bfloat16* __restrict__ wtkv,
    __hip_bfloat16* __restrict__ wto, __hip_bfloat16* __restrict__ wtfi,
    __hip_bfloat16* __restrict__ wtfo, const int* __restrict__ flag) {
  const int isb = *flag;
  __shared__ float T[64][65];
  const int bx = blockIdx.x;
  const void* W; __hip_bfloat16* Wt; int K, N, tl;
  if (bx < 256)       { W = wq;  Wt = wtq;  K = 512;  N = 512;  tl = bx; }
  else if (bx < 768)  { W = wkv; Wt = wtkv; K = 512;  N = 1024; tl = bx - 256; }
  else if (bx < 1024) { W = wo;  Wt = wto;  K = 512;  N = 512;  tl = bx - 768; }
  else if (bx < 2048) { W = wfi; Wt = wtfi; K = 512;  N = 2048; tl = bx - 1024; }
  else                { W = wfo; Wt = wtfo; K = 2048; N = 512;  tl = bx - 2048; }
  const int nx = N >> 6, nk = K >> 6;
  const int z = tl / (nx * nk);
  const int rem = tl % (nx * nk);
  const int k0 = (rem / nx) * 64, n0 = (rem % nx) * 64;
  const long ibase = (long)z * K * N;
  const long obase = (long)z * N * K;
  const int t = threadIdx.x;
  const int cn = t & 63, r4 = t >> 6;
  for (int rr = r4; rr < 64; rr += 4)
    T[rr][cn] = ldin(W, ibase + (long)(k0 + rr) * N + n0 + cn, isb);
  __syncthreads();
  for (int nn = r4; nn < 64; nn += 4)
    Wt[obase + (long)(n0 + nn) * K + k0 + cn] = __float2bfloat16(T[cn][nn]);
}

// ---------------- LayerNorm -> bf16 out (+optional AdaLN mod + mask) --------
__global__ __launch_bounds__(256) void k_ln(
    const float* __restrict__ x, const void* __restrict__ g,
    const float* __restrict__ scsh, const void* __restrict__ seqm,
    __hip_bfloat16* __restrict__ xnb, int d, int domod, const int* __restrict__ flag) {
  const int isb = *flag;
  const int wid = threadIdx.x >> 6, lane = threadIdx.x & 63;
  const int row = blockIdx.x * 4 + wid;
  const int b = row >> 10;
  const float* xr = x + (long)row * kD + lane * 8;
  const float4 v0 = *(const float4*)xr;
  const float4 v1 = *(const float4*)(xr + 4);
  float v[8] = {v0.x, v0.y, v0.z, v0.w, v1.x, v1.y, v1.z, v1.w};
  float s = 0.f, s2 = 0.f;
  #pragma unroll
  for (int i = 0; i < 8; i++) { s += v[i]; s2 += v[i] * v[i]; }
  #pragma unroll
  for (int off = 1; off < 64; off <<= 1) { s += __shfl_xor(s, off); s2 += __shfl_xor(s2, off); }
  const float mean = s * (1.f / kD);
  const float var = fmaxf(s2 * (1.f / kD) - mean * mean, 0.f);
  const float rstd = rsqrtf(var + 1e-5f);
  float mk = 1.f;
  if (domod) mk = ldin(seqm, row, isb);
  __align__(16) unsigned short pk[8];
  #pragma unroll
  for (int i = 0; i < 8; i++) {
    const int cc = lane * 8 + i;
    float y = (v[i] - mean) * rstd * ldin(g, (long)d * kD + cc, isb);
    if (domod)
      y = (y * (scsh[(long)b * 2 * kD + cc] + 1.f) + scsh[(long)b * 2 * kD + kD + cc]) * mk;
    pk[i] = bfbits(y);
  }
  *(uint4*)(xnb + (long)row * kD + lane * 8) = *(const uint4*)pk;
}

// ======== bf16 MFMA GEMM core geometry (BM=64, BN=128, BK=64) ========
// 4 waves (2m x 2n); wave = 32x64 out = 2x4 frags of 16x16.
// LDS XOR-swizzle: LDS[r][chunk] holds global chunk (chunk ^ (r&7));
// achieved by inverse-swizzled global source (gload16 dest stays linear).
// Frag read at chunk q: LDS[r][q ^ (r&7)] -> conflict-free (2-way max).

// EPI: 2 out: X+=acc*mask   3 ffin: Cb=bf16(silu(acc+b)*(sc+1)+sh)
//      4 ffout: X=(X+acc+b)*mask, Xb=bf16(X)
template <int EPI>
__global__ __launch_bounds__(256) void k_mgemm(
    const __hip_bfloat16* __restrict__ A, const __hip_bfloat16* __restrict__ Wt,
    long woff, int K, int Nc,
    __hip_bfloat16* __restrict__ Cb,
    float* __restrict__ X, __hip_bfloat16* __restrict__ Xb,
    const void* __restrict__ bias, long boff,
    const float* __restrict__ scsh, const void* __restrict__ seqm,
    const int* __restrict__ flag) {
  const int isb = *flag;
  __shared__ __align__(16) short As[64 * 64];
  __shared__ __align__(16) short Bs[128 * 64];
  const int t = threadIdx.x;
  const int l = t & 63, wid = t >> 6;
  const int wm = wid & 1, wn = wid >> 1;
  const int lr = l >> 4, lc = l & 15;
  const int m0 = blockIdx.y * 64, n0 = blockIdx.x * 128;

  f32x4 acc[2][4] = {};
  const int lrow8 = l >> 3;
  const int lchunk = (l & 7) ^ lrow8;
  const __hip_bfloat16* gA = A + (long)(m0 + wid * 8 + lrow8) * K + lchunk * 8;
  const __hip_bfloat16* gB = Wt + woff + (long)(n0 + wid * 8 + lrow8) * K + lchunk * 8;

  for (int k0 = 0; k0 < K; k0 += 64) {
    #pragma unroll
    for (int p = 0; p < 2; p++)
      gload16(gA + (long)p * 32 * K + k0, As + p * 2048 + wid * 512);
    #pragma unroll
    for (int p = 0; p < 4; p++)
      gload16(gB + (long)p * 32 * K + k0, Bs + p * 2048 + wid * 512);
    __syncthreads();
    #pragma unroll
    for (int kk = 0; kk < 2; kk++) {
      s16x8 af[2], bf[4];
      #pragma unroll
      for (int fm = 0; fm < 2; fm++) {
        const int r = wm * 32 + fm * 16 + lc;
        af[fm] = *(const s16x8*)&As[r * 64 + (((kk * 4 + lr) ^ (r & 7)) * 8)];
      }
      #pragma unroll
      for (int fn = 0; fn < 4; fn++) {
        const int r = wn * 64 + fn * 16 + lc;
        bf[fn] = *(const s16x8*)&Bs[r * 64 + (((kk * 4 + lr) ^ (r & 7)) * 8)];
      }
      #pragma unroll
      for (int fm = 0; fm < 2; fm++)
        #pragma unroll
        for (int fn = 0; fn < 4; fn++)
          acc[fm][fn] = __builtin_amdgcn_mfma_f32_16x16x32_bf16(af[fm], bf[fn], acc[fm][fn], 0, 0, 0);
    }
    __syncthreads();
  }

  #pragma unroll
  for (int fm = 0; fm < 2; fm++) {
    #pragma unroll
    for (int j = 0; j < 4; j++) {
      const int r = m0 + wm * 32 + fm * 16 + lr * 4 + j;
      const int bb = r >> 10;
      float mk = 1.f;
      if constexpr (EPI == 2 || EPI == 4) mk = ldin(seqm, r, isb);
      #pragma unroll
      for (int fn = 0; fn < 4; fn++) {
        const int cc = n0 + wn * 64 + fn * 16 + lc;
        const long off = (long)r * Nc + cc;
        float v = acc[fm][fn][j];
        if constexpr (EPI == 2) {
          X[off] += v * mk;
        } else if constexpr (EPI == 3) {
          v += ldin(bias, boff + cc, isb);
          v = v / (1.f + __expf(-v));
          v = v * (scsh[(long)bb * 2 * kI + cc] + 1.f) + scsh[(long)bb * 2 * kI + kI + cc];
          Cb[off] = __float2bfloat16(v);
        } else {
          v += ldin(bias, boff + cc, isb);
          const float nx = (X[off] + v) * mk;
          X[off] = nx;
          Xb[off] = __float2bfloat16(nx);
        }
      }
    }
  }
}

// ---------------- fused q + kv GEMM (one launch, 768 blocks) -------------
// blockIdx.x<4: q = bf16((xn @ Wq)*0.125); else kv = bf16(x @ Wkv). K=512.
__global__ __launch_bounds__(256) void k_qkv(
    const __hip_bfloat16* __restrict__ xnb, const __hip_bfloat16* __restrict__ xb,
    const __hip_bfloat16* __restrict__ wtq, const __hip_bfloat16* __restrict__ wtkv,
    __hip_bfloat16* __restrict__ qbuf, __hip_bfloat16* __restrict__ kvb) {
  constexpr int K = kD;
  __shared__ __align__(16) short As[64 * 64];
  __shared__ __align__(16) short Bs[128 * 64];
  const int t = threadIdx.x;
  const int l = t & 63, wid = t >> 6;
  const int wm = wid & 1, wn = wid >> 1;
  const int lr = l >> 4, lc = l & 15;
  const int m0 = blockIdx.y * 64;

  const __hip_bfloat16* A; const __hip_bfloat16* Wt; __hip_bfloat16* C;
  int Nc, n0; float scale;
  if (blockIdx.x < 4) {
    A = xnb; Wt = wtq; C = qbuf; Nc = kHid; n0 = blockIdx.x * 128; scale = 0.125f;
  } else {
    A = xb; Wt = wtkv; C = kvb; Nc = 2 * kHid; n0 = (blockIdx.x - 4) * 128; scale = 1.f;
  }

  f32x4 acc[2][4] = {};
  const int lrow8 = l >> 3;
  const int lchunk = (l & 7) ^ lrow8;
  const __hip_bfloat16* gA = A + (long)(m0 + wid * 8 + lrow8) * K + lchunk * 8;
  const __hip_bfloat16* gB = Wt + (long)(n0 + wid * 8 + lrow8) * K + lchunk * 8;

  for (int k0 = 0; k0 < K; k0 += 64) {
    #pragma unroll
    for (int p = 0; p < 2; p++)
      gload16(gA + (long)p * 32 * K + k0, As + p * 2048 + wid * 512);
    #pragma unroll
    for (int p = 0; p < 4; p++)
      gload16(gB + (long)p * 32 * K + k0, Bs + p * 2048 + wid * 512);
    __syncthreads();
    #pragma unroll
    for (int kk = 0; kk < 2; kk++) {
      s16x8 af[2], bf[4];
      #pragma unroll
      for (int fm = 0; fm < 2; fm++) {
        const int r = wm * 32 + fm * 16 + lc;
        af[fm] = *(const s16x8*)&As[r * 64 + (((kk * 4 + lr) ^ (r & 7)) * 8)];
      }
      #pragma unroll
      for (int fn = 0; fn < 4; fn++) {
        const int r = wn * 64 + fn * 16 + lc;
        bf[fn] = *(const s16x8*)&Bs[r * 64 + (((kk * 4 + lr) ^ (r & 7)) * 8)];
      }
      #pragma unroll
      for (int fm = 0; fm < 2; fm++)
        #pragma unroll
        for (int fn = 0; fn < 4; fn++)
          acc[fm][fn] = __builtin_amdgcn_mfma_f32_16x16x32_bf16(af[fm], bf[fn], acc[fm][fn], 0, 0, 0);
    }
    __syncthreads();
  }

  #pragma unroll
  for (int fm = 0; fm < 2; fm++)
    #pragma unroll
    for (int j = 0; j < 4; j++) {
      const int r = m0 + wm * 32 + fm * 16 + lr * 4 + j;
      #pragma unroll
      for (int fn = 0; fn < 4; fn++) {
        const int cc = n0 + wn * 64 + fn * 16 + lc;
        C[(long)r * Nc + cc] = __float2bfloat16(acc[fm][fn][j] * scale);
      }
    }
}

// ---------------- MFMA flash attention ----------------
// grid (kN/64, kH, kB), block 256 = 4 waves x 16 q-rows.
__global__ __launch_bounds__(256) void k_attn(
    const __hip_bfloat16* __restrict__ qb, const __hip_bfloat16* __restrict__ kvb,
    __hip_bfloat16* __restrict__ aob,
    const void* __restrict__ rpw, const void* __restrict__ rpb,
    const void* __restrict__ seqm, const int* __restrict__ ridx,
    const int* __restrict__ flag) {
  const int isb = *flag;
  const int t = threadIdx.x;
  const int i0 = blockIdx.x * 64;
  const int h = blockIdx.y;
  const int b = blockIdx.z;

  __shared__ __align__(16) short Ks[64 * 64];      // swizzled: elem d at d^((j&7)*8)
  __shared__ __align__(16) short Vt[64 * 72];      // Vt[d][j], rows padded to 72
  __shared__ __align__(16) short Ps[4][16 * 72];   // per-wave P, rows padded to 72
  __shared__ float biasw[kRel];
  __shared__ int riq[64], rik[64];
  __shared__ float mkq[64], mkk[64];

  const int l = t & 63, wid = t >> 6;
  const int g = l >> 4, li = l & 15;

  if (t < kRel) biasw[t] = ldin(rpw, (long)t * kH + h, isb) + ldin(rpb, h, isb);
  if (t < 64) { riq[t] = ridx[b * kN + i0 + t]; mkq[t] = ldin(seqm, b * kN + i0 + t, isb); }

  const __hip_bfloat16* qptr =
      qb + ((long)(b * kN + i0 + wid * 16 + li)) * kHid + h * kDh + g * 8;
  s16x8 aq[2];
  aq[0] = *(const s16x8*)qptr;
  aq[1] = *(const s16x8*)(qptr + 32);

  __syncthreads();

  float mkqv[4]; int riqv[4];
  #pragma unroll
  for (int r = 0; r < 4; r++) {
    riqv[r] = riq[wid * 16 + g * 4 + r];
    mkqv[r] = mkq[wid * 16 + g * 4 + r];
  }

  float m_run[4] = {-1e30f, -1e30f, -1e30f, -1e30f};
  float l_run[4] = {0.f, 0.f, 0.f, 0.f};
  f32x4 o[4] = {};

  for (int j0 = 0; j0 < kN; j0 += 64) {
    if (t < 64) { rik[t] = ridx[b * kN + j0 + t]; mkk[t] = ldin(seqm, b * kN + j0 + t, isb); }
    #pragma unroll
    for (int p = 0; p < 2; p++) {
      const int j = p * 32 + wid * 8 + (l >> 3);
      const short* gk = (const short*)kvb + ((long)(b * kN + j0 + j)) * 1024 + h * 64 +
                        (((l & 7) ^ (l >> 3)) * 8);
      gload16(gk, Ks + p * 2048 + wid * 512);
    }
    {
      const int jv = l;
      const int d0 = wid * 16;
      const short* gv = (const short*)kvb + ((long)(b * kN + j0 + jv)) * 1024 + 512 + h * 64 + d0;
      s16x8 v0 = *(const s16x8*)gv;
      s16x8 v1 = *(const s16x8*)(gv + 8);
      #pragma unroll
      for (int dd = 0; dd < 8; dd++) {
        Vt[(d0 + dd) * 72 + jv] = v0[dd];
        Vt[(d0 + 8 + dd) * 72 + jv] = v1[dd];
      }
    }
    __syncthreads();

    f32x4 s[4] = {};
    __builtin_amdgcn_s_setprio(1);
    #pragma unroll
    for (int kc = 0; kc < 2; kc++) {
      #pragma unroll
      for (int fc = 0; fc < 4; fc++) {
        const int jl = fc * 16 + li;
        const s16x8 bk = *(const s16x8*)&Ks[jl * 64 + ((kc * 32 + g * 8) ^ ((li & 7) * 8))];
        s[fc] = __builtin_amdgcn_mfma_f32_16x16x32_bf16(aq[kc], bk, s[fc], 0, 0, 0);
      }
    }
    __builtin_amdgcn_s_setprio(0);

    int rikv[4]; float mkkv[4];
    #pragma unroll
    for (int fc = 0; fc < 4; fc++) { rikv[fc] = rik[fc * 16 + li]; mkkv[fc] = mkk[fc * 16 + li]; }
    #pragma unroll
    for (int fc = 0; fc < 4; fc++) {
      #pragma unroll
      for (int r = 0; r < 4; r++) {
        int di = riqv[r] - rikv[fc];
        di = di < -32 ? -32 : (di > 32 ? 32 : di);
        s[fc][r] += biasw[di + 32] - (1.f - mkqv[r] * mkkv[fc]) * 1e6f;
      }
    }

    #pragma unroll
    for (int r = 0; r < 4; r++) {
      float mx = fmaxf(fmaxf(s[0][r], s[1][r]), fmaxf(s[2][r], s[3][r]));
      mx = fmaxf(mx, __shfl_xor(mx, 1));
      mx = fmaxf(mx, __shfl_xor(mx, 2));
      mx = fmaxf(mx, __shfl_xor(mx, 4));
      mx = fmaxf(mx, __shfl_xor(mx, 8));
      const float m_new = fmaxf(m_run[r], mx);
      const float e = __expf(m_run[r] - m_new);
      float ps = 0.f;
      #pragma unroll
      for (int fc = 0; fc < 4; fc++) {
        const float p = __expf(s[fc][r] - m_new);
        ps += p;
        Ps[wid][(g * 4 + r) * 72 + fc * 16 + li] = (short)bfbits(p);
      }
      ps += __shfl_xor(ps, 1);
      ps += __shfl_xor(ps, 2);
      ps += __shfl_xor(ps, 4);
      ps += __shfl_xor(ps, 8);
      l_run[r] = l_run[r] * e + ps;
      m_run[r] = m_new;
      o[0][r] *= e; o[1][r] *= e; o[2][r] *= e; o[3][r] *= e;
    }

    __builtin_amdgcn_s_setprio(1);
    #pragma unroll
    for (int kc = 0; kc < 2; kc++) {
      const s16x8 pa = *(const s16x8*)&Ps[wid][li * 72 + kc * 32 + g * 8];
      #pragma unroll
      for (int fd = 0; fd < 4; fd++) {
        const s16x8 bv = *(const s16x8*)&Vt[(fd * 16 + li) * 72 + kc * 32 + g * 8];
        o[fd] = __builtin_amdgcn_mfma_f32_16x16x32_bf16(pa, bv, o[fd], 0, 0, 0);
      }
    }
    __builtin_amdgcn_s_setprio(0);
    __syncthreads();
  }

  float inv[4];
  #pragma unroll
  for (int r = 0; r < 4; r++) inv[r] = 1.f / l_run[r];
  #pragma unroll
  for (int fd = 0; fd < 4; fd++) {
    #pragma unroll
    for (int r = 0; r < 4; r++) {
      const long off =
          ((long)(b * kN + i0 + wid * 16 + g * 4 + r)) * kHid + h * kDh + fd * 16 + li;
      aob[off] = __float2bfloat16(o[fd][r] * inv[r]);
    }
  }
}

// ---------------- write out (dual dtype) ----------------
__global__ void k_out(const float* __restrict__ x, void* __restrict__ out,
                      const int* __restrict__ flag) {
  const int i = blockIdx.x * 256 + threadIdx.x;
  if (*flag) ((__hip_bfloat16*)out)[i] = __float2bfloat16(x[i]);
  else ((float*)out)[i] = x[i];
}

extern "C" void kernel_launch(void* const* d_in, const int* in_sizes, int n_in,
                              void* d_out, int out_size, void* d_ws, size_t ws_size,
                              hipStream_t stream) {
  const void* xin  = d_in[0];
  const void* timein = d_in[1];
  const void* seqm = d_in[2];
  const int*  ridx = (const int*)d_in[3];
  const void* rpw  = d_in[4];
  const void* rpb  = d_in[5];
  const void* ang  = d_in[6];
  const void* atw  = d_in[7];
  const void* atb  = d_in[8];
  const void* wq   = d_in[9];
  const void* wkv  = d_in[10];
  const void* wo   = d_in[11];
  const void* fng  = d_in[12];
  const void* ftw  = d_in[13];
  const void* ftb  = d_in[14];
  const void* wfi  = d_in[15];
  const void* bfi  = d_in[16];
  const void* wfo  = d_in[17];
  const void* bfo  = d_in[18];

  float* ws = (float*)d_ws;
  float* x     = ws;                 // 2,097,152 f32
  float* ascsh = ws + 2097152;       // 16,384  [D][B][2*kD]
  float* fscsh = ws + 2113536;       // 65,536  [D][B][2*kI]
  float* part  = ws + 2179072;       // 655,360 [D][8][B][5120]
  int*   flag  = (int*)(ws + 2834432);
  __hip_bfloat16* bfb = (__hip_bfloat16*)(ws + 2834496);
  __hip_bfloat16* xnb  = bfb;             // 2,097,152
  __hip_bfloat16* xb   = bfb + 2097152;   // 2,097,152
  __hip_bfloat16* aob  = bfb + 4194304;   // 2,097,152
  __hip_bfloat16* hb   = bfb + 6291456;   // 8,388,608
  __hip_bfloat16* qbuf = bfb + 14680064;  // 2,097,152
  __hip_bfloat16* kvb  = bfb + 16777216;  // 4,194,304
  __hip_bfloat16* wtq  = bfb + 20971520;  // 1,048,576 [D][512][512]
  __hip_bfloat16* wtkv = bfb + 22020096;  // 2,097,152 [D][1024][512]
  __hip_bfloat16* wto  = bfb + 24117248;  // 1,048,576 [D][512][512]
  __hip_bfloat16* wtfi = bfb + 25165824;  // 4,194,304 [D][2048][512]
  __hip_bfloat16* wtfo = bfb + 29360128;  // 4,194,304 [D][512][2048]

  k_detect<<<1, 64, 0, stream>>>(xin, flag);
  k_xinit<<<kBN * kD / 2048, 256, 0, stream>>>(xin, seqm, x, xb, flag);
  k_timeproj_part<<<dim3(20, 8, kDepth), 256, 0, stream>>>(timein, atw, ftw, part, flag);
  k_timeproj_comb<<<dim3(20, kDepth), 256, 0, stream>>>(part, atb, ftb, ascsh, fscsh, flag);
  k_wtall<<<3072, 256, 0, stream>>>(wq, wkv, wo, wfi, wfo, wtq, wtkv, wto, wtfi, wtfo, flag);

  for (int d = 0; d < kDepth; ++d) {
    k_ln<<<kBN / 4, 256, 0, stream>>>(x, ang, ascsh + (long)d * kB * 2 * kD, seqm, xnb, d, 1, flag);
    k_qkv<<<dim3(12, kBN / 64), 256, 0, stream>>>(
        xnb, xb, wtq + (long)d * kD * kHid, wtkv + (long)d * kD * 2 * kHid, qbuf, kvb);
    k_attn<<<dim3(kN / 64, kH, kB), 256, 0, stream>>>(qbuf, kvb, aob, rpw, rpb, seqm, ridx, flag);
    // x += (ao @ Wo) * mask
    k_mgemm<2><<<dim3(kD / 128, kBN / 64), 256, 0, stream>>>(
        aob, wto, (long)d * kHid * kD, kHid, kD, nullptr, x, nullptr,
        nullptr, 0, nullptr, seqm, flag);
    k_ln<<<kBN / 4, 256, 0, stream>>>(x, fng, nullptr, seqm, xnb, d, 0, flag);
    // h = silu(xn @ Wfi + b)*(sc+1)+sh
    k_mgemm<3><<<dim3(kI / 128, kBN / 64), 256, 0, stream>>>(
        xnb, wtfi, (long)d * kD * kI, kD, kI, hb, nullptr, nullptr,
        bfi, (long)d * kI, fscsh + (long)d * kB * 2 * kI, nullptr, flag);
    // x = (x + h @ Wfo + b)*mask ; xb = bf16(x)
    k_mgemm<4><<<dim3(kD / 128, kBN / 64), 256, 0, stream>>>(
        hb, wtfo, (long)d * kI * kD, kI, kD, nullptr, x, xb,
        bfo, (long)d * kD, nullptr, seqm, flag);
  }
  k_out<<<kBN * kD / 256, 256, 0, stream>>>(x, d_out, flag);
}

// Round 11
// 792.329 us; speedup vs baseline: 5.8240x; 1.0758x over previous
//
#include <hip/hip_runtime.h>
#include <hip/hip_bf16.h>

// Problem constants
constexpr int kB = 4, kN = 1024, kD = 512, kH = 8, kDh = 64, kT = 512;
constexpr int kHid = 512, kI = 2048, kRel = 65, kDepth = 4;
constexpr int kBN = kB * kN;

typedef short s16x8 __attribute__((ext_vector_type(8)));
typedef float f32x4 __attribute__((ext_vector_type(4)));

// ---------------- dual-dtype load helper ----------------
__device__ __forceinline__ float ldin(const void* p, long i, int isb) {
  if (isb) return __bfloat162float(((const __hip_bfloat16*)p)[i]);
  return ((const float*)p)[i];
}

__device__ __forceinline__ unsigned short bfbits(float v) {
  __hip_bfloat16 h = __float2bfloat16(v);
  return *(unsigned short*)&h;
}

// async global->LDS, 16B per lane. LDS dest must be wave-uniform base.
__device__ __forceinline__ void gload16(const void* g, void* l) {
  __builtin_amdgcn_global_load_lds(
      (const __attribute__((address_space(1))) unsigned int*)g,
      (__attribute__((address_space(3))) unsigned int*)l, 16, 0, 0);
}

// ---------------- dtype detect ----------------
__global__ void k_detect(const void* __restrict__ x, int* __restrict__ flag) {
  const unsigned int* u = (const unsigned int*)x;
  unsigned int v = u[threadIdx.x];
  int e = (v >> 7) & 0xFF;
  int good = (e >= 100 && e <= 140) ? 1 : 0;
  unsigned long long m = __ballot(good);
  if (threadIdx.x == 0) flag[0] = (__popcll(m) >= 48) ? 1 : 0;
}

// ---------------- x = x_in * mask (fp32 + bf16 copies) ----------------
__global__ void k_xinit(const void* __restrict__ xin, const void* __restrict__ seqm,
                        float* __restrict__ x, __hip_bfloat16* __restrict__ xb,
                        const int* __restrict__ flag) {
  const int isb = *flag;
  const long base = ((long)blockIdx.x * 256 + threadIdx.x) * 8;
  const int row = (int)(base >> 9);
  const float mk = ldin(seqm, row, isb);
  __align__(16) unsigned short pk[8];
  #pragma unroll
  for (int j = 0; j < 8; j++) {
    float v = ldin(xin, base + j, isb) * mk;
    x[base + j] = v;
    pk[j] = bfbits(v);
  }
  *(uint4*)(xb + base) = *(const uint4*)pk;
}

// ---------------- time projection, split-K partials ----------------
__global__ __launch_bounds__(256) void k_timeproj_part(
    const void* __restrict__ timein,
    const void* __restrict__ atw, const void* __restrict__ ftw,
    float* __restrict__ part, const int* __restrict__ flag) {
  const int isb = *flag;
  __shared__ float T[kB * 64];
  const int d = blockIdx.z, kc = blockIdx.y;
  const int tt0 = kc * 64;
  {
    const int b = threadIdx.x >> 6, ttl = threadIdx.x & 63;
    const float tv = ldin(timein, (long)b * kT + tt0 + ttl, isb);
    T[b * 64 + ttl] = tv / (1.f + __expf(-tv));
  }
  __syncthreads();
  const int c = blockIdx.x * 256 + threadIdx.x;
  float a0 = 0, a1 = 0, a2 = 0, a3 = 0;
  if (c < 2 * kD) {
    const long wo = (long)d * kT * 2 * kD + (long)tt0 * 2 * kD + c;
    #pragma unroll 4
    for (int tt = 0; tt < 64; tt++) {
      const float w = ldin(atw, wo + (long)tt * 2 * kD, isb);
      a0 += T[0 * 64 + tt] * w; a1 += T[1 * 64 + tt] * w;
      a2 += T[2 * 64 + tt] * w; a3 += T[3 * 64 + tt] * w;
    }
  } else {
    const int c2 = c - 2 * kD;
    const long wo = (long)d * kT * 2 * kI + (long)tt0 * 2 * kI + c2;
    #pragma unroll 4
    for (int tt = 0; tt < 64; tt++) {
      const float w = ldin(ftw, wo + (long)tt * 2 * kI, isb);
      a0 += T[0 * 64 + tt] * w; a1 += T[1 * 64 + tt] * w;
      a2 += T[2 * 64 + tt] * w; a3 += T[3 * 64 + tt] * w;
    }
  }
  float* pp = part + ((long)(d * 8 + kc) * 4) * 5120 + c;
  pp[0] = a0; pp[5120] = a1; pp[2 * 5120] = a2; pp[3 * 5120] = a3;
}

__global__ __launch_bounds__(256) void k_timeproj_comb(
    const float* __restrict__ part,
    const void* __restrict__ atb, const void* __restrict__ ftb,
    float* __restrict__ ascsh, float* __restrict__ fscsh,
    const int* __restrict__ flag) {
  const int isb = *flag;
  const int d = blockIdx.y;
  const int c = blockIdx.x * 256 + threadIdx.x;
  float s[4] = {0, 0, 0, 0};
  #pragma unroll
  for (int kc = 0; kc < 8; kc++) {
    const float* pp = part + ((long)(d * 8 + kc) * 4) * 5120 + c;
    s[0] += pp[0]; s[1] += pp[5120]; s[2] += pp[2 * 5120]; s[3] += pp[3 * 5120];
  }
  if (c < 2 * kD) {
    const float bv = ldin(atb, (long)d * 2 * kD + c, isb);
    #pragma unroll
    for (int b = 0; b < 4; b++) ascsh[((long)d * kB + b) * 2 * kD + c] = s[b] + bv;
  } else {
    const int c2 = c - 2 * kD;
    const float bv = ldin(ftb, (long)d * 2 * kI + c2, isb);
    #pragma unroll
    for (int b = 0; b < 4; b++) fscsh[((long)d * kB + b) * 2 * kI + c2] = s[b] + bv;
  }
}

// ---------------- fused weight transpose-convert (all 5 weights) ----------
__global__ __launch_bounds__(256) void k_wtall(
    const void* __restrict__ wq, const void* __restrict__ wkv,
    const void* __restrict__ wo, const void* __restrict__ wfi,
    const void* __restrict__ wfo,
    __hip_bfloat16* __restrict__ wtq, __hip_bfloat16* __restrict__ wtkv,
    __hip_bfloat16* __restrict__ wto, __hip_bfloat16* __restrict__ wtfi,
    __hip_bfloat16* __restrict__ wtfo, const int* __restrict__ flag) {
  const int isb = *flag;
  __shared__ float T[64][65];
  const int bx = blockIdx.x;
  const void* W; __hip_bfloat16* Wt; int K, N, tl;
  if (bx < 256)       { W = wq;  Wt = wtq;  K = 512;  N = 512;  tl = bx; }
  else if (bx < 768)  { W = wkv; Wt = wtkv; K = 512;  N = 1024; tl = bx - 256; }
  else if (bx < 1024) { W = wo;  Wt = wto;  K = 512;  N = 512;  tl = bx - 768; }
  else if (bx < 2048) { W = wfi; Wt = wtfi; K = 512;  N = 2048; tl = bx - 1024; }
  else                { W = wfo; Wt = wtfo; K = 2048; N = 512;  tl = bx - 2048; }
  const int nx = N >> 6, nk = K >> 6;
  const int z = tl / (nx * nk);
  const int rem = tl % (nx * nk);
  const int k0 = (rem / nx) * 64, n0 = (rem % nx) * 64;
  const long ibase = (long)z * K * N;
  const long obase = (long)z * N * K;
  const int t = threadIdx.x;
  const int cn = t & 63, r4 = t >> 6;
  for (int rr = r4; rr < 64; rr += 4)
    T[rr][cn] = ldin(W, ibase + (long)(k0 + rr) * N + n0 + cn, isb);
  __syncthreads();
  for (int nn = r4; nn < 64; nn += 4)
    Wt[obase + (long)(n0 + nn) * K + k0 + cn] = __float2bfloat16(T[cn][nn]);
}

// ---------------- LayerNorm -> bf16 out (+optional AdaLN mod + mask) --------
__global__ __launch_bounds__(256) void k_ln(
    const float* __restrict__ x, const void* __restrict__ g,
    const float* __restrict__ scsh, const void* __restrict__ seqm,
    __hip_bfloat16* __restrict__ xnb, int d, int domod, const int* __restrict__ flag) {
  const int isb = *flag;
  const int wid = threadIdx.x >> 6, lane = threadIdx.x & 63;
  const int row = blockIdx.x * 4 + wid;
  const int b = row >> 10;
  const float* xr = x + (long)row * kD + lane * 8;
  const float4 v0 = *(const float4*)xr;
  const float4 v1 = *(const float4*)(xr + 4);
  float v[8] = {v0.x, v0.y, v0.z, v0.w, v1.x, v1.y, v1.z, v1.w};
  float s = 0.f, s2 = 0.f;
  #pragma unroll
  for (int i = 0; i < 8; i++) { s += v[i]; s2 += v[i] * v[i]; }
  #pragma unroll
  for (int off = 1; off < 64; off <<= 1) { s += __shfl_xor(s, off); s2 += __shfl_xor(s2, off); }
  const float mean = s * (1.f / kD);
  const float var = fmaxf(s2 * (1.f / kD) - mean * mean, 0.f);
  const float rstd = rsqrtf(var + 1e-5f);
  float mk = 1.f;
  if (domod) mk = ldin(seqm, row, isb);
  __align__(16) unsigned short pk[8];
  #pragma unroll
  for (int i = 0; i < 8; i++) {
    const int cc = lane * 8 + i;
    float y = (v[i] - mean) * rstd * ldin(g, (long)d * kD + cc, isb);
    if (domod)
      y = (y * (scsh[(long)b * 2 * kD + cc] + 1.f) + scsh[(long)b * 2 * kD + kD + cc]) * mk;
    pk[i] = bfbits(y);
  }
  *(uint4*)(xnb + (long)row * kD + lane * 8) = *(const uint4*)pk;
}

// ======== bf16 MFMA GEMM, 2-phase double-buffered (BM=64, BN tmpl, BK=64) ====
// 4 waves (2m x 2n); wave tile 32 x BN/2; frags: 2 x (BN/32) of 16x16.
// LDS XOR-swizzle via inverse-swizzled global source; frag read at
// LDS[r][q ^ (r&7)] -> 2-way max conflicts.
// Pipeline: stage(t+1) issued BEFORE compute(t); ONE barrier per K-step.
// EPI: 2 out: X+=acc*mask   3 ffin: Cb=bf16(silu(acc+b)*(sc+1)+sh)
//      4 ffout: X=(X+acc+b)*mask, Xb=bf16(X)
template <int EPI, int BN>
__global__ __launch_bounds__(256) void k_mgemm(
    const __hip_bfloat16* __restrict__ A, const __hip_bfloat16* __restrict__ Wt,
    long woff, int K, int Nc,
    __hip_bfloat16* __restrict__ Cb,
    float* __restrict__ X, __hip_bfloat16* __restrict__ Xb,
    const void* __restrict__ bias, long boff,
    const float* __restrict__ scsh, const void* __restrict__ seqm,
    const int* __restrict__ flag) {
  constexpr int FN = BN / 32;   // B frags per wave
  const int isb = *flag;
  __shared__ __align__(16) short As[2][64 * 64];
  __shared__ __align__(16) short Bs[2][BN * 64];
  const int t = threadIdx.x;
  const int l = t & 63, wid = t >> 6;
  const int wm = wid & 1, wn = wid >> 1;
  const int lr = l >> 4, lc = l & 15;
  const int m0 = blockIdx.y * 64, n0 = blockIdx.x * BN;

  f32x4 acc[2][FN] = {};
  const int lrow8 = l >> 3;
  const int lchunk = (l & 7) ^ lrow8;
  const __hip_bfloat16* gA = A + (long)(m0 + wid * 8 + lrow8) * K + lchunk * 8;
  const __hip_bfloat16* gB = Wt + woff + (long)(n0 + wid * 8 + lrow8) * K + lchunk * 8;

  // prologue: stage tile 0 into buf 0
  #pragma unroll
  for (int p = 0; p < 2; p++)
    gload16(gA + (long)p * 32 * K, &As[0][p * 2048 + wid * 512]);
  #pragma unroll
  for (int p = 0; p < FN; p++)
    gload16(gB + (long)p * 32 * K, &Bs[0][p * 2048 + wid * 512]);
  __syncthreads();

  const int nt = K >> 6;
  int cur = 0;
  for (int tt = 0; tt < nt; tt++) {
    if (tt + 1 < nt) {
      const int k0 = (tt + 1) * 64;
      #pragma unroll
      for (int p = 0; p < 2; p++)
        gload16(gA + (long)p * 32 * K + k0, &As[cur ^ 1][p * 2048 + wid * 512]);
      #pragma unroll
      for (int p = 0; p < FN; p++)
        gload16(gB + (long)p * 32 * K + k0, &Bs[cur ^ 1][p * 2048 + wid * 512]);
    }
    #pragma unroll
    for (int kk = 0; kk < 2; kk++) {
      s16x8 af[2], bf[FN];
      #pragma unroll
      for (int fm = 0; fm < 2; fm++) {
        const int r = wm * 32 + fm * 16 + lc;
        af[fm] = *(const s16x8*)&As[cur][r * 64 + (((kk * 4 + lr) ^ (r & 7)) * 8)];
      }
      #pragma unroll
      for (int fn = 0; fn < FN; fn++) {
        const int r = wn * (BN / 2) + fn * 16 + lc;
        bf[fn] = *(const s16x8*)&Bs[cur][r * 64 + (((kk * 4 + lr) ^ (r & 7)) * 8)];
      }
      #pragma unroll
      for (int fm = 0; fm < 2; fm++)
        #pragma unroll
        for (int fn = 0; fn < FN; fn++)
          acc[fm][fn] = __builtin_amdgcn_mfma_f32_16x16x32_bf16(af[fm], bf[fn], acc[fm][fn], 0, 0, 0);
    }
    __syncthreads();
    cur ^= 1;
  }

  #pragma unroll
  for (int fm = 0; fm < 2; fm++) {
    #pragma unroll
    for (int j = 0; j < 4; j++) {
      const int r = m0 + wm * 32 + fm * 16 + lr * 4 + j;
      const int bb = r >> 10;
      float mk = 1.f;
      if constexpr (EPI == 2 || EPI == 4) mk = ldin(seqm, r, isb);
      #pragma unroll
      for (int fn = 0; fn < FN; fn++) {
        const int cc = n0 + wn * (BN / 2) + fn * 16 + lc;
        const long off = (long)r * Nc + cc;
        float v = acc[fm][fn][j];
        if constexpr (EPI == 2) {
          X[off] += v * mk;
        } else if constexpr (EPI == 3) {
          v += ldin(bias, boff + cc, isb);
          v = v / (1.f + __expf(-v));
          v = v * (scsh[(long)bb * 2 * kI + cc] + 1.f) + scsh[(long)bb * 2 * kI + kI + cc];
          Cb[off] = __float2bfloat16(v);
        } else {
          v += ldin(bias, boff + cc, isb);
          const float nx = (X[off] + v) * mk;
          X[off] = nx;
          Xb[off] = __float2bfloat16(nx);
        }
      }
    }
  }
}

// ---------------- fused q + kv GEMM, 2-phase (one launch, 768 blocks) ------
// blockIdx.x<4: q = bf16((xn @ Wq)*0.125); else kv = bf16(x @ Wkv). K=512.
__global__ __launch_bounds__(256) void k_qkv(
    const __hip_bfloat16* __restrict__ xnb, const __hip_bfloat16* __restrict__ xb,
    const __hip_bfloat16* __restrict__ wtq, const __hip_bfloat16* __restrict__ wtkv,
    __hip_bfloat16* __restrict__ qbuf, __hip_bfloat16* __restrict__ kvb) {
  constexpr int K = kD;
  __shared__ __align__(16) short As[2][64 * 64];
  __shared__ __align__(16) short Bs[2][128 * 64];
  const int t = threadIdx.x;
  const int l = t & 63, wid = t >> 6;
  const int wm = wid & 1, wn = wid >> 1;
  const int lr = l >> 4, lc = l & 15;
  const int m0 = blockIdx.y * 64;

  const __hip_bfloat16* A; const __hip_bfloat16* Wt; __hip_bfloat16* C;
  int Nc, n0; float scale;
  if (blockIdx.x < 4) {
    A = xnb; Wt = wtq; C = qbuf; Nc = kHid; n0 = blockIdx.x * 128; scale = 0.125f;
  } else {
    A = xb; Wt = wtkv; C = kvb; Nc = 2 * kHid; n0 = (blockIdx.x - 4) * 128; scale = 1.f;
  }

  f32x4 acc[2][4] = {};
  const int lrow8 = l >> 3;
  const int lchunk = (l & 7) ^ lrow8;
  const __hip_bfloat16* gA = A + (long)(m0 + wid * 8 + lrow8) * K + lchunk * 8;
  const __hip_bfloat16* gB = Wt + (long)(n0 + wid * 8 + lrow8) * K + lchunk * 8;

  #pragma unroll
  for (int p = 0; p < 2; p++)
    gload16(gA + (long)p * 32 * K, &As[0][p * 2048 + wid * 512]);
  #pragma unroll
  for (int p = 0; p < 4; p++)
    gload16(gB + (long)p * 32 * K, &Bs[0][p * 2048 + wid * 512]);
  __syncthreads();

  const int nt = K >> 6;
  int cur = 0;
  for (int tt = 0; tt < nt; tt++) {
    if (tt + 1 < nt) {
      const int k0 = (tt + 1) * 64;
      #pragma unroll
      for (int p = 0; p < 2; p++)
        gload16(gA + (long)p * 32 * K + k0, &As[cur ^ 1][p * 2048 + wid * 512]);
      #pragma unroll
      for (int p = 0; p < 4; p++)
        gload16(gB + (long)p * 32 * K + k0, &Bs[cur ^ 1][p * 2048 + wid * 512]);
    }
    #pragma unroll
    for (int kk = 0; kk < 2; kk++) {
      s16x8 af[2], bf[4];
      #pragma unroll
      for (int fm = 0; fm < 2; fm++) {
        const int r = wm * 32 + fm * 16 + lc;
        af[fm] = *(const s16x8*)&As[cur][r * 64 + (((kk * 4 + lr) ^ (r & 7)) * 8)];
      }
      #pragma unroll
      for (int fn = 0; fn < 4; fn++) {
        const int r = wn * 64 + fn * 16 + lc;
        bf[fn] = *(const s16x8*)&Bs[cur][r * 64 + (((kk * 4 + lr) ^ (r & 7)) * 8)];
      }
      #pragma unroll
      for (int fm = 0; fm < 2; fm++)
        #pragma unroll
        for (int fn = 0; fn < 4; fn++)
          acc[fm][fn] = __builtin_amdgcn_mfma_f32_16x16x32_bf16(af[fm], bf[fn], acc[fm][fn], 0, 0, 0);
    }
    __syncthreads();
    cur ^= 1;
  }

  #pragma unroll
  for (int fm = 0; fm < 2; fm++)
    #pragma unroll
    for (int j = 0; j < 4; j++) {
      const int r = m0 + wm * 32 + fm * 16 + lr * 4 + j;
      #pragma unroll
      for (int fn = 0; fn < 4; fn++) {
        const int cc = n0 + wn * 64 + fn * 16 + lc;
        C[(long)r * Nc + cc] = __float2bfloat16(acc[fm][fn][j] * scale);
      }
    }
}

// ---------------- MFMA flash attention, double-buffered + XCD swizzle ------
// 1D grid 512 blocks; swizzled so the 16 blocks sharing (b,h) KV land on one
// XCD. Per block: 64 q-rows, 4 waves x 16 rows. K/V LDS double-buffered:
// stage(t+1) issued before compute(t); V ds_write deferred after compute.
__global__ __launch_bounds__(256) void k_attn(
    const __hip_bfloat16* __restrict__ qb, const __hip_bfloat16* __restrict__ kvb,
    __hip_bfloat16* __restrict__ aob,
    const void* __restrict__ rpw, const void* __restrict__ rpb,
    const void* __restrict__ seqm, const int* __restrict__ ridx,
    const int* __restrict__ flag) {
  const int isb = *flag;
  const int t = threadIdx.x;
  // bijective XCD chunk swizzle: 512 blocks = 8 XCDs x 64
  const int bid = blockIdx.x;
  const int swz = (bid & 7) * 64 + (bid >> 3);
  const int x = swz & 15, h = (swz >> 4) & 7, b = swz >> 7;
  const int i0 = x * 64;

  __shared__ __align__(16) short Ks[2][64 * 64];   // swizzled: elem d at d^((j&7)*8)
  __shared__ __align__(16) short Vt[2][64 * 72];   // Vt[d][j], rows padded to 72
  __shared__ __align__(16) short Ps[4][16 * 72];   // per-wave P, rows padded to 72
  __shared__ float biasw[kRel];
  __shared__ int riq[64];
  __shared__ float mkq[64];
  __shared__ int rik[2][64];
  __shared__ float mkk[2][64];

  const int l = t & 63, wid = t >> 6;
  const int g = l >> 4, li = l & 15;

  if (t < kRel) biasw[t] = ldin(rpw, (long)t * kH + h, isb) + ldin(rpb, h, isb);
  if (t < 64) { riq[t] = ridx[b * kN + i0 + t]; mkq[t] = ldin(seqm, b * kN + i0 + t, isb); }

  const __hip_bfloat16* qptr =
      qb + ((long)(b * kN + i0 + wid * 16 + li)) * kHid + h * kDh + g * 8;
  s16x8 aq[2];
  aq[0] = *(const s16x8*)qptr;
  aq[1] = *(const s16x8*)(qptr + 32);

  // ---- stage tile 0 into buffer 0 ----
  {
    #pragma unroll
    for (int p = 0; p < 2; p++) {
      const int j = p * 32 + wid * 8 + (l >> 3);
      const short* gk = (const short*)kvb + ((long)(b * kN + j)) * 1024 + h * 64 +
                        (((l & 7) ^ (l >> 3)) * 8);
      gload16(gk, &Ks[0][p * 2048 + wid * 512]);
    }
    const short* gv = (const short*)kvb + ((long)(b * kN + l)) * 1024 + 512 + h * 64 + wid * 16;
    s16x8 v0 = *(const s16x8*)gv;
    s16x8 v1 = *(const s16x8*)(gv + 8);
    #pragma unroll
    for (int dd = 0; dd < 8; dd++) {
      Vt[0][(wid * 16 + dd) * 72 + l] = v0[dd];
      Vt[0][(wid * 16 + 8 + dd) * 72 + l] = v1[dd];
    }
    if (t < 64) { rik[0][t] = ridx[b * kN + t]; mkk[0][t] = ldin(seqm, b * kN + t, isb); }
  }
  __syncthreads();

  float mkqv[4]; int riqv[4];
  #pragma unroll
  for (int r = 0; r < 4; r++) {
    riqv[r] = riq[wid * 16 + g * 4 + r];
    mkqv[r] = mkq[wid * 16 + g * 4 + r];
  }

  float m_run[4] = {-1e30f, -1e30f, -1e30f, -1e30f};
  float l_run[4] = {0.f, 0.f, 0.f, 0.f};
  f32x4 o[4] = {};

  constexpr int NT = kN / 64;  // 16
  int cur = 0;
  for (int tt = 0; tt < NT; tt++) {
    // ---- issue stage for tile tt+1 into buf cur^1 (before compute) ----
    s16x8 nv0, nv1;
    int nri = 0; float nmk = 0.f;
    const bool have = (tt + 1) < NT;
    if (have) {
      const int j0n = (tt + 1) * 64;
      #pragma unroll
      for (int p = 0; p < 2; p++) {
        const int j = p * 32 + wid * 8 + (l >> 3);
        const short* gk = (const short*)kvb + ((long)(b * kN + j0n + j)) * 1024 + h * 64 +
                          (((l & 7) ^ (l >> 3)) * 8);
        gload16(gk, &Ks[cur ^ 1][p * 2048 + wid * 512]);
      }
      const short* gv =
          (const short*)kvb + ((long)(b * kN + j0n + l)) * 1024 + 512 + h * 64 + wid * 16;
      nv0 = *(const s16x8*)gv;
      nv1 = *(const s16x8*)(gv + 8);
      if (t < 64) { nri = ridx[b * kN + j0n + t]; nmk = ldin(seqm, b * kN + j0n + t, isb); }
    }

    // ---- compute on buf cur ----
    f32x4 s[4] = {};
    __builtin_amdgcn_s_setprio(1);
    #pragma unroll
    for (int kc = 0; kc < 2; kc++) {
      #pragma unroll
      for (int fc = 0; fc < 4; fc++) {
        const int jl = fc * 16 + li;
        const s16x8 bk = *(const s16x8*)&Ks[cur][jl * 64 + ((kc * 32 + g * 8) ^ ((li & 7) * 8))];
        s[fc] = __builtin_amdgcn_mfma_f32_16x16x32_bf16(aq[kc], bk, s[fc], 0, 0, 0);
      }
    }
    __builtin_amdgcn_s_setprio(0);

    int rikv[4]; float mkkv[4];
    #pragma unroll
    for (int fc = 0; fc < 4; fc++) {
      rikv[fc] = rik[cur][fc * 16 + li];
      mkkv[fc] = mkk[cur][fc * 16 + li];
    }
    #pragma unroll
    for (int fc = 0; fc < 4; fc++) {
      #pragma unroll
      for (int r = 0; r < 4; r++) {
        int di = riqv[r] - rikv[fc];
        di = di < -32 ? -32 : (di > 32 ? 32 : di);
        s[fc][r] += biasw[di + 32] - (1.f - mkqv[r] * mkkv[fc]) * 1e6f;
      }
    }

    #pragma unroll
    for (int r = 0; r < 4; r++) {
      float mx = fmaxf(fmaxf(s[0][r], s[1][r]), fmaxf(s[2][r], s[3][r]));
      mx = fmaxf(mx, __shfl_xor(mx, 1));
      mx = fmaxf(mx, __shfl_xor(mx, 2));
      mx = fmaxf(mx, __shfl_xor(mx, 4));
      mx = fmaxf(mx, __shfl_xor(mx, 8));
      const float m_new = fmaxf(m_run[r], mx);
      const float e = __expf(m_run[r] - m_new);
      float ps = 0.f;
      #pragma unroll
      for (int fc = 0; fc < 4; fc++) {
        const float p = __expf(s[fc][r] - m_new);
        ps += p;
        Ps[wid][(g * 4 + r) * 72 + fc * 16 + li] = (short)bfbits(p);
      }
      ps += __shfl_xor(ps, 1);
      ps += __shfl_xor(ps, 2);
      ps += __shfl_xor(ps, 4);
      ps += __shfl_xor(ps, 8);
      l_run[r] = l_run[r] * e + ps;
      m_run[r] = m_new;
      o[0][r] *= e; o[1][r] *= e; o[2][r] *= e; o[3][r] *= e;
    }

    __builtin_amdgcn_s_setprio(1);
    #pragma unroll
    for (int kc = 0; kc < 2; kc++) {
      const s16x8 pa = *(const s16x8*)&Ps[wid][li * 72 + kc * 32 + g * 8];
      #pragma unroll
      for (int fd = 0; fd < 4; fd++) {
        const s16x8 bv = *(const s16x8*)&Vt[cur][(fd * 16 + li) * 72 + kc * 32 + g * 8];
        o[fd] = __builtin_amdgcn_mfma_f32_16x16x32_bf16(pa, bv, o[fd], 0, 0, 0);
      }
    }
    __builtin_amdgcn_s_setprio(0);

    // ---- deferred writes of staged tile (V + metadata) ----
    if (have) {
      #pragma unroll
      for (int dd = 0; dd < 8; dd++) {
        Vt[cur ^ 1][(wid * 16 + dd) * 72 + l] = nv0[dd];
        Vt[cur ^ 1][(wid * 16 + 8 + dd) * 72 + l] = nv1[dd];
      }
      if (t < 64) { rik[cur ^ 1][t] = nri; mkk[cur ^ 1][t] = nmk; }
    }
    __syncthreads();
    cur ^= 1;
  }

  float inv[4];
  #pragma unroll
  for (int r = 0; r < 4; r++) inv[r] = 1.f / l_run[r];
  #pragma unroll
  for (int fd = 0; fd < 4; fd++) {
    #pragma unroll
    for (int r = 0; r < 4; r++) {
      const long off =
          ((long)(b * kN + i0 + wid * 16 + g * 4 + r)) * kHid + h * kDh + fd * 16 + li;
      aob[off] = __float2bfloat16(o[fd][r] * inv[r]);
    }
  }
}

// ---------------- write out (dual dtype) ----------------
__global__ void k_out(const float* __restrict__ x, void* __restrict__ out,
                      const int* __restrict__ flag) {
  const int i = blockIdx.x * 256 + threadIdx.x;
  if (*flag) ((__hip_bfloat16*)out)[i] = __float2bfloat16(x[i]);
  else ((float*)out)[i] = x[i];
}

extern "C" void kernel_launch(void* const* d_in, const int* in_sizes, int n_in,
                              void* d_out, int out_size, void* d_ws, size_t ws_size,
                              hipStream_t stream) {
  const void* xin  = d_in[0];
  const void* timein = d_in[1];
  const void* seqm = d_in[2];
  const int*  ridx = (const int*)d_in[3];
  const void* rpw  = d_in[4];
  const void* rpb  = d_in[5];
  const void* ang  = d_in[6];
  const void* atw  = d_in[7];
  const void* atb  = d_in[8];
  const void* wq   = d_in[9];
  const void* wkv  = d_in[10];
  const void* wo   = d_in[11];
  const void* fng  = d_in[12];
  const void* ftw  = d_in[13];
  const void* ftb  = d_in[14];
  const void* wfi  = d_in[15];
  const void* bfi  = d_in[16];
  const void* wfo  = d_in[17];
  const void* bfo  = d_in[18];

  float* ws = (float*)d_ws;
  float* x     = ws;                 // 2,097,152 f32
  float* ascsh = ws + 2097152;       // 16,384  [D][B][2*kD]
  float* fscsh = ws + 2113536;       // 65,536  [D][B][2*kI]
  float* part  = ws + 2179072;       // 655,360 [D][8][B][5120]
  int*   flag  = (int*)(ws + 2834432);
  __hip_bfloat16* bfb = (__hip_bfloat16*)(ws + 2834496);
  __hip_bfloat16* xnb  = bfb;             // 2,097,152
  __hip_bfloat16* xb   = bfb + 2097152;   // 2,097,152
  __hip_bfloat16* aob  = bfb + 4194304;   // 2,097,152
  __hip_bfloat16* hb   = bfb + 6291456;   // 8,388,608
  __hip_bfloat16* qbuf = bfb + 14680064;  // 2,097,152
  __hip_bfloat16* kvb  = bfb + 16777216;  // 4,194,304
  __hip_bfloat16* wtq  = bfb + 20971520;  // 1,048,576 [D][512][512]
  __hip_bfloat16* wtkv = bfb + 22020096;  // 2,097,152 [D][1024][512]
  __hip_bfloat16* wto  = bfb + 24117248;  // 1,048,576 [D][512][512]
  __hip_bfloat16* wtfi = bfb + 25165824;  // 4,194,304 [D][2048][512]
  __hip_bfloat16* wtfo = bfb + 29360128;  // 4,194,304 [D][512][2048]

  k_detect<<<1, 64, 0, stream>>>(xin, flag);
  k_xinit<<<kBN * kD / 2048, 256, 0, stream>>>(xin, seqm, x, xb, flag);
  k_timeproj_part<<<dim3(20, 8, kDepth), 256, 0, stream>>>(timein, atw, ftw, part, flag);
  k_timeproj_comb<<<dim3(20, kDepth), 256, 0, stream>>>(part, atb, ftb, ascsh, fscsh, flag);
  k_wtall<<<3072, 256, 0, stream>>>(wq, wkv, wo, wfi, wfo, wtq, wtkv, wto, wtfi, wtfo, flag);

  for (int d = 0; d < kDepth; ++d) {
    k_ln<<<kBN / 4, 256, 0, stream>>>(x, ang, ascsh + (long)d * kB * 2 * kD, seqm, xnb, d, 1, flag);
    k_qkv<<<dim3(12, kBN / 64), 256, 0, stream>>>(
        xnb, xb, wtq + (long)d * kD * kHid, wtkv + (long)d * kD * 2 * kHid, qbuf, kvb);
    k_attn<<<512, 256, 0, stream>>>(qbuf, kvb, aob, rpw, rpb, seqm, ridx, flag);
    // x += (ao @ Wo) * mask
    k_mgemm<2, 64><<<dim3(kD / 64, kBN / 64), 256, 0, stream>>>(
        aob, wto, (long)d * kHid * kD, kHid, kD, nullptr, x, nullptr,
        nullptr, 0, nullptr, seqm, flag);
    k_ln<<<kBN / 4, 256, 0, stream>>>(x, fng, nullptr, seqm, xnb, d, 0, flag);
    // h = silu(xn @ Wfi + b)*(sc+1)+sh
    k_mgemm<3, 128><<<dim3(kI / 128, kBN / 64), 256, 0, stream>>>(
        xnb, wtfi, (long)d * kD * kI, kD, kI, hb, nullptr, nullptr,
        bfi, (long)d * kI, fscsh + (long)d * kB * 2 * kI, nullptr, flag);
    // x = (x + h @ Wfo + b)*mask ; xb = bf16(x)
    k_mgemm<4, 64><<<dim3(kD / 64, kBN / 64), 256, 0, stream>>>(
        hb, wtfo, (long)d * kI * kD, kI, kD, nullptr, x, xb,
        bfo, (long)d * kD, nullptr, seqm, flag);
  }
  k_out<<<kBN * kD / 256, 256, 0, stream>>>(x, d_out, flag);
}

// Round 14
// 768.488 us; speedup vs baseline: 6.0047x; 1.0310x over previous
//
#include <hip/hip_runtime.h>
#include <hip/hip_bf16.h>

// Problem constants
constexpr int kB = 4, kN = 1024, kD = 512, kH = 8, kDh = 64, kT = 512;
constexpr int kHid = 512, kI = 2048, kRel = 65, kDepth = 4;
constexpr int kBN = kB * kN;

typedef short s16x8 __attribute__((ext_vector_type(8)));
typedef float f32x4 __attribute__((ext_vector_type(4)));

// ---------------- dual-dtype load helper ----------------
__device__ __forceinline__ float ldin(const void* p, long i, int isb) {
  if (isb) return __bfloat162float(((const __hip_bfloat16*)p)[i]);
  return ((const float*)p)[i];
}

__device__ __forceinline__ unsigned short bfbits(float v) {
  __hip_bfloat16 h = __float2bfloat16(v);
  return *(unsigned short*)&h;
}

// async global->LDS, 16B per lane. LDS dest must be wave-uniform base.
__device__ __forceinline__ void gload16(const void* g, void* l) {
  __builtin_amdgcn_global_load_lds(
      (const __attribute__((address_space(1))) unsigned int*)g,
      (__attribute__((address_space(3))) unsigned int*)l, 16, 0, 0);
}

// ---------------- dtype detect ----------------
__global__ void k_detect(const void* __restrict__ x, int* __restrict__ flag) {
  const unsigned int* u = (const unsigned int*)x;
  unsigned int v = u[threadIdx.x];
  int e = (v >> 7) & 0xFF;
  int good = (e >= 100 && e <= 140) ? 1 : 0;
  unsigned long long m = __ballot(good);
  if (threadIdx.x == 0) flag[0] = (__popcll(m) >= 48) ? 1 : 0;
}

// ---------------- x = x_in * mask (fp32 + bf16 copies) ----------------
__global__ void k_xinit(const void* __restrict__ xin, const void* __restrict__ seqm,
                        float* __restrict__ x, __hip_bfloat16* __restrict__ xb,
                        const int* __restrict__ flag) {
  const int isb = *flag;
  const long base = ((long)blockIdx.x * 256 + threadIdx.x) * 8;
  const int row = (int)(base >> 9);
  const float mk = ldin(seqm, row, isb);
  __align__(16) unsigned short pk[8];
  #pragma unroll
  for (int j = 0; j < 8; j++) {
    float v = ldin(xin, base + j, isb) * mk;
    x[base + j] = v;
    pk[j] = bfbits(v);
  }
  *(uint4*)(xb + base) = *(const uint4*)pk;
}

// ---------------- time projection, split-K partials ----------------
__global__ __launch_bounds__(256) void k_timeproj_part(
    const void* __restrict__ timein,
    const void* __restrict__ atw, const void* __restrict__ ftw,
    float* __restrict__ part, const int* __restrict__ flag) {
  const int isb = *flag;
  __shared__ float T[kB * 64];
  const int d = blockIdx.z, kc = blockIdx.y;
  const int tt0 = kc * 64;
  {
    const int b = threadIdx.x >> 6, ttl = threadIdx.x & 63;
    const float tv = ldin(timein, (long)b * kT + tt0 + ttl, isb);
    T[b * 64 + ttl] = tv / (1.f + __expf(-tv));
  }
  __syncthreads();
  const int c = blockIdx.x * 256 + threadIdx.x;
  float a0 = 0, a1 = 0, a2 = 0, a3 = 0;
  if (c < 2 * kD) {
    const long wo = (long)d * kT * 2 * kD + (long)tt0 * 2 * kD + c;
    #pragma unroll 4
    for (int tt = 0; tt < 64; tt++) {
      const float w = ldin(atw, wo + (long)tt * 2 * kD, isb);
      a0 += T[0 * 64 + tt] * w; a1 += T[1 * 64 + tt] * w;
      a2 += T[2 * 64 + tt] * w; a3 += T[3 * 64 + tt] * w;
    }
  } else {
    const int c2 = c - 2 * kD;
    const long wo = (long)d * kT * 2 * kI + (long)tt0 * 2 * kI + c2;
    #pragma unroll 4
    for (int tt = 0; tt < 64; tt++) {
      const float w = ldin(ftw, wo + (long)tt * 2 * kI, isb);
      a0 += T[0 * 64 + tt] * w; a1 += T[1 * 64 + tt] * w;
      a2 += T[2 * 64 + tt] * w; a3 += T[3 * 64 + tt] * w;
    }
  }
  float* pp = part + ((long)(d * 8 + kc) * 4) * 5120 + c;
  pp[0] = a0; pp[5120] = a1; pp[2 * 5120] = a2; pp[3 * 5120] = a3;
}

__global__ __launch_bounds__(256) void k_timeproj_comb(
    const float* __restrict__ part,
    const void* __restrict__ atb, const void* __restrict__ ftb,
    float* __restrict__ ascsh, float* __restrict__ fscsh,
    const int* __restrict__ flag) {
  const int isb = *flag;
  const int d = blockIdx.y;
  const int c = blockIdx.x * 256 + threadIdx.x;
  float s[4] = {0, 0, 0, 0};
  #pragma unroll
  for (int kc = 0; kc < 8; kc++) {
    const float* pp = part + ((long)(d * 8 + kc) * 4) * 5120 + c;
    s[0] += pp[0]; s[1] += pp[5120]; s[2] += pp[2 * 5120]; s[3] += pp[3 * 5120];
  }
  if (c < 2 * kD) {
    const float bv = ldin(atb, (long)d * 2 * kD + c, isb);
    #pragma unroll
    for (int b = 0; b < 4; b++) ascsh[((long)d * kB + b) * 2 * kD + c] = s[b] + bv;
  } else {
    const int c2 = c - 2 * kD;
    const float bv = ldin(ftb, (long)d * 2 * kI + c2, isb);
    #pragma unroll
    for (int b = 0; b < 4; b++) fscsh[((long)d * kB + b) * 2 * kI + c2] = s[b] + bv;
  }
}

// ---------------- fused weight transpose-convert (all 5 weights) ----------
__global__ __launch_bounds__(256) void k_wtall(
    const void* __restrict__ wq, const void* __restrict__ wkv,
    const void* __restrict__ wo, const void* __restrict__ wfi,
    const void* __restrict__ wfo,
    __hip_bfloat16* __restrict__ wtq, __hip_bfloat16* __restrict__ wtkv,
    __hip_bfloat16* __restrict__ wto, __hip_bfloat16* __restrict__ wtfi,
    __hip_bfloat16* __restrict__ wtfo, const int* __restrict__ flag) {
  const int isb = *flag;
  __shared__ float T[64][65];
  const int bx = blockIdx.x;
  const void* W; __hip_bfloat16* Wt; int K, N, tl;
  if (bx < 256)       { W = wq;  Wt = wtq;  K = 512;  N = 512;  tl = bx; }
  else if (bx < 768)  { W = wkv; Wt = wtkv; K = 512;  N = 1024; tl = bx - 256; }
  else if (bx < 1024) { W = wo;  Wt = wto;  K = 512;  N = 512;  tl = bx - 768; }
  else if (bx < 2048) { W = wfi; Wt = wtfi; K = 512;  N = 2048; tl = bx - 1024; }
  else                { W = wfo; Wt = wtfo; K = 2048; N = 512;  tl = bx - 2048; }
  const int nx = N >> 6, nk = K >> 6;
  const int z = tl / (nx * nk);
  const int rem = tl % (nx * nk);
  const int k0 = (rem / nx) * 64, n0 = (rem % nx) * 64;
  const long ibase = (long)z * K * N;
  const long obase = (long)z * N * K;
  const int t = threadIdx.x;
  const int cn = t & 63, r4 = t >> 6;
  for (int rr = r4; rr < 64; rr += 4)
    T[rr][cn] = ldin(W, ibase + (long)(k0 + rr) * N + n0 + cn, isb);
  __syncthreads();
  for (int nn = r4; nn < 64; nn += 4)
    Wt[obase + (long)(n0 + nn) * K + k0 + cn] = __float2bfloat16(T[cn][nn]);
}

// ---------------- LayerNorm -> bf16 out (+optional AdaLN mod + mask) --------
__global__ __launch_bounds__(256) void k_ln(
    const float* __restrict__ x, const void* __restrict__ g,
    const float* __restrict__ scsh, const void* __restrict__ seqm,
    __hip_bfloat16* __restrict__ xnb, int d, int domod, const int* __restrict__ flag) {
  const int isb = *flag;
  const int wid = threadIdx.x >> 6, lane = threadIdx.x & 63;
  const int row = blockIdx.x * 4 + wid;
  const int b = row >> 10;
  const float* xr = x + (long)row * kD + lane * 8;
  const float4 v0 = *(const float4*)xr;
  const float4 v1 = *(const float4*)(xr + 4);
  float v[8] = {v0.x, v0.y, v0.z, v0.w, v1.x, v1.y, v1.z, v1.w};
  float s = 0.f, s2 = 0.f;
  #pragma unroll
  for (int i = 0; i < 8; i++) { s += v[i]; s2 += v[i] * v[i]; }
  #pragma unroll
  for (int off = 1; off < 64; off <<= 1) { s += __shfl_xor(s, off); s2 += __shfl_xor(s2, off); }
  const float mean = s * (1.f / kD);
  const float var = fmaxf(s2 * (1.f / kD) - mean * mean, 0.f);
  const float rstd = rsqrtf(var + 1e-5f);
  float mk = 1.f;
  if (domod) mk = ldin(seqm, row, isb);
  __align__(16) unsigned short pk[8];
  #pragma unroll
  for (int i = 0; i < 8; i++) {
    const int cc = lane * 8 + i;
    float y = (v[i] - mean) * rstd * ldin(g, (long)d * kD + cc, isb);
    if (domod)
      y = (y * (scsh[(long)b * 2 * kD + cc] + 1.f) + scsh[(long)b * 2 * kD + kD + cc]) * mk;
    pk[i] = bfbits(y);
  }
  *(uint4*)(xnb + (long)row * kD + lane * 8) = *(const uint4*)pk;
}

// ======== bf16 MFMA GEMM, 2-phase double-buffered (BM=64, BN tmpl, BK=64) ====
template <int EPI, int BN>
__global__ __launch_bounds__(256) void k_mgemm(
    const __hip_bfloat16* __restrict__ A, const __hip_bfloat16* __restrict__ Wt,
    long woff, int K, int Nc,
    __hip_bfloat16* __restrict__ Cb,
    float* __restrict__ X, __hip_bfloat16* __restrict__ Xb,
    const void* __restrict__ bias, long boff,
    const float* __restrict__ scsh, const void* __restrict__ seqm,
    const int* __restrict__ flag) {
  constexpr int FN = BN / 32;   // B frags per wave
  const int isb = *flag;
  __shared__ __align__(16) short As[2][64 * 64];
  __shared__ __align__(16) short Bs[2][BN * 64];
  const int t = threadIdx.x;
  const int l = t & 63, wid = t >> 6;
  const int wm = wid & 1, wn = wid >> 1;
  const int lr = l >> 4, lc = l & 15;
  const int m0 = blockIdx.y * 64, n0 = blockIdx.x * BN;

  f32x4 acc[2][FN] = {};
  const int lrow8 = l >> 3;
  const int lchunk = (l & 7) ^ lrow8;
  const __hip_bfloat16* gA = A + (long)(m0 + wid * 8 + lrow8) * K + lchunk * 8;
  const __hip_bfloat16* gB = Wt + woff + (long)(n0 + wid * 8 + lrow8) * K + lchunk * 8;

  #pragma unroll
  for (int p = 0; p < 2; p++)
    gload16(gA + (long)p * 32 * K, &As[0][p * 2048 + wid * 512]);
  #pragma unroll
  for (int p = 0; p < FN; p++)
    gload16(gB + (long)p * 32 * K, &Bs[0][p * 2048 + wid * 512]);
  __syncthreads();

  const int nt = K >> 6;
  int cur = 0;
  for (int tt = 0; tt < nt; tt++) {
    if (tt + 1 < nt) {
      const int k0 = (tt + 1) * 64;
      #pragma unroll
      for (int p = 0; p < 2; p++)
        gload16(gA + (long)p * 32 * K + k0, &As[cur ^ 1][p * 2048 + wid * 512]);
      #pragma unroll
      for (int p = 0; p < FN; p++)
        gload16(gB + (long)p * 32 * K + k0, &Bs[cur ^ 1][p * 2048 + wid * 512]);
    }
    #pragma unroll
    for (int kk = 0; kk < 2; kk++) {
      s16x8 af[2], bf[FN];
      #pragma unroll
      for (int fm = 0; fm < 2; fm++) {
        const int r = wm * 32 + fm * 16 + lc;
        af[fm] = *(const s16x8*)&As[cur][r * 64 + (((kk * 4 + lr) ^ (r & 7)) * 8)];
      }
      #pragma unroll
      for (int fn = 0; fn < FN; fn++) {
        const int r = wn * (BN / 2) + fn * 16 + lc;
        bf[fn] = *(const s16x8*)&Bs[cur][r * 64 + (((kk * 4 + lr) ^ (r & 7)) * 8)];
      }
      #pragma unroll
      for (int fm = 0; fm < 2; fm++)
        #pragma unroll
        for (int fn = 0; fn < FN; fn++)
          acc[fm][fn] = __builtin_amdgcn_mfma_f32_16x16x32_bf16(af[fm], bf[fn], acc[fm][fn], 0, 0, 0);
    }
    __syncthreads();
    cur ^= 1;
  }

  #pragma unroll
  for (int fm = 0; fm < 2; fm++) {
    #pragma unroll
    for (int j = 0; j < 4; j++) {
      const int r = m0 + wm * 32 + fm * 16 + lr * 4 + j;
      const int bb = r >> 10;
      float mk = 1.f;
      if constexpr (EPI == 2 || EPI == 4) mk = ldin(seqm, r, isb);
      #pragma unroll
      for (int fn = 0; fn < FN; fn++) {
        const int cc = n0 + wn * (BN / 2) + fn * 16 + lc;
        const long off = (long)r * Nc + cc;
        float v = acc[fm][fn][j];
        if constexpr (EPI == 2) {
          X[off] += v * mk;
        } else if constexpr (EPI == 3) {
          v += ldin(bias, boff + cc, isb);
          v = v / (1.f + __expf(-v));
          v = v * (scsh[(long)bb * 2 * kI + cc] + 1.f) + scsh[(long)bb * 2 * kI + kI + cc];
          Cb[off] = __float2bfloat16(v);
        } else {
          v += ldin(bias, boff + cc, isb);
          const float nx = (X[off] + v) * mk;
          X[off] = nx;
          Xb[off] = __float2bfloat16(nx);
        }
      }
    }
  }
}

// ---------------- fused q + kv GEMM, 2-phase, BN=64 (grid (24, 64)) --------
// blockIdx.x<8: q = bf16((xn @ Wq)*0.125); else kv = bf16(x @ Wkv). K=512.
__global__ __launch_bounds__(256) void k_qkv(
    const __hip_bfloat16* __restrict__ xnb, const __hip_bfloat16* __restrict__ xb,
    const __hip_bfloat16* __restrict__ wtq, const __hip_bfloat16* __restrict__ wtkv,
    __hip_bfloat16* __restrict__ qbuf, __hip_bfloat16* __restrict__ kvb) {
  constexpr int K = kD;
  __shared__ __align__(16) short As[2][64 * 64];
  __shared__ __align__(16) short Bs[2][64 * 64];
  const int t = threadIdx.x;
  const int l = t & 63, wid = t >> 6;
  const int wm = wid & 1, wn = wid >> 1;
  const int lr = l >> 4, lc = l & 15;
  const int m0 = blockIdx.y * 64;

  const __hip_bfloat16* A; const __hip_bfloat16* Wt; __hip_bfloat16* C;
  int Nc, n0; float scale;
  if (blockIdx.x < 8) {
    A = xnb; Wt = wtq; C = qbuf; Nc = kHid; n0 = blockIdx.x * 64; scale = 0.125f;
  } else {
    A = xb; Wt = wtkv; C = kvb; Nc = 2 * kHid; n0 = (blockIdx.x - 8) * 64; scale = 1.f;
  }

  f32x4 acc[2][2] = {};
  const int lrow8 = l >> 3;
  const int lchunk = (l & 7) ^ lrow8;
  const __hip_bfloat16* gA = A + (long)(m0 + wid * 8 + lrow8) * K + lchunk * 8;
  const __hip_bfloat16* gB = Wt + (long)(n0 + wid * 8 + lrow8) * K + lchunk * 8;

  #pragma unroll
  for (int p = 0; p < 2; p++) {
    gload16(gA + (long)p * 32 * K, &As[0][p * 2048 + wid * 512]);
    gload16(gB + (long)p * 32 * K, &Bs[0][p * 2048 + wid * 512]);
  }
  __syncthreads();

  const int nt = K >> 6;
  int cur = 0;
  for (int tt = 0; tt < nt; tt++) {
    if (tt + 1 < nt) {
      const int k0 = (tt + 1) * 64;
      #pragma unroll
      for (int p = 0; p < 2; p++) {
        gload16(gA + (long)p * 32 * K + k0, &As[cur ^ 1][p * 2048 + wid * 512]);
        gload16(gB + (long)p * 32 * K + k0, &Bs[cur ^ 1][p * 2048 + wid * 512]);
      }
    }
    #pragma unroll
    for (int kk = 0; kk < 2; kk++) {
      s16x8 af[2], bf[2];
      #pragma unroll
      for (int fm = 0; fm < 2; fm++) {
        const int r = wm * 32 + fm * 16 + lc;
        af[fm] = *(const s16x8*)&As[cur][r * 64 + (((kk * 4 + lr) ^ (r & 7)) * 8)];
      }
      #pragma unroll
      for (int fn = 0; fn < 2; fn++) {
        const int r = wn * 32 + fn * 16 + lc;
        bf[fn] = *(const s16x8*)&Bs[cur][r * 64 + (((kk * 4 + lr) ^ (r & 7)) * 8)];
      }
      #pragma unroll
      for (int fm = 0; fm < 2; fm++)
        #pragma unroll
        for (int fn = 0; fn < 2; fn++)
          acc[fm][fn] = __builtin_amdgcn_mfma_f32_16x16x32_bf16(af[fm], bf[fn], acc[fm][fn], 0, 0, 0);
    }
    __syncthreads();
    cur ^= 1;
  }

  #pragma unroll
  for (int fm = 0; fm < 2; fm++)
    #pragma unroll
    for (int j = 0; j < 4; j++) {
      const int r = m0 + wm * 32 + fm * 16 + lr * 4 + j;
      #pragma unroll
      for (int fn = 0; fn < 2; fn++) {
        const int cc = n0 + wn * 32 + fn * 16 + lc;
        C[(long)r * Nc + cc] = __float2bfloat16(acc[fm][fn][j] * scale);
      }
    }
}

// ---------------- MFMA flash attention: 8-wave blocks, split-j -------------
// grid 512 blocks x 512 threads. logical = (((b*8+h)*8)+x)*2 + jh;
// XCD swizzle: swz = (bid&7)*64 + (bid>>3). Block: 128 q-rows (8 waves x 16),
// j-range [jh*512, jh*512+512). Writes UNNORMALIZED o (f32) + per-row (m,l).
__global__ __launch_bounds__(512) void k_attn(
    const __hip_bfloat16* __restrict__ qb, const __hip_bfloat16* __restrict__ kvb,
    float* __restrict__ opart, float* __restrict__ mpart, float* __restrict__ lpart,
    const void* __restrict__ rpw, const void* __restrict__ rpb,
    const void* __restrict__ seqm, const int* __restrict__ ridx,
    const int* __restrict__ flag) {
  const int isb = *flag;
  const int t = threadIdx.x;
  const int bid = blockIdx.x;
  const int swz = (bid & 7) * 64 + (bid >> 3);
  const int jh = swz & 1, x = (swz >> 1) & 7, h = (swz >> 4) & 7, b = swz >> 7;
  const int i0 = x * 128;
  const int jbase = jh * 512;

  __shared__ __align__(16) short Ks[2][64 * 64];   // swizzled: elem d at d^((j&7)*8)
  __shared__ __align__(16) short Vt[2][64 * 72];   // Vt[d][j], rows padded to 72
  __shared__ __align__(16) short Ps[8][16 * 72];   // per-wave P, rows padded to 72
  __shared__ float biasw[kRel];
  __shared__ int riq[128];
  __shared__ float mkq[128];
  __shared__ int rik[2][64];
  __shared__ float mkk[2][64];

  const int l = t & 63, wid = t >> 6;       // wid 0..7
  const int g = l >> 4, li = l & 15;

  if (t < kRel) biasw[t] = ldin(rpw, (long)t * kH + h, isb) + ldin(rpb, h, isb);
  if (t < 128) { riq[t] = ridx[b * kN + i0 + t]; mkq[t] = ldin(seqm, b * kN + i0 + t, isb); }

  const __hip_bfloat16* qptr =
      qb + ((long)(b * kN + i0 + wid * 16 + li)) * kHid + h * kDh + g * 8;
  s16x8 aq[2];
  aq[0] = *(const s16x8*)qptr;
  aq[1] = *(const s16x8*)(qptr + 32);

  // ---- stage tile 0 into buffer 0 ----
  {
    const int j = wid * 8 + (l >> 3);
    const short* gk = (const short*)kvb + ((long)(b * kN + jbase + j)) * 1024 + h * 64 +
                      (((l & 7) ^ (l >> 3)) * 8);
    gload16(gk, &Ks[0][wid * 512]);
    const short* gv =
        (const short*)kvb + ((long)(b * kN + jbase + l)) * 1024 + 512 + h * 64 + wid * 8;
    s16x8 v0 = *(const s16x8*)gv;
    #pragma unroll
    for (int dd = 0; dd < 8; dd++) Vt[0][(wid * 8 + dd) * 72 + l] = v0[dd];
    if (t < 64) {
      rik[0][t] = ridx[b * kN + jbase + t];
      mkk[0][t] = ldin(seqm, b * kN + jbase + t, isb);
    }
  }
  __syncthreads();

  float mkqv[4]; int riqv[4];
  #pragma unroll
  for (int r = 0; r < 4; r++) {
    riqv[r] = riq[wid * 16 + g * 4 + r];
    mkqv[r] = mkq[wid * 16 + g * 4 + r];
  }

  float m_run[4] = {-1e30f, -1e30f, -1e30f, -1e30f};
  float l_run[4] = {0.f, 0.f, 0.f, 0.f};
  f32x4 o[4] = {};

  constexpr int NT = 8;   // 512 / 64
  int cur = 0;
  for (int tt = 0; tt < NT; tt++) {
    // ---- issue stage for tile tt+1 into buf cur^1 (before compute) ----
    s16x8 nv0;
    int nri = 0; float nmk = 0.f;
    const bool have = (tt + 1) < NT;
    if (have) {
      const int j0n = jbase + (tt + 1) * 64;
      const int j = wid * 8 + (l >> 3);
      const short* gk = (const short*)kvb + ((long)(b * kN + j0n + j)) * 1024 + h * 64 +
                        (((l & 7) ^ (l >> 3)) * 8);
      gload16(gk, &Ks[cur ^ 1][wid * 512]);
      const short* gv =
          (const short*)kvb + ((long)(b * kN + j0n + l)) * 1024 + 512 + h * 64 + wid * 8;
      nv0 = *(const s16x8*)gv;
      if (t < 64) { nri = ridx[b * kN + j0n + t]; nmk = ldin(seqm, b * kN + j0n + t, isb); }
    }

    // ---- compute on buf cur ----
    f32x4 s[4] = {};
    __builtin_amdgcn_s_setprio(1);
    #pragma unroll
    for (int kc = 0; kc < 2; kc++) {
      #pragma unroll
      for (int fc = 0; fc < 4; fc++) {
        const int jl = fc * 16 + li;
        const s16x8 bk = *(const s16x8*)&Ks[cur][jl * 64 + ((kc * 32 + g * 8) ^ ((li & 7) * 8))];
        s[fc] = __builtin_amdgcn_mfma_f32_16x16x32_bf16(aq[kc], bk, s[fc], 0, 0, 0);
      }
    }
    __builtin_amdgcn_s_setprio(0);

    int rikv[4]; float mkkv[4];
    #pragma unroll
    for (int fc = 0; fc < 4; fc++) {
      rikv[fc] = rik[cur][fc * 16 + li];
      mkkv[fc] = mkk[cur][fc * 16 + li];
    }
    #pragma unroll
    for (int fc = 0; fc < 4; fc++) {
      #pragma unroll
      for (int r = 0; r < 4; r++) {
        int di = riqv[r] - rikv[fc];
        di = di < -32 ? -32 : (di > 32 ? 32 : di);
        s[fc][r] += biasw[di + 32] - (1.f - mkqv[r] * mkkv[fc]) * 1e6f;
      }
    }

    #pragma unroll
    for (int r = 0; r < 4; r++) {
      float mx = fmaxf(fmaxf(s[0][r], s[1][r]), fmaxf(s[2][r], s[3][r]));
      mx = fmaxf(mx, __shfl_xor(mx, 1));
      mx = fmaxf(mx, __shfl_xor(mx, 2));
      mx = fmaxf(mx, __shfl_xor(mx, 4));
      mx = fmaxf(mx, __shfl_xor(mx, 8));
      const float m_new = fmaxf(m_run[r], mx);
      const float e = __expf(m_run[r] - m_new);
      float ps = 0.f;
      #pragma unroll
      for (int fc = 0; fc < 4; fc++) {
        const float p = __expf(s[fc][r] - m_new);
        ps += p;
        Ps[wid][(g * 4 + r) * 72 + fc * 16 + li] = (short)bfbits(p);
      }
      ps += __shfl_xor(ps, 1);
      ps += __shfl_xor(ps, 2);
      ps += __shfl_xor(ps, 4);
      ps += __shfl_xor(ps, 8);
      l_run[r] = l_run[r] * e + ps;
      m_run[r] = m_new;
      o[0][r] *= e; o[1][r] *= e; o[2][r] *= e; o[3][r] *= e;
    }

    __builtin_amdgcn_s_setprio(1);
    #pragma unroll
    for (int kc = 0; kc < 2; kc++) {
      const s16x8 pa = *(const s16x8*)&Ps[wid][li * 72 + kc * 32 + g * 8];
      #pragma unroll
      for (int fd = 0; fd < 4; fd++) {
        const s16x8 bv = *(const s16x8*)&Vt[cur][(fd * 16 + li) * 72 + kc * 32 + g * 8];
        o[fd] = __builtin_amdgcn_mfma_f32_16x16x32_bf16(pa, bv, o[fd], 0, 0, 0);
      }
    }
    __builtin_amdgcn_s_setprio(0);

    // ---- deferred writes of staged tile (V + metadata) ----
    if (have) {
      #pragma unroll
      for (int dd = 0; dd < 8; dd++) Vt[cur ^ 1][(wid * 8 + dd) * 72 + l] = nv0[dd];
      if (t < 64) { rik[cur ^ 1][t] = nri; mkk[cur ^ 1][t] = nmk; }
    }
    __syncthreads();
    cur ^= 1;
  }

  // ---- write unnormalized O (f32) + per-row m,l ----
  #pragma unroll
  for (int fd = 0; fd < 4; fd++) {
    #pragma unroll
    for (int r = 0; r < 4; r++) {
      const long off =
          ((long)(b * kN + i0 + wid * 16 + g * 4 + r)) * kHid + h * kDh + fd * 16 + li;
      opart[(long)jh * 2097152 + off] = o[fd][r];
    }
  }
  if (li == 0) {
    #pragma unroll
    for (int r = 0; r < 4; r++) {
      const int row = i0 + wid * 16 + g * 4 + r;
      const int idx = (b * kN + row) * 8 + h;
      mpart[jh * 32768 + idx] = m_run[r];
      lpart[jh * 32768 + idx] = l_run[r];
    }
  }
}

// ---------------- combine the two j-halves -> aob (bf16) ----------------
__global__ __launch_bounds__(256) void k_acomb(
    const float* __restrict__ opart, const float* __restrict__ mpart,
    const float* __restrict__ lpart, __hip_bfloat16* __restrict__ aob) {
  const long e = ((long)blockIdx.x * 256 + threadIdx.x) * 8;
  const int h = (int)((e >> 6) & 7);
  const int row = (int)(e >> 9);
  const int idx = row * 8 + h;
  const float m0 = mpart[idx], m1 = mpart[32768 + idx];
  const float l0 = lpart[idx], l1 = lpart[32768 + idx];
  const float mm = fmaxf(m0, m1);
  const float e0 = __expf(m0 - mm), e1 = __expf(m1 - mm);
  const float den = fmaxf(e0 * l0 + e1 * l1, 1e-30f);
  const float s0 = e0 / den, s1 = e1 / den;
  const float4 a0 = *(const float4*)(opart + e);
  const float4 a1 = *(const float4*)(opart + e + 4);
  const float4 b0 = *(const float4*)(opart + 2097152 + e);
  const float4 b1 = *(const float4*)(opart + 2097152 + e + 4);
  __align__(16) unsigned short pk[8];
  pk[0] = bfbits(a0.x * s0 + b0.x * s1);
  pk[1] = bfbits(a0.y * s0 + b0.y * s1);
  pk[2] = bfbits(a0.z * s0 + b0.z * s1);
  pk[3] = bfbits(a0.w * s0 + b0.w * s1);
  pk[4] = bfbits(a1.x * s0 + b1.x * s1);
  pk[5] = bfbits(a1.y * s0 + b1.y * s1);
  pk[6] = bfbits(a1.z * s0 + b1.z * s1);
  pk[7] = bfbits(a1.w * s0 + b1.w * s1);
  *(uint4*)(aob + e) = *(const uint4*)pk;
}

// ---------------- write out (dual dtype) ----------------
__global__ void k_out(const float* __restrict__ x, void* __restrict__ out,
                      const int* __restrict__ flag) {
  const int i = blockIdx.x * 256 + threadIdx.x;
  if (*flag) ((__hip_bfloat16*)out)[i] = __float2bfloat16(x[i]);
  else ((float*)out)[i] = x[i];
}

extern "C" void kernel_launch(void* const* d_in, const int* in_sizes, int n_in,
                              void* d_out, int out_size, void* d_ws, size_t ws_size,
                              hipStream_t stream) {
  const void* xin  = d_in[0];
  const void* timein = d_in[1];
  const void* seqm = d_in[2];
  const int*  ridx = (const int*)d_in[3];
  const void* rpw  = d_in[4];
  const void* rpb  = d_in[5];
  const void* ang  = d_in[6];
  const void* atw  = d_in[7];
  const void* atb  = d_in[8];
  const void* wq   = d_in[9];
  const void* wkv  = d_in[10];
  const void* wo   = d_in[11];
  const void* fng  = d_in[12];
  const void* ftw  = d_in[13];
  const void* ftb  = d_in[14];
  const void* wfi  = d_in[15];
  const void* bfi  = d_in[16];
  const void* wfo  = d_in[17];
  const void* bfo  = d_in[18];

  float* ws = (float*)d_ws;
  float* x     = ws;                 // 2,097,152 f32
  float* ascsh = ws + 2097152;       // 16,384  [D][B][2*kD]
  float* fscsh = ws + 2113536;       // 65,536  [D][B][2*kI]
  float* part  = ws + 2179072;       // 655,360; reused as attn m/l after timeproj
  int*   flag  = (int*)(ws + 2834432);
  __hip_bfloat16* bfb = (__hip_bfloat16*)(ws + 2834496);
  __hip_bfloat16* xnb  = bfb;             // 2,097,152
  __hip_bfloat16* xb   = bfb + 2097152;   // 2,097,152
  __hip_bfloat16* aob  = bfb + 4194304;   // 2,097,152
  __hip_bfloat16* hb   = bfb + 6291456;   // 8,388,608 (reused as attn opart f32)
  __hip_bfloat16* qbuf = bfb + 14680064;  // 2,097,152
  __hip_bfloat16* kvb  = bfb + 16777216;  // 4,194,304
  __hip_bfloat16* wtq  = bfb + 20971520;  // 1,048,576 [D][512][512]
  __hip_bfloat16* wtkv = bfb + 22020096;  // 2,097,152 [D][1024][512]
  __hip_bfloat16* wto  = bfb + 24117248;  // 1,048,576 [D][512][512]
  __hip_bfloat16* wtfi = bfb + 25165824;  // 4,194,304 [D][2048][512]
  __hip_bfloat16* wtfo = bfb + 29360128;  // 4,194,304 [D][512][2048]
  float* opart = (float*)hb;              // 2 x 2,097,152 f32 (16.78 MB = hb size)
  float* mpart = part;                    // 2 x 32,768
  float* lpart = part + 65536;            // 2 x 32,768

  k_detect<<<1, 64, 0, stream>>>(xin, flag);
  k_xinit<<<kBN * kD / 2048, 256, 0, stream>>>(xin, seqm, x, xb, flag);
  k_timeproj_part<<<dim3(20, 8, kDepth), 256, 0, stream>>>(timein, atw, ftw, part, flag);
  k_timeproj_comb<<<dim3(20, kDepth), 256, 0, stream>>>(part, atb, ftb, ascsh, fscsh, flag);
  k_wtall<<<3072, 256, 0, stream>>>(wq, wkv, wo, wfi, wfo, wtq, wtkv, wto, wtfi, wtfo, flag);

  for (int d = 0; d < kDepth; ++d) {
    k_ln<<<kBN / 4, 256, 0, stream>>>(x, ang, ascsh + (long)d * kB * 2 * kD, seqm, xnb, d, 1, flag);
    k_qkv<<<dim3(24, kBN / 64), 256, 0, stream>>>(
        xnb, xb, wtq + (long)d * kD * kHid, wtkv + (long)d * kD * 2 * kHid, qbuf, kvb);
    k_attn<<<512, 512, 0, stream>>>(qbuf, kvb, opart, mpart, lpart, rpw, rpb, seqm, ridx, flag);
    k_acomb<<<1024, 256, 0, stream>>>(opart, mpart, lpart, aob);
    // x += (ao @ Wo) * mask
    k_mgemm<2, 64><<<dim3(kD / 64, kBN / 64), 256, 0, stream>>>(
        aob, wto, (long)d * kHid * kD, kHid, kD, nullptr, x, nullptr,
        nullptr, 0, nullptr, seqm, flag);
    k_ln<<<kBN / 4, 256, 0, stream>>>(x, fng, nullptr, seqm, xnb, d, 0, flag);
    // h = silu(xn @ Wfi + b)*(sc+1)+sh
    k_mgemm<3, 64><<<dim3(kI / 64, kBN / 64), 256, 0, stream>>>(
        xnb, wtfi, (long)d * kD * kI, kD, kI, hb, nullptr, nullptr,
        bfi, (long)d * kI, fscsh + (long)d * kB * 2 * kI, nullptr, flag);
    // x = (x + h @ Wfo + b)*mask ; xb = bf16(x)
    k_mgemm<4, 64><<<dim3(kD / 64, kBN / 64), 256, 0, stream>>>(
        hb, wtfo, (long)d * kI * kD, kI, kD, nullptr, x, xb,
        bfo, (long)d * kD, nullptr, seqm, flag);
  }
  k_out<<<kBN * kD / 256, 256, 0, stream>>>(x, d_out, flag);
}

// Round 15
// 736.521 us; speedup vs baseline: 6.2653x; 1.0434x over previous
//
#include <hip/hip_runtime.h>
#include <hip/hip_bf16.h>

// Problem constants
constexpr int kB = 4, kN = 1024, kD = 512, kH = 8, kDh = 64, kT = 512;
constexpr int kHid = 512, kI = 2048, kRel = 65, kDepth = 4;
constexpr int kBN = kB * kN;

typedef short s16x8 __attribute__((ext_vector_type(8)));
typedef float f32x4 __attribute__((ext_vector_type(4)));

// ---------------- dual-dtype load helper ----------------
__device__ __forceinline__ float ldin(const void* p, long i, int isb) {
  if (isb) return __bfloat162float(((const __hip_bfloat16*)p)[i]);
  return ((const float*)p)[i];
}

__device__ __forceinline__ unsigned short bfbits(float v) {
  __hip_bfloat16 h = __float2bfloat16(v);
  return *(unsigned short*)&h;
}

// async global->LDS, 16B per lane. LDS dest must be wave-uniform base.
__device__ __forceinline__ void gload16(const void* g, void* l) {
  __builtin_amdgcn_global_load_lds(
      (const __attribute__((address_space(1))) unsigned int*)g,
      (__attribute__((address_space(3))) unsigned int*)l, 16, 0, 0);
}

// ---------------- dtype detect ----------------
__global__ void k_detect(const void* __restrict__ x, int* __restrict__ flag) {
  const unsigned int* u = (const unsigned int*)x;
  unsigned int v = u[threadIdx.x];
  int e = (v >> 7) & 0xFF;
  int good = (e >= 100 && e <= 140) ? 1 : 0;
  unsigned long long m = __ballot(good);
  if (threadIdx.x == 0) flag[0] = (__popcll(m) >= 48) ? 1 : 0;
}

// ---------------- x = x_in * mask (fp32 + bf16 copies) ----------------
__global__ void k_xinit(const void* __restrict__ xin, const void* __restrict__ seqm,
                        float* __restrict__ x, __hip_bfloat16* __restrict__ xb,
                        const int* __restrict__ flag) {
  const int isb = *flag;
  const long base = ((long)blockIdx.x * 256 + threadIdx.x) * 8;
  const int row = (int)(base >> 9);
  const float mk = ldin(seqm, row, isb);
  __align__(16) unsigned short pk[8];
  #pragma unroll
  for (int j = 0; j < 8; j++) {
    float v = ldin(xin, base + j, isb) * mk;
    x[base + j] = v;
    pk[j] = bfbits(v);
  }
  *(uint4*)(xb + base) = *(const uint4*)pk;
}

// ---------------- time projection, split-K partials ----------------
__global__ __launch_bounds__(256) void k_timeproj_part(
    const void* __restrict__ timein,
    const void* __restrict__ atw, const void* __restrict__ ftw,
    float* __restrict__ part, const int* __restrict__ flag) {
  const int isb = *flag;
  __shared__ float T[kB * 64];
  const int d = blockIdx.z, kc = blockIdx.y;
  const int tt0 = kc * 64;
  {
    const int b = threadIdx.x >> 6, ttl = threadIdx.x & 63;
    const float tv = ldin(timein, (long)b * kT + tt0 + ttl, isb);
    T[b * 64 + ttl] = tv / (1.f + __expf(-tv));
  }
  __syncthreads();
  const int c = blockIdx.x * 256 + threadIdx.x;
  float a0 = 0, a1 = 0, a2 = 0, a3 = 0;
  if (c < 2 * kD) {
    const long wo = (long)d * kT * 2 * kD + (long)tt0 * 2 * kD + c;
    #pragma unroll 4
    for (int tt = 0; tt < 64; tt++) {
      const float w = ldin(atw, wo + (long)tt * 2 * kD, isb);
      a0 += T[0 * 64 + tt] * w; a1 += T[1 * 64 + tt] * w;
      a2 += T[2 * 64 + tt] * w; a3 += T[3 * 64 + tt] * w;
    }
  } else {
    const int c2 = c - 2 * kD;
    const long wo = (long)d * kT * 2 * kI + (long)tt0 * 2 * kI + c2;
    #pragma unroll 4
    for (int tt = 0; tt < 64; tt++) {
      const float w = ldin(ftw, wo + (long)tt * 2 * kI, isb);
      a0 += T[0 * 64 + tt] * w; a1 += T[1 * 64 + tt] * w;
      a2 += T[2 * 64 + tt] * w; a3 += T[3 * 64 + tt] * w;
    }
  }
  float* pp = part + ((long)(d * 8 + kc) * 4) * 5120 + c;
  pp[0] = a0; pp[5120] = a1; pp[2 * 5120] = a2; pp[3 * 5120] = a3;
}

__global__ __launch_bounds__(256) void k_timeproj_comb(
    const float* __restrict__ part,
    const void* __restrict__ atb, const void* __restrict__ ftb,
    float* __restrict__ ascsh, float* __restrict__ fscsh,
    const int* __restrict__ flag) {
  const int isb = *flag;
  const int d = blockIdx.y;
  const int c = blockIdx.x * 256 + threadIdx.x;
  float s[4] = {0, 0, 0, 0};
  #pragma unroll
  for (int kc = 0; kc < 8; kc++) {
    const float* pp = part + ((long)(d * 8 + kc) * 4) * 5120 + c;
    s[0] += pp[0]; s[1] += pp[5120]; s[2] += pp[2 * 5120]; s[3] += pp[3 * 5120];
  }
  if (c < 2 * kD) {
    const float bv = ldin(atb, (long)d * 2 * kD + c, isb);
    #pragma unroll
    for (int b = 0; b < 4; b++) ascsh[((long)d * kB + b) * 2 * kD + c] = s[b] + bv;
  } else {
    const int c2 = c - 2 * kD;
    const float bv = ldin(ftb, (long)d * 2 * kI + c2, isb);
    #pragma unroll
    for (int b = 0; b < 4; b++) fscsh[((long)d * kB + b) * 2 * kI + c2] = s[b] + bv;
  }
}

// ---------------- fused weight transpose-convert (all 5 weights) ----------
__global__ __launch_bounds__(256) void k_wtall(
    const void* __restrict__ wq, const void* __restrict__ wkv,
    const void* __restrict__ wo, const void* __restrict__ wfi,
    const void* __restrict__ wfo,
    __hip_bfloat16* __restrict__ wtq, __hip_bfloat16* __restrict__ wtkv,
    __hip_bfloat16* __restrict__ wto, __hip_bfloat16* __restrict__ wtfi,
    __hip_bfloat16* __restrict__ wtfo, const int* __restrict__ flag) {
  const int isb = *flag;
  __shared__ float T[64][65];
  const int bx = blockIdx.x;
  const void* W; __hip_bfloat16* Wt; int K, N, tl;
  if (bx < 256)       { W = wq;  Wt = wtq;  K = 512;  N = 512;  tl = bx; }
  else if (bx < 768)  { W = wkv; Wt = wtkv; K = 512;  N = 1024; tl = bx - 256; }
  else if (bx < 1024) { W = wo;  Wt = wto;  K = 512;  N = 512;  tl = bx - 768; }
  else if (bx < 2048) { W = wfi; Wt = wtfi; K = 512;  N = 2048; tl = bx - 1024; }
  else                { W = wfo; Wt = wtfo; K = 2048; N = 512;  tl = bx - 2048; }
  const int nx = N >> 6, nk = K >> 6;
  const int z = tl / (nx * nk);
  const int rem = tl % (nx * nk);
  const int k0 = (rem / nx) * 64, n0 = (rem % nx) * 64;
  const long ibase = (long)z * K * N;
  const long obase = (long)z * N * K;
  const int t = threadIdx.x;
  const int cn = t & 63, r4 = t >> 6;
  for (int rr = r4; rr < 64; rr += 4)
    T[rr][cn] = ldin(W, ibase + (long)(k0 + rr) * N + n0 + cn, isb);
  __syncthreads();
  for (int nn = r4; nn < 64; nn += 4)
    Wt[obase + (long)(n0 + nn) * K + k0 + cn] = __float2bfloat16(T[cn][nn]);
}

// ---------------- LayerNorm -> bf16 out (+optional AdaLN mod + mask) --------
__global__ __launch_bounds__(256) void k_ln(
    const float* __restrict__ x, const void* __restrict__ g,
    const float* __restrict__ scsh, const void* __restrict__ seqm,
    __hip_bfloat16* __restrict__ xnb, int d, int domod, const int* __restrict__ flag) {
  const int isb = *flag;
  const int wid = threadIdx.x >> 6, lane = threadIdx.x & 63;
  const int row = blockIdx.x * 4 + wid;
  const int b = row >> 10;
  const float* xr = x + (long)row * kD + lane * 8;
  const float4 v0 = *(const float4*)xr;
  const float4 v1 = *(const float4*)(xr + 4);
  float v[8] = {v0.x, v0.y, v0.z, v0.w, v1.x, v1.y, v1.z, v1.w};
  float s = 0.f, s2 = 0.f;
  #pragma unroll
  for (int i = 0; i < 8; i++) { s += v[i]; s2 += v[i] * v[i]; }
  #pragma unroll
  for (int off = 1; off < 64; off <<= 1) { s += __shfl_xor(s, off); s2 += __shfl_xor(s2, off); }
  const float mean = s * (1.f / kD);
  const float var = fmaxf(s2 * (1.f / kD) - mean * mean, 0.f);
  const float rstd = rsqrtf(var + 1e-5f);
  float mk = 1.f;
  if (domod) mk = ldin(seqm, row, isb);
  __align__(16) unsigned short pk[8];
  #pragma unroll
  for (int i = 0; i < 8; i++) {
    const int cc = lane * 8 + i;
    float y = (v[i] - mean) * rstd * ldin(g, (long)d * kD + cc, isb);
    if (domod)
      y = (y * (scsh[(long)b * 2 * kD + cc] + 1.f) + scsh[(long)b * 2 * kD + kD + cc]) * mk;
    pk[i] = bfbits(y);
  }
  *(uint4*)(xnb + (long)row * kD + lane * 8) = *(const uint4*)pk;
}

// ======== bf16 MFMA GEMM, 2-phase double-buffered (BM=64, BN tmpl, BK=64) ====
// EPI: 2 out: X+=acc*mask   4 ffout: X=(X+acc+b)*mask, Xb=bf16(X)
template <int EPI, int BN>
__global__ __launch_bounds__(256) void k_mgemm(
    const __hip_bfloat16* __restrict__ A, const __hip_bfloat16* __restrict__ Wt,
    long woff, int K, int Nc,
    __hip_bfloat16* __restrict__ Cb,
    float* __restrict__ X, __hip_bfloat16* __restrict__ Xb,
    const void* __restrict__ bias, long boff,
    const float* __restrict__ scsh, const void* __restrict__ seqm,
    const int* __restrict__ flag) {
  constexpr int FN = BN / 32;   // B frags per wave
  const int isb = *flag;
  __shared__ __align__(16) short As[2][64 * 64];
  __shared__ __align__(16) short Bs[2][BN * 64];
  const int t = threadIdx.x;
  const int l = t & 63, wid = t >> 6;
  const int wm = wid & 1, wn = wid >> 1;
  const int lr = l >> 4, lc = l & 15;
  const int m0 = blockIdx.y * 64, n0 = blockIdx.x * BN;

  f32x4 acc[2][FN] = {};
  const int lrow8 = l >> 3;
  const int lchunk = (l & 7) ^ lrow8;
  const __hip_bfloat16* gA = A + (long)(m0 + wid * 8 + lrow8) * K + lchunk * 8;
  const __hip_bfloat16* gB = Wt + woff + (long)(n0 + wid * 8 + lrow8) * K + lchunk * 8;

  #pragma unroll
  for (int p = 0; p < 2; p++)
    gload16(gA + (long)p * 32 * K, &As[0][p * 2048 + wid * 512]);
  #pragma unroll
  for (int p = 0; p < FN; p++)
    gload16(gB + (long)p * 32 * K, &Bs[0][p * 2048 + wid * 512]);
  __syncthreads();

  const int nt = K >> 6;
  int cur = 0;
  for (int tt = 0; tt < nt; tt++) {
    if (tt + 1 < nt) {
      const int k0 = (tt + 1) * 64;
      #pragma unroll
      for (int p = 0; p < 2; p++)
        gload16(gA + (long)p * 32 * K + k0, &As[cur ^ 1][p * 2048 + wid * 512]);
      #pragma unroll
      for (int p = 0; p < FN; p++)
        gload16(gB + (long)p * 32 * K + k0, &Bs[cur ^ 1][p * 2048 + wid * 512]);
    }
    #pragma unroll
    for (int kk = 0; kk < 2; kk++) {
      s16x8 af[2], bf[FN];
      #pragma unroll
      for (int fm = 0; fm < 2; fm++) {
        const int r = wm * 32 + fm * 16 + lc;
        af[fm] = *(const s16x8*)&As[cur][r * 64 + (((kk * 4 + lr) ^ (r & 7)) * 8)];
      }
      #pragma unroll
      for (int fn = 0; fn < FN; fn++) {
        const int r = wn * (BN / 2) + fn * 16 + lc;
        bf[fn] = *(const s16x8*)&Bs[cur][r * 64 + (((kk * 4 + lr) ^ (r & 7)) * 8)];
      }
      #pragma unroll
      for (int fm = 0; fm < 2; fm++)
        #pragma unroll
        for (int fn = 0; fn < FN; fn++)
          acc[fm][fn] = __builtin_amdgcn_mfma_f32_16x16x32_bf16(af[fm], bf[fn], acc[fm][fn], 0, 0, 0);
    }
    __syncthreads();
    cur ^= 1;
  }

  #pragma unroll
  for (int fm = 0; fm < 2; fm++) {
    #pragma unroll
    for (int j = 0; j < 4; j++) {
      const int r = m0 + wm * 32 + fm * 16 + lr * 4 + j;
      float mk = 1.f;
      if constexpr (EPI == 2 || EPI == 4) mk = ldin(seqm, r, isb);
      #pragma unroll
      for (int fn = 0; fn < FN; fn++) {
        const int cc = n0 + wn * (BN / 2) + fn * 16 + lc;
        const long off = (long)r * Nc + cc;
        float v = acc[fm][fn][j];
        if constexpr (EPI == 2) {
          X[off] += v * mk;
        } else {
          v += ldin(bias, boff + cc, isb);
          const float nx = (X[off] + v) * mk;
          X[off] = nx;
          Xb[off] = __float2bfloat16(nx);
        }
      }
    }
  }
}

// ======== 8-wave bf16 MFMA GEMM, BM=128, BN=128, BK=64, 2-phase ==========
// 512 threads = 8 waves (2m x 4n); wave tile 64x32 = 4x2 frags of 16x16.
// 16 MFMA per K-step per wave. LDS 64KB -> 2 blocks/CU.
// EPI 3: Cb = bf16(silu(acc+b)*(sc+1)+sh)
template <int EPI>
__global__ __launch_bounds__(512) void k_mgemm8(
    const __hip_bfloat16* __restrict__ A, const __hip_bfloat16* __restrict__ Wt,
    long woff, int K, int Nc,
    __hip_bfloat16* __restrict__ Cb,
    const void* __restrict__ bias, long boff,
    const float* __restrict__ scsh, const int* __restrict__ flag) {
  const int isb = *flag;
  __shared__ __align__(16) short As[2][128 * 64];
  __shared__ __align__(16) short Bs[2][128 * 64];
  const int t = threadIdx.x;
  const int l = t & 63, wid = t >> 6;      // 8 waves
  const int wm = wid & 1, wn = wid >> 1;   // 2 x 4
  const int lr = l >> 4, lc = l & 15;
  const int m0 = blockIdx.y * 128, n0 = blockIdx.x * 128;

  f32x4 acc[4][2] = {};
  const int lrow8 = l >> 3;
  const int lchunk = (l & 7) ^ lrow8;
  const __hip_bfloat16* gA = A + (long)(m0 + wid * 8 + lrow8) * K + lchunk * 8;
  const __hip_bfloat16* gB = Wt + woff + (long)(n0 + wid * 8 + lrow8) * K + lchunk * 8;

  // stage tile 0: pass p stages rows [p*64, p*64+64) across 8 waves
  #pragma unroll
  for (int p = 0; p < 2; p++) {
    gload16(gA + (long)p * 64 * K, &As[0][p * 4096 + wid * 512]);
    gload16(gB + (long)p * 64 * K, &Bs[0][p * 4096 + wid * 512]);
  }
  __syncthreads();

  const int nt = K >> 6;
  int cur = 0;
  for (int tt = 0; tt < nt; tt++) {
    if (tt + 1 < nt) {
      const int k0 = (tt + 1) * 64;
      #pragma unroll
      for (int p = 0; p < 2; p++) {
        gload16(gA + (long)p * 64 * K + k0, &As[cur ^ 1][p * 4096 + wid * 512]);
        gload16(gB + (long)p * 64 * K + k0, &Bs[cur ^ 1][p * 4096 + wid * 512]);
      }
    }
    #pragma unroll
    for (int kk = 0; kk < 2; kk++) {
      s16x8 af[4], bf[2];
      #pragma unroll
      for (int fm = 0; fm < 4; fm++) {
        const int r = wm * 64 + fm * 16 + lc;
        af[fm] = *(const s16x8*)&As[cur][r * 64 + (((kk * 4 + lr) ^ (r & 7)) * 8)];
      }
      #pragma unroll
      for (int fn = 0; fn < 2; fn++) {
        const int r = wn * 32 + fn * 16 + lc;
        bf[fn] = *(const s16x8*)&Bs[cur][r * 64 + (((kk * 4 + lr) ^ (r & 7)) * 8)];
      }
      #pragma unroll
      for (int fm = 0; fm < 4; fm++)
        #pragma unroll
        for (int fn = 0; fn < 2; fn++)
          acc[fm][fn] = __builtin_amdgcn_mfma_f32_16x16x32_bf16(af[fm], bf[fn], acc[fm][fn], 0, 0, 0);
    }
    __syncthreads();
    cur ^= 1;
  }

  #pragma unroll
  for (int fm = 0; fm < 4; fm++) {
    #pragma unroll
    for (int j = 0; j < 4; j++) {
      const int r = m0 + wm * 64 + fm * 16 + lr * 4 + j;
      const int bb = r >> 10;
      #pragma unroll
      for (int fn = 0; fn < 2; fn++) {
        const int cc = n0 + wn * 32 + fn * 16 + lc;
        const long off = (long)r * Nc + cc;
        float v = acc[fm][fn][j];
        v += ldin(bias, boff + cc, isb);
        v = v / (1.f + __expf(-v));
        v = v * (scsh[(long)bb * 2 * kI + cc] + 1.f) + scsh[(long)bb * 2 * kI + kI + cc];
        Cb[off] = __float2bfloat16(v);
      }
    }
  }
}

// ---------------- fused q + kv GEMM, 8-wave 128x128, 2-phase --------------
// grid (12, 32) x 512 thr. blockIdx.x<4: q = bf16((xn@Wq)*0.125), n0=bx*128;
// else kv = bf16(x@Wkv), n0=(bx-4)*128. K=512.
__global__ __launch_bounds__(512) void k_qkv8(
    const __hip_bfloat16* __restrict__ xnb, const __hip_bfloat16* __restrict__ xb,
    const __hip_bfloat16* __restrict__ wtq, const __hip_bfloat16* __restrict__ wtkv,
    __hip_bfloat16* __restrict__ qbuf, __hip_bfloat16* __restrict__ kvb) {
  constexpr int K = kD;
  __shared__ __align__(16) short As[2][128 * 64];
  __shared__ __align__(16) short Bs[2][128 * 64];
  const int t = threadIdx.x;
  const int l = t & 63, wid = t >> 6;
  const int wm = wid & 1, wn = wid >> 1;
  const int lr = l >> 4, lc = l & 15;
  const int m0 = blockIdx.y * 128;

  const __hip_bfloat16* A; const __hip_bfloat16* Wt; __hip_bfloat16* C;
  int Nc, n0; float scale;
  if (blockIdx.x < 4) {
    A = xnb; Wt = wtq; C = qbuf; Nc = kHid; n0 = blockIdx.x * 128; scale = 0.125f;
  } else {
    A = xb; Wt = wtkv; C = kvb; Nc = 2 * kHid; n0 = (blockIdx.x - 4) * 128; scale = 1.f;
  }

  f32x4 acc[4][2] = {};
  const int lrow8 = l >> 3;
  const int lchunk = (l & 7) ^ lrow8;
  const __hip_bfloat16* gA = A + (long)(m0 + wid * 8 + lrow8) * K + lchunk * 8;
  const __hip_bfloat16* gB = Wt + (long)(n0 + wid * 8 + lrow8) * K + lchunk * 8;

  #pragma unroll
  for (int p = 0; p < 2; p++) {
    gload16(gA + (long)p * 64 * K, &As[0][p * 4096 + wid * 512]);
    gload16(gB + (long)p * 64 * K, &Bs[0][p * 4096 + wid * 512]);
  }
  __syncthreads();

  const int nt = K >> 6;
  int cur = 0;
  for (int tt = 0; tt < nt; tt++) {
    if (tt + 1 < nt) {
      const int k0 = (tt + 1) * 64;
      #pragma unroll
      for (int p = 0; p < 2; p++) {
        gload16(gA + (long)p * 64 * K + k0, &As[cur ^ 1][p * 4096 + wid * 512]);
        gload16(gB + (long)p * 64 * K + k0, &Bs[cur ^ 1][p * 4096 + wid * 512]);
      }
    }
    #pragma unroll
    for (int kk = 0; kk < 2; kk++) {
      s16x8 af[4], bf[2];
      #pragma unroll
      for (int fm = 0; fm < 4; fm++) {
        const int r = wm * 64 + fm * 16 + lc;
        af[fm] = *(const s16x8*)&As[cur][r * 64 + (((kk * 4 + lr) ^ (r & 7)) * 8)];
      }
      #pragma unroll
      for (int fn = 0; fn < 2; fn++) {
        const int r = wn * 32 + fn * 16 + lc;
        bf[fn] = *(const s16x8*)&Bs[cur][r * 64 + (((kk * 4 + lr) ^ (r & 7)) * 8)];
      }
      #pragma unroll
      for (int fm = 0; fm < 4; fm++)
        #pragma unroll
        for (int fn = 0; fn < 2; fn++)
          acc[fm][fn] = __builtin_amdgcn_mfma_f32_16x16x32_bf16(af[fm], bf[fn], acc[fm][fn], 0, 0, 0);
    }
    __syncthreads();
    cur ^= 1;
  }

  #pragma unroll
  for (int fm = 0; fm < 4; fm++)
    #pragma unroll
    for (int j = 0; j < 4; j++) {
      const int r = m0 + wm * 64 + fm * 16 + lr * 4 + j;
      #pragma unroll
      for (int fn = 0; fn < 2; fn++) {
        const int cc = n0 + wn * 32 + fn * 16 + lc;
        C[(long)r * Nc + cc] = __float2bfloat16(acc[fm][fn][j] * scale);
      }
    }
}

// ---------------- MFMA flash attention: 8-wave blocks, split-j -------------
// grid 512 blocks x 512 threads. logical = (((b*8+h)*8)+x)*2 + jh;
// XCD swizzle: swz = (bid&7)*64 + (bid>>3). Block: 128 q-rows (8 waves x 16),
// j-range [jh*512, jh*512+512). Writes UNNORMALIZED o (f32) + per-row (m,l).
__global__ __launch_bounds__(512) void k_attn(
    const __hip_bfloat16* __restrict__ qb, const __hip_bfloat16* __restrict__ kvb,
    float* __restrict__ opart, float* __restrict__ mpart, float* __restrict__ lpart,
    const void* __restrict__ rpw, const void* __restrict__ rpb,
    const void* __restrict__ seqm, const int* __restrict__ ridx,
    const int* __restrict__ flag) {
  const int isb = *flag;
  const int t = threadIdx.x;
  const int bid = blockIdx.x;
  const int swz = (bid & 7) * 64 + (bid >> 3);
  const int jh = swz & 1, x = (swz >> 1) & 7, h = (swz >> 4) & 7, b = swz >> 7;
  const int i0 = x * 128;
  const int jbase = jh * 512;

  __shared__ __align__(16) short Ks[2][64 * 64];   // swizzled: elem d at d^((j&7)*8)
  __shared__ __align__(16) short Vt[2][64 * 72];   // Vt[d][j], rows padded to 72
  __shared__ __align__(16) short Ps[8][16 * 72];   // per-wave P, rows padded to 72
  __shared__ float biasw[kRel];
  __shared__ int riq[128];
  __shared__ float mkq[128];
  __shared__ int rik[2][64];
  __shared__ float mkk[2][64];

  const int l = t & 63, wid = t >> 6;       // wid 0..7
  const int g = l >> 4, li = l & 15;

  if (t < kRel) biasw[t] = ldin(rpw, (long)t * kH + h, isb) + ldin(rpb, h, isb);
  if (t < 128) { riq[t] = ridx[b * kN + i0 + t]; mkq[t] = ldin(seqm, b * kN + i0 + t, isb); }

  const __hip_bfloat16* qptr =
      qb + ((long)(b * kN + i0 + wid * 16 + li)) * kHid + h * kDh + g * 8;
  s16x8 aq[2];
  aq[0] = *(const s16x8*)qptr;
  aq[1] = *(const s16x8*)(qptr + 32);

  // ---- stage tile 0 into buffer 0 ----
  {
    const int j = wid * 8 + (l >> 3);
    const short* gk = (const short*)kvb + ((long)(b * kN + jbase + j)) * 1024 + h * 64 +
                      (((l & 7) ^ (l >> 3)) * 8);
    gload16(gk, &Ks[0][wid * 512]);
    const short* gv =
        (const short*)kvb + ((long)(b * kN + jbase + l)) * 1024 + 512 + h * 64 + wid * 8;
    s16x8 v0 = *(const s16x8*)gv;
    #pragma unroll
    for (int dd = 0; dd < 8; dd++) Vt[0][(wid * 8 + dd) * 72 + l] = v0[dd];
    if (t < 64) {
      rik[0][t] = ridx[b * kN + jbase + t];
      mkk[0][t] = ldin(seqm, b * kN + jbase + t, isb);
    }
  }
  __syncthreads();

  float mkqv[4]; int riqv[4];
  #pragma unroll
  for (int r = 0; r < 4; r++) {
    riqv[r] = riq[wid * 16 + g * 4 + r];
    mkqv[r] = mkq[wid * 16 + g * 4 + r];
  }

  float m_run[4] = {-1e30f, -1e30f, -1e30f, -1e30f};
  float l_run[4] = {0.f, 0.f, 0.f, 0.f};
  f32x4 o[4] = {};

  constexpr int NT = 8;   // 512 / 64
  int cur = 0;
  for (int tt = 0; tt < NT; tt++) {
    // ---- issue stage for tile tt+1 into buf cur^1 (before compute) ----
    s16x8 nv0;
    int nri = 0; float nmk = 0.f;
    const bool have = (tt + 1) < NT;
    if (have) {
      const int j0n = jbase + (tt + 1) * 64;
      const int j = wid * 8 + (l >> 3);
      const short* gk = (const short*)kvb + ((long)(b * kN + j0n + j)) * 1024 + h * 64 +
                        (((l & 7) ^ (l >> 3)) * 8);
      gload16(gk, &Ks[cur ^ 1][wid * 512]);
      const short* gv =
          (const short*)kvb + ((long)(b * kN + j0n + l)) * 1024 + 512 + h * 64 + wid * 8;
      nv0 = *(const s16x8*)gv;
      if (t < 64) { nri = ridx[b * kN + j0n + t]; nmk = ldin(seqm, b * kN + j0n + t, isb); }
    }

    // ---- compute on buf cur ----
    f32x4 s[4] = {};
    __builtin_amdgcn_s_setprio(1);
    #pragma unroll
    for (int kc = 0; kc < 2; kc++) {
      #pragma unroll
      for (int fc = 0; fc < 4; fc++) {
        const int jl = fc * 16 + li;
        const s16x8 bk = *(const s16x8*)&Ks[cur][jl * 64 + ((kc * 32 + g * 8) ^ ((li & 7) * 8))];
        s[fc] = __builtin_amdgcn_mfma_f32_16x16x32_bf16(aq[kc], bk, s[fc], 0, 0, 0);
      }
    }
    __builtin_amdgcn_s_setprio(0);

    int rikv[4]; float mkkv[4];
    #pragma unroll
    for (int fc = 0; fc < 4; fc++) {
      rikv[fc] = rik[cur][fc * 16 + li];
      mkkv[fc] = mkk[cur][fc * 16 + li];
    }
    #pragma unroll
    for (int fc = 0; fc < 4; fc++) {
      #pragma unroll
      for (int r = 0; r < 4; r++) {
        int di = riqv[r] - rikv[fc];
        di = di < -32 ? -32 : (di > 32 ? 32 : di);
        s[fc][r] += biasw[di + 32] - (1.f - mkqv[r] * mkkv[fc]) * 1e6f;
      }
    }

    #pragma unroll
    for (int r = 0; r < 4; r++) {
      float mx = fmaxf(fmaxf(s[0][r], s[1][r]), fmaxf(s[2][r], s[3][r]));
      mx = fmaxf(mx, __shfl_xor(mx, 1));
      mx = fmaxf(mx, __shfl_xor(mx, 2));
      mx = fmaxf(mx, __shfl_xor(mx, 4));
      mx = fmaxf(mx, __shfl_xor(mx, 8));
      const float m_new = fmaxf(m_run[r], mx);
      const float e = __expf(m_run[r] - m_new);
      float ps = 0.f;
      #pragma unroll
      for (int fc = 0; fc < 4; fc++) {
        const float p = __expf(s[fc][r] - m_new);
        ps += p;
        Ps[wid][(g * 4 + r) * 72 + fc * 16 + li] = (short)bfbits(p);
      }
      ps += __shfl_xor(ps, 1);
      ps += __shfl_xor(ps, 2);
      ps += __shfl_xor(ps, 4);
      ps += __shfl_xor(ps, 8);
      l_run[r] = l_run[r] * e + ps;
      m_run[r] = m_new;
      o[0][r] *= e; o[1][r] *= e; o[2][r] *= e; o[3][r] *= e;
    }

    __builtin_amdgcn_s_setprio(1);
    #pragma unroll
    for (int kc = 0; kc < 2; kc++) {
      const s16x8 pa = *(const s16x8*)&Ps[wid][li * 72 + kc * 32 + g * 8];
      #pragma unroll
      for (int fd = 0; fd < 4; fd++) {
        const s16x8 bv = *(const s16x8*)&Vt[cur][(fd * 16 + li) * 72 + kc * 32 + g * 8];
        o[fd] = __builtin_amdgcn_mfma_f32_16x16x32_bf16(pa, bv, o[fd], 0, 0, 0);
      }
    }
    __builtin_amdgcn_s_setprio(0);

    // ---- deferred writes of staged tile (V + metadata) ----
    if (have) {
      #pragma unroll
      for (int dd = 0; dd < 8; dd++) Vt[cur ^ 1][(wid * 8 + dd) * 72 + l] = nv0[dd];
      if (t < 64) { rik[cur ^ 1][t] = nri; mkk[cur ^ 1][t] = nmk; }
    }
    __syncthreads();
    cur ^= 1;
  }

  // ---- write unnormalized O (f32) + per-row m,l ----
  #pragma unroll
  for (int fd = 0; fd < 4; fd++) {
    #pragma unroll
    for (int r = 0; r < 4; r++) {
      const long off =
          ((long)(b * kN + i0 + wid * 16 + g * 4 + r)) * kHid + h * kDh + fd * 16 + li;
      opart[(long)jh * 2097152 + off] = o[fd][r];
    }
  }
  if (li == 0) {
    #pragma unroll
    for (int r = 0; r < 4; r++) {
      const int row = i0 + wid * 16 + g * 4 + r;
      const int idx = (b * kN + row) * 8 + h;
      mpart[jh * 32768 + idx] = m_run[r];
      lpart[jh * 32768 + idx] = l_run[r];
    }
  }
}

// ---------------- combine the two j-halves -> aob (bf16) ----------------
__global__ __launch_bounds__(256) void k_acomb(
    const float* __restrict__ opart, const float* __restrict__ mpart,
    const float* __restrict__ lpart, __hip_bfloat16* __restrict__ aob) {
  const long e = ((long)blockIdx.x * 256 + threadIdx.x) * 8;
  const int h = (int)((e >> 6) & 7);
  const int row = (int)(e >> 9);
  const int idx = row * 8 + h;
  const float m0 = mpart[idx], m1 = mpart[32768 + idx];
  const float l0 = lpart[idx], l1 = lpart[32768 + idx];
  const float mm = fmaxf(m0, m1);
  const float e0 = __expf(m0 - mm), e1 = __expf(m1 - mm);
  const float den = fmaxf(e0 * l0 + e1 * l1, 1e-30f);
  const float s0 = e0 / den, s1 = e1 / den;
  const float4 a0 = *(const float4*)(opart + e);
  const float4 a1 = *(const float4*)(opart + e + 4);
  const float4 b0 = *(const float4*)(opart + 2097152 + e);
  const float4 b1 = *(const float4*)(opart + 2097152 + e + 4);
  __align__(16) unsigned short pk[8];
  pk[0] = bfbits(a0.x * s0 + b0.x * s1);
  pk[1] = bfbits(a0.y * s0 + b0.y * s1);
  pk[2] = bfbits(a0.z * s0 + b0.z * s1);
  pk[3] = bfbits(a0.w * s0 + b0.w * s1);
  pk[4] = bfbits(a1.x * s0 + b1.x * s1);
  pk[5] = bfbits(a1.y * s0 + b1.y * s1);
  pk[6] = bfbits(a1.z * s0 + b1.z * s1);
  pk[7] = bfbits(a1.w * s0 + b1.w * s1);
  *(uint4*)(aob + e) = *(const uint4*)pk;
}

// ---------------- write out (dual dtype) ----------------
__global__ void k_out(const float* __restrict__ x, void* __restrict__ out,
                      const int* __restrict__ flag) {
  const int i = blockIdx.x * 256 + threadIdx.x;
  if (*flag) ((__hip_bfloat16*)out)[i] = __float2bfloat16(x[i]);
  else ((float*)out)[i] = x[i];
}

extern "C" void kernel_launch(void* const* d_in, const int* in_sizes, int n_in,
                              void* d_out, int out_size, void* d_ws, size_t ws_size,
                              hipStream_t stream) {
  const void* xin  = d_in[0];
  const void* timein = d_in[1];
  const void* seqm = d_in[2];
  const int*  ridx = (const int*)d_in[3];
  const void* rpw  = d_in[4];
  const void* rpb  = d_in[5];
  const void* ang  = d_in[6];
  const void* atw  = d_in[7];
  const void* atb  = d_in[8];
  const void* wq   = d_in[9];
  const void* wkv  = d_in[10];
  const void* wo   = d_in[11];
  const void* fng  = d_in[12];
  const void* ftw  = d_in[13];
  const void* ftb  = d_in[14];
  const void* wfi  = d_in[15];
  const void* bfi  = d_in[16];
  const void* wfo  = d_in[17];
  const void* bfo  = d_in[18];

  float* ws = (float*)d_ws;
  float* x     = ws;                 // 2,097,152 f32
  float* ascsh = ws + 2097152;       // 16,384  [D][B][2*kD]
  float* fscsh = ws + 2113536;       // 65,536  [D][B][2*kI]
  float* part  = ws + 2179072;       // 655,360; reused as attn m/l after timeproj
  int*   flag  = (int*)(ws + 2834432);
  __hip_bfloat16* bfb = (__hip_bfloat16*)(ws + 2834496);
  __hip_bfloat16* xnb  = bfb;             // 2,097,152
  __hip_bfloat16* xb   = bfb + 2097152;   // 2,097,152
  __hip_bfloat16* aob  = bfb + 4194304;   // 2,097,152
  __hip_bfloat16* hb   = bfb + 6291456;   // 8,388,608 (reused as attn opart f32)
  __hip_bfloat16* qbuf = bfb + 14680064;  // 2,097,152
  __hip_bfloat16* kvb  = bfb + 16777216;  // 4,194,304
  __hip_bfloat16* wtq  = bfb + 20971520;  // 1,048,576 [D][512][512]
  __hip_bfloat16* wtkv = bfb + 22020096;  // 2,097,152 [D][1024][512]
  __hip_bfloat16* wto  = bfb + 24117248;  // 1,048,576 [D][512][512]
  __hip_bfloat16* wtfi = bfb + 25165824;  // 4,194,304 [D][2048][512]
  __hip_bfloat16* wtfo = bfb + 29360128;  // 4,194,304 [D][512][2048]
  float* opart = (float*)hb;              // 2 x 2,097,152 f32 (16.78 MB = hb size)
  float* mpart = part;                    // 2 x 32,768
  float* lpart = part + 65536;            // 2 x 32,768

  k_detect<<<1, 64, 0, stream>>>(xin, flag);
  k_xinit<<<kBN * kD / 2048, 256, 0, stream>>>(xin, seqm, x, xb, flag);
  k_timeproj_part<<<dim3(20, 8, kDepth), 256, 0, stream>>>(timein, atw, ftw, part, flag);
  k_timeproj_comb<<<dim3(20, kDepth), 256, 0, stream>>>(part, atb, ftb, ascsh, fscsh, flag);
  k_wtall<<<3072, 256, 0, stream>>>(wq, wkv, wo, wfi, wfo, wtq, wtkv, wto, wtfi, wtfo, flag);

  for (int d = 0; d < kDepth; ++d) {
    k_ln<<<kBN / 4, 256, 0, stream>>>(x, ang, ascsh + (long)d * kB * 2 * kD, seqm, xnb, d, 1, flag);
    k_qkv8<<<dim3(12, kBN / 128), 512, 0, stream>>>(
        xnb, xb, wtq + (long)d * kD * kHid, wtkv + (long)d * kD * 2 * kHid, qbuf, kvb);
    k_attn<<<512, 512, 0, stream>>>(qbuf, kvb, opart, mpart, lpart, rpw, rpb, seqm, ridx, flag);
    k_acomb<<<1024, 256, 0, stream>>>(opart, mpart, lpart, aob);
    // x += (ao @ Wo) * mask
    k_mgemm<2, 64><<<dim3(kD / 64, kBN / 64), 256, 0, stream>>>(
        aob, wto, (long)d * kHid * kD, kHid, kD, nullptr, x, nullptr,
        nullptr, 0, nullptr, seqm, flag);
    k_ln<<<kBN / 4, 256, 0, stream>>>(x, fng, nullptr, seqm, xnb, d, 0, flag);
    // h = silu(xn @ Wfi + b)*(sc+1)+sh
    k_mgemm8<3><<<dim3(kI / 128, kBN / 128), 512, 0, stream>>>(
        xnb, wtfi, (long)d * kD * kI, kD, kI, hb,
        bfi, (long)d * kI, fscsh + (long)d * kB * 2 * kI, flag);
    // x = (x + h @ Wfo + b)*mask ; xb = bf16(x)
    k_mgemm<4, 64><<<dim3(kD / 64, kBN / 64), 256, 0, stream>>>(
        hb, wtfo, (long)d * kI * kD, kI, kD, nullptr, x, xb,
        bfo, (long)d * kD, nullptr, seqm, flag);
  }
  k_out<<<kBN * kD / 256, 256, 0, stream>>>(x, d_out, flag);
}